// Round 3
// baseline (1598.687 us; speedup 1.0000x reference)
//
#include <hip/hip_runtime.h>

// GCN1: ChebConv(K=3) -> global max pool -> MLP(32->1024->512->4)
// Device dtypes (established rounds 0-2): floats are fp32, edge_index/batch
// are int32 (harness converts int64->int32), output is fp32.

#define NTHREADS 256

__device__ __forceinline__ void atomicMaxFloat(float* addr, float val) {
    // correct for all non-NaN floats given init = -inf
    if (val >= 0.0f) atomicMax((int*)addr, __float_as_int(val));
    else             atomicMin((unsigned int*)addr, __float_as_uint(val));
}

// ---- degree (segment_sum of ones over row) ----
__global__ void k_degree(const int* __restrict__ row, float* __restrict__ deg, int E) {
    int e = blockIdx.x * blockDim.x + threadIdx.x;
    if (e < E) atomicAdd(&deg[row[e]], 1.0f);
}

// ---- deg -> dis = deg>0 ? rsqrt(deg) : 0 (in place) ----
__global__ void k_dis(float* __restrict__ deg, int N) {
    int i = blockIdx.x * blockDim.x + threadIdx.x;
    if (i < N) {
        float d = deg[i];
        deg[i] = (d > 0.0f) ? rsqrtf(d) : 0.0f;
    }
}

// ---- prop: dst[col] += -(dis[row]*dis[col]) * src[row]  (8 threads/edge, float4) ----
__global__ void k_prop(const int* __restrict__ row, const int* __restrict__ col,
                       const float* __restrict__ dis,
                       const float* __restrict__ src, float* __restrict__ dst, int E) {
    int idx = blockIdx.x * blockDim.x + threadIdx.x;
    int e = idx >> 3, q = idx & 7;
    if (e < E) {
        int r = row[e], c = col[e];
        float w = -dis[r] * dis[c];
        float4 v = ((const float4*)(src + (size_t)r * 32))[q];
        float* d = dst + (size_t)c * 32 + q * 4;
        atomicAdd(d + 0, w * v.x);
        atomicAdd(d + 1, w * v.y);
        atomicAdd(d + 2, w * v.z);
        atomicAdd(d + 3, w * v.w);
    }
}

// ---- init pooled max to -inf ----
__global__ void k_ginit(float* __restrict__ g) {
    int i = blockIdx.x * blockDim.x + threadIdx.x;
    if (i < 64 * 32) g[i] = -__builtin_inff();
}

// ---- fused: h = x@W0 + Tx1@W1 + (2*P2 - x)@W2 + b ; block-segmented max -> atomicMax ----
__global__ __launch_bounds__(256) void k_combine(
    const float* __restrict__ x, const float* __restrict__ tx1, const float* __restrict__ p2,
    const float* __restrict__ Wc, const float* __restrict__ bc,
    const int* __restrict__ batch, float* __restrict__ g, int N) {
    __shared__ float sW[3 * 32 * 32];
    __shared__ float sb[32];
    __shared__ float sx[8][32], s1[8][32], s2[8][32], sval[8][32];
    __shared__ int sbatch[8];

    int tid = threadIdx.x;
    for (int i = tid; i < 3072; i += 256) sW[i] = Wc[i];
    if (tid < 32) sb[tid] = bc[tid];

    int ty = tid >> 5, f = tid & 31;
    int r = blockIdx.x * 8 + ty;
    if (r < N) {
        sx[ty][f] = x[(size_t)r * 32 + f];
        s1[ty][f] = tx1[(size_t)r * 32 + f];
        s2[ty][f] = p2[(size_t)r * 32 + f];
        if (f == 0) sbatch[ty] = batch[r];
    } else if (f == 0) {
        sbatch[ty] = -1;
    }
    __syncthreads();

    float acc = sb[f];
    if (r < N) {
        for (int k = 0; k < 32; k++) {
            float t0 = sx[ty][k];
            float t1 = s1[ty][k];
            float t2 = 2.0f * s2[ty][k] - t0;
            acc += t0 * sW[k * 32 + f] + t1 * sW[1024 + k * 32 + f] + t2 * sW[2048 + k * 32 + f];
        }
    }
    sval[ty][f] = acc;
    __syncthreads();

    if (ty == 0) {  // 32 threads, one per feature: segmented max over the 8 rows
        int curb = -1;
        float curm = 0.0f;
        for (int j = 0; j < 8; j++) {
            int b = sbatch[j];
            if (b < 0) continue;
            if (b != curb) {
                if (curb >= 0) atomicMaxFloat(&g[curb * 32 + f], curm);
                curb = b;
                curm = sval[j][f];
            } else {
                curm = fmaxf(curm, sval[j][f]);
            }
        }
        if (curb >= 0) atomicMaxFloat(&g[curb * 32 + f], curm);
    }
}

// ---- MLP layer 1: h1[64,1024] = relu(g[64,32] @ W1 + b1) ----
__global__ void k_mlp1(const float* __restrict__ g, const float* __restrict__ W1,
                       const float* __restrict__ b1, float* __restrict__ h1) {
    __shared__ float sg[64 * 32];
    int tid = threadIdx.x;
    for (int i = tid; i < 64 * 32; i += 256) sg[i] = g[i];
    __syncthreads();
    int idx = blockIdx.x * 256 + tid;            // 65536 total
    int gi = idx >> 10, j = idx & 1023;
    float acc = b1[j];
    for (int k = 0; k < 32; k++) acc += sg[gi * 32 + k] * W1[k * 1024 + j];
    h1[idx] = fmaxf(acc, 0.0f);
}

// ---- MLP layer 2: h2[64,512] = relu(h1 @ W2 + b2), one block per graph ----
__global__ void k_mlp2(const float* __restrict__ h1, const float* __restrict__ W2,
                       const float* __restrict__ b2, float* __restrict__ h2) {
    __shared__ float sh[1024];
    int gi = blockIdx.x, tid = threadIdx.x;
    for (int i = tid; i < 1024; i += 256) sh[i] = h1[gi * 1024 + i];
    __syncthreads();
    for (int j = tid; j < 512; j += 256) {
        float acc = b2[j];
        for (int k = 0; k < 1024; k++) acc += sh[k] * W2[k * 512 + j];
        h2[gi * 512 + j] = fmaxf(acc, 0.0f);
    }
}

// ---- MLP layer 3: out[64,4] = h2 @ W3 + b3 (fp32 store) ----
__global__ void k_mlp3(const float* __restrict__ h2, const float* __restrict__ W3,
                       const float* __restrict__ b3, float* __restrict__ out) {
    int tid = threadIdx.x;  // 256 = 64*4
    int gi = tid >> 2, j = tid & 3;
    float acc = b3[j];
    for (int k = 0; k < 512; k++) acc += h2[gi * 512 + k] * W3[k * 4 + j];
    out[tid] = acc;
}

extern "C" void kernel_launch(void* const* d_in, const int* in_sizes, int n_in,
                              void* d_out, int out_size, void* d_ws, size_t ws_size,
                              hipStream_t stream) {
    const float* x     = (const float*)d_in[0];
    const int* ei      = (const int*)d_in[1];    // int64 in reference -> int32 on device
    const int* batch   = (const int*)d_in[2];
    const float* Wc    = (const float*)d_in[3];
    const float* bc    = (const float*)d_in[4];
    const float* W1    = (const float*)d_in[5];
    const float* b1    = (const float*)d_in[6];
    const float* W2    = (const float*)d_in[7];
    const float* b2    = (const float*)d_in[8];
    const float* W3    = (const float*)d_in[9];
    const float* b3    = (const float*)d_in[10];
    float* out         = (float*)d_out;

    const int N = in_sizes[2];      // 100000 nodes (batch array length)
    const int E = in_sizes[1] / 2;  // 1.6M edges
    const int* row = ei;
    const int* col = ei + E;

    float* ws  = (float*)d_ws;
    float* deg = ws;                                  // N
    float* tx1 = deg + N;                             // N*32
    float* p2  = tx1 + (size_t)N * 32;                // N*32
    float* g   = p2  + (size_t)N * 32;                // 64*32
    float* h1  = g + 64 * 32;                         // 64*1024
    float* h2  = h1 + 64 * 1024;                      // 64*512

    // zero deg, tx1, p2 in one contiguous memset (ws is re-poisoned every call)
    hipMemsetAsync(deg, 0, sizeof(float) * ((size_t)N + 2 * (size_t)N * 32), stream);

    k_degree<<<(E + NTHREADS - 1) / NTHREADS, NTHREADS, 0, stream>>>(row, deg, E);
    k_dis<<<(N + NTHREADS - 1) / NTHREADS, NTHREADS, 0, stream>>>(deg, N);
    k_prop<<<((E * 8) + NTHREADS - 1) / NTHREADS, NTHREADS, 0, stream>>>(row, col, deg, x, tx1, E);
    k_prop<<<((E * 8) + NTHREADS - 1) / NTHREADS, NTHREADS, 0, stream>>>(row, col, deg, tx1, p2, E);
    k_ginit<<<8, NTHREADS, 0, stream>>>(g);
    k_combine<<<(N + 7) / 8, NTHREADS, 0, stream>>>(x, tx1, p2, Wc, bc, batch, g, N);
    k_mlp1<<<256, NTHREADS, 0, stream>>>(g, W1, b1, h1);
    k_mlp2<<<64, NTHREADS, 0, stream>>>(h1, W2, b2, h2);
    k_mlp3<<<1, NTHREADS, 0, stream>>>(h2, W3, b3, out);
}

// Round 4
// 553.843 us; speedup vs baseline: 2.8865x; 2.8865x over previous
//
#include <hip/hip_runtime.h>

// GCN1: ChebConv(K=3) -> global max pool -> MLP(32->1024->512->4)
// fp32 floats, int32 indices (established rounds 0-3).
// Round 4: replace scatter-atomic propagation (79G atomics/s ceiling, 800MB
// HBM write-through per prop) with device-built CSR + pure-gather prop.

#define NT 256

__device__ __forceinline__ void atomicMaxFloat(float* addr, float val) {
    // correct for all non-NaN floats given init = -inf
    if (val >= 0.0f) atomicMax((int*)addr, __float_as_int(val));
    else             atomicMin((unsigned int*)addr, __float_as_uint(val));
}

// ---- histogram: out-degree (by row) for dis, in-degree (by col) for CSR ----
__global__ void k_hist(const int* __restrict__ row, const int* __restrict__ col,
                       int* __restrict__ rowcnt, int* __restrict__ colcnt, int E) {
    int e = blockIdx.x * blockDim.x + threadIdx.x;
    if (e < E) {
        atomicAdd(&rowcnt[row[e]], 1);
        atomicAdd(&colcnt[col[e]], 1);
    }
}

// ---- scan stage 1: per-block exclusive scan of colcnt -> offs (partial), block sums; dis ----
__global__ __launch_bounds__(NT) void k_scan1(const int* __restrict__ colcnt,
                                              const int* __restrict__ rowcnt,
                                              int* __restrict__ offs, int* __restrict__ bsum,
                                              float* __restrict__ dis, int N) {
    __shared__ int s[NT];
    int tid = threadIdx.x;
    int i = blockIdx.x * NT + tid;
    int v = (i < N) ? colcnt[i] : 0;
    s[tid] = v;
    __syncthreads();
    for (int off = 1; off < NT; off <<= 1) {
        int t = (tid >= off) ? s[tid - off] : 0;
        __syncthreads();
        s[tid] += t;
        __syncthreads();
    }
    if (i < N) {
        offs[i] = s[tid] - v;  // block-local exclusive
        int d = rowcnt[i];
        dis[i] = (d > 0) ? rsqrtf((float)d) : 0.0f;
    }
    if (tid == NT - 1) bsum[blockIdx.x] = s[tid];
}

// ---- scan stage 2: exclusive scan of block sums (NB <= 512, one block) ----
__global__ __launch_bounds__(512) void k_scan2(const int* __restrict__ bsum,
                                               int* __restrict__ bscan, int NB) {
    __shared__ int s[512];
    int tid = threadIdx.x;
    int v = (tid < NB) ? bsum[tid] : 0;
    s[tid] = v;
    __syncthreads();
    for (int off = 1; off < 512; off <<= 1) {
        int t = (tid >= off) ? s[tid - off] : 0;
        __syncthreads();
        s[tid] += t;
        __syncthreads();
    }
    if (tid < NB) bscan[tid] = s[tid] - v;
}

// ---- scan stage 3: add block offsets; init cursor; offs[N]=E ----
__global__ void k_scan3(int* __restrict__ offs, const int* __restrict__ bscan,
                        int* __restrict__ cursor, int N, int E) {
    int i = blockIdx.x * blockDim.x + threadIdx.x;
    if (i < N) {
        int o = offs[i] + bscan[blockIdx.x];
        offs[i] = o;
        cursor[i] = o;
    }
    if (i == 0) offs[N] = E;
}

// ---- scatter edges into CSR buckets (by col), storing source index ----
__global__ void k_scatter(const int* __restrict__ row, const int* __restrict__ col,
                          int* __restrict__ cursor, int* __restrict__ entries, int E) {
    int e = blockIdx.x * blockDim.x + threadIdx.x;
    if (e < E) {
        int pos = atomicAdd(&cursor[col[e]], 1);
        entries[pos] = row[e];
    }
}

// ---- gather prop: dst[c] = -dis[c] * sum_{e in in(c)} dis[r_e] * src[r_e] ----
// 4 threads per node, 8 features (2x float4) each. No atomics; dst fully written.
__global__ __launch_bounds__(NT) void k_prop_g(const int* __restrict__ offs,
                                               const int* __restrict__ entries,
                                               const float* __restrict__ dis,
                                               const float* __restrict__ src,
                                               float* __restrict__ dst, int N) {
    int idx = blockIdx.x * blockDim.x + threadIdx.x;
    int node = idx >> 2, q = idx & 3;
    if (node >= N) return;
    int s = offs[node], t = offs[node + 1];
    float a0x = 0, a0y = 0, a0z = 0, a0w = 0;
    float a1x = 0, a1y = 0, a1z = 0, a1w = 0;
    for (int e = s; e < t; e++) {
        int r = entries[e];
        float w = dis[r];
        const float4* p = (const float4*)(src + (size_t)r * 32 + q * 8);
        float4 v0 = p[0];
        float4 v1 = p[1];
        a0x += w * v0.x; a0y += w * v0.y; a0z += w * v0.z; a0w += w * v0.w;
        a1x += w * v1.x; a1y += w * v1.y; a1z += w * v1.z; a1w += w * v1.w;
    }
    float sc = -dis[node];
    float4 o0 = {sc * a0x, sc * a0y, sc * a0z, sc * a0w};
    float4 o1 = {sc * a1x, sc * a1y, sc * a1z, sc * a1w};
    float4* d = (float4*)(dst + (size_t)node * 32 + q * 8);
    d[0] = o0;
    d[1] = o1;
}

// ---- init pooled max to -inf ----
__global__ void k_ginit(float* __restrict__ g) {
    int i = blockIdx.x * blockDim.x + threadIdx.x;
    if (i < 64 * 32) g[i] = -__builtin_inff();
}

// ---- fused: h = x@W0 + Tx1@W1 + (2*P2 - x)@W2 + b ; block-segmented max -> atomicMax ----
__global__ __launch_bounds__(NT) void k_combine(
    const float* __restrict__ x, const float* __restrict__ tx1, const float* __restrict__ p2,
    const float* __restrict__ Wc, const float* __restrict__ bc,
    const int* __restrict__ batch, float* __restrict__ g, int N) {
    __shared__ float sW[3 * 32 * 32];
    __shared__ float sb[32];
    __shared__ float sx[8][32], s1[8][32], s2[8][32], sval[8][32];
    __shared__ int sbatch[8];

    int tid = threadIdx.x;
    for (int i = tid; i < 3072; i += NT) sW[i] = Wc[i];
    if (tid < 32) sb[tid] = bc[tid];

    int ty = tid >> 5, f = tid & 31;
    int r = blockIdx.x * 8 + ty;
    if (r < N) {
        sx[ty][f] = x[(size_t)r * 32 + f];
        s1[ty][f] = tx1[(size_t)r * 32 + f];
        s2[ty][f] = p2[(size_t)r * 32 + f];
        if (f == 0) sbatch[ty] = batch[r];
    } else if (f == 0) {
        sbatch[ty] = -1;
    }
    __syncthreads();

    float acc = sb[f];
    if (r < N) {
        for (int k = 0; k < 32; k++) {
            float t0 = sx[ty][k];
            float t1 = s1[ty][k];
            float t2 = 2.0f * s2[ty][k] - t0;
            acc += t0 * sW[k * 32 + f] + t1 * sW[1024 + k * 32 + f] + t2 * sW[2048 + k * 32 + f];
        }
    }
    sval[ty][f] = acc;
    __syncthreads();

    if (ty == 0) {  // 32 threads, one per feature: segmented max over the 8 rows
        int curb = -1;
        float curm = 0.0f;
        for (int j = 0; j < 8; j++) {
            int b = sbatch[j];
            if (b < 0) continue;
            if (b != curb) {
                if (curb >= 0) atomicMaxFloat(&g[curb * 32 + f], curm);
                curb = b;
                curm = sval[j][f];
            } else {
                curm = fmaxf(curm, sval[j][f]);
            }
        }
        if (curb >= 0) atomicMaxFloat(&g[curb * 32 + f], curm);
    }
}

// ---- MLP layer 1: h1[64,1024] = relu(g[64,32] @ W1 + b1) ----
__global__ void k_mlp1(const float* __restrict__ g, const float* __restrict__ W1,
                       const float* __restrict__ b1, float* __restrict__ h1) {
    __shared__ float sg[64 * 32];
    int tid = threadIdx.x;
    for (int i = tid; i < 64 * 32; i += NT) sg[i] = g[i];
    __syncthreads();
    int idx = blockIdx.x * NT + tid;  // 65536 total
    int gi = idx >> 10, j = idx & 1023;
    float acc = b1[j];
    for (int k = 0; k < 32; k++) acc += sg[gi * 32 + k] * W1[k * 1024 + j];
    h1[idx] = fmaxf(acc, 0.0f);
}

// ---- MLP layer 2: h2[64,512] = relu(h1 @ W2 + b2), one block per graph ----
__global__ void k_mlp2(const float* __restrict__ h1, const float* __restrict__ W2,
                       const float* __restrict__ b2, float* __restrict__ h2) {
    __shared__ float sh[1024];
    int gi = blockIdx.x, tid = threadIdx.x;
    for (int i = tid; i < 1024; i += NT) sh[i] = h1[gi * 1024 + i];
    __syncthreads();
    for (int j = tid; j < 512; j += NT) {
        float acc = b2[j];
        for (int k = 0; k < 1024; k++) acc += sh[k] * W2[k * 512 + j];
        h2[gi * 512 + j] = fmaxf(acc, 0.0f);
    }
}

// ---- MLP layer 3: out[64,4] = h2 @ W3 + b3 ----
__global__ void k_mlp3(const float* __restrict__ h2, const float* __restrict__ W3,
                       const float* __restrict__ b3, float* __restrict__ out) {
    int tid = threadIdx.x;  // 256 = 64*4
    int gi = tid >> 2, j = tid & 3;
    float acc = b3[j];
    for (int k = 0; k < 512; k++) acc += h2[gi * 512 + k] * W3[k * 4 + j];
    out[tid] = acc;
}

extern "C" void kernel_launch(void* const* d_in, const int* in_sizes, int n_in,
                              void* d_out, int out_size, void* d_ws, size_t ws_size,
                              hipStream_t stream) {
    const float* x   = (const float*)d_in[0];
    const int* ei    = (const int*)d_in[1];   // int64 in reference -> int32 on device
    const int* batch = (const int*)d_in[2];
    const float* Wc  = (const float*)d_in[3];
    const float* bc  = (const float*)d_in[4];
    const float* W1  = (const float*)d_in[5];
    const float* b1  = (const float*)d_in[6];
    const float* W2  = (const float*)d_in[7];
    const float* b2  = (const float*)d_in[8];
    const float* W3  = (const float*)d_in[9];
    const float* b3  = (const float*)d_in[10];
    float* out       = (float*)d_out;

    const int N = in_sizes[2];      // 100000
    const int E = in_sizes[1] / 2;  // 1.6M
    const int* row = ei;
    const int* col = ei + E;
    const int NB = (N + NT - 1) / NT;  // scan blocks (391 <= 512)

    // workspace layout (all 16B-aligned: sizes rounded to multiples of 4 elems)
    int* iws = (int*)d_ws;
    int* rowcnt  = iws;                          // N
    int* colcnt  = rowcnt + N;                   // N (dead after scan1 -> reused as cursor)
    int* offs    = colcnt + N;                   // N+1 (pad to N+4)
    int* bsum    = offs + N + 4;                 // NB (pad 512)
    int* bscan   = bsum + 512;                   // NB (pad 512)
    float* dis   = (float*)(bscan + 512);        // N
    int* entries = (int*)(dis + N);              // E
    float* tx1   = (float*)(entries + E);        // N*32
    float* p2    = tx1 + (size_t)N * 32;         // N*32
    float* g     = p2 + (size_t)N * 32;          // 64*32
    float* h1    = g + 64 * 32;                  // 64*1024
    float* h2    = h1 + 64 * 1024;               // 64*512
    int* cursor  = colcnt;                       // reuse

    // zero only the histograms (rowcnt+colcnt contiguous)
    hipMemsetAsync(rowcnt, 0, sizeof(int) * 2 * (size_t)N, stream);

    k_hist<<<(E + NT - 1) / NT, NT, 0, stream>>>(row, col, rowcnt, colcnt, E);
    k_scan1<<<NB, NT, 0, stream>>>(colcnt, rowcnt, offs, bsum, dis, N);
    k_scan2<<<1, 512, 0, stream>>>(bsum, bscan, NB);
    k_scan3<<<NB, NT, 0, stream>>>(offs, bscan, cursor, N, E);
    k_scatter<<<(E + NT - 1) / NT, NT, 0, stream>>>(row, col, cursor, entries, E);
    k_prop_g<<<((size_t)N * 4 + NT - 1) / NT, NT, 0, stream>>>(offs, entries, dis, x, tx1, N);
    k_prop_g<<<((size_t)N * 4 + NT - 1) / NT, NT, 0, stream>>>(offs, entries, dis, tx1, p2, N);
    k_ginit<<<8, NT, 0, stream>>>(g);
    k_combine<<<(N + 7) / 8, NT, 0, stream>>>(x, tx1, p2, Wc, bc, batch, g, N);
    k_mlp1<<<256, NT, 0, stream>>>(g, W1, b1, h1);
    k_mlp2<<<64, NT, 0, stream>>>(h1, W2, b2, h2);
    k_mlp3<<<1, NT, 0, stream>>>(h2, W3, b3, out);
}

// Round 6
// 428.673 us; speedup vs baseline: 3.7294x; 1.2920x over previous
//
#include <hip/hip_runtime.h>

// GCN1: ChebConv(K=3) -> global max pool -> MLP(32->1024->512->4)
// fp32 floats, int32 indices (established rounds 0-3).
// Round 5 (resubmitted round 6 after infra flake): CSR build via two-level
// bucketed counting sort — no per-edge global atomics, no random 4B stores
// (round-4 k_scatter: 105MB L2-out writes, 126us; k_hist: 3.2M atomics).

#define NT 256
#define BSHIFT 8
#define BSIZE 256   // nodes per bucket; NBK = ceil(N/256) = 391 <= 512

__device__ __forceinline__ void atomicMaxFloat(float* addr, float val) {
    if (val >= 0.0f) atomicMax((int*)addr, __float_as_int(val));
    else             atomicMin((unsigned int*)addr, __float_as_uint(val));
}

// ---- pass 1: rowcnt histogram (global atomics) + LDS bucket histogram of col ----
__global__ __launch_bounds__(NT) void k_hist2(const int* __restrict__ row,
                                              const int* __restrict__ col,
                                              int* __restrict__ rowcnt,
                                              int* __restrict__ bhist,
                                              int E, int NBK, int epb) {
    __shared__ int lh[512];
    int tid = threadIdx.x;
    for (int i = tid; i < NBK; i += NT) lh[i] = 0;
    __syncthreads();
    int start = blockIdx.x * epb;
    int end = min(start + epb, E);
    for (int e = start + tid; e < end; e += NT) {
        atomicAdd(&rowcnt[row[e]], 1);
        atomicAdd(&lh[col[e] >> BSHIFT], 1);
    }
    __syncthreads();
    for (int i = tid; i < NBK; i += NT) {
        int v = lh[i];
        if (v) atomicAdd(&bhist[i], v);
    }
}

// ---- pass 2: exclusive scan of bucket counts (one block) ----
__global__ __launch_bounds__(512) void k_bscan(const int* __restrict__ bhist,
                                               int* __restrict__ bbase,
                                               int* __restrict__ bcur, int NBK, int E) {
    __shared__ int s[512];
    int tid = threadIdx.x;
    int v = (tid < NBK) ? bhist[tid] : 0;
    s[tid] = v;
    __syncthreads();
    for (int off = 1; off < 512; off <<= 1) {
        int t = (tid >= off) ? s[tid - off] : 0;
        __syncthreads();
        s[tid] += t;
        __syncthreads();
    }
    if (tid < NBK) {
        int b = s[tid] - v;
        bbase[tid] = b;
        bcur[tid] = b;
    }
    if (tid == 0) bbase[NBK] = E;
}

// ---- dis = rowcnt>0 ? rsqrt(rowcnt) : 0 ----
__global__ void k_dis(const int* __restrict__ rowcnt, float* __restrict__ dis, int N) {
    int i = blockIdx.x * blockDim.x + threadIdx.x;
    if (i < N) {
        int d = rowcnt[i];
        dis[i] = (d > 0) ? rsqrtf((float)d) : 0.0f;
    }
}

// ---- pass 3: bucket-scatter edges as int2, chunk-reserved (1 atomic per block-bucket) ----
__global__ __launch_bounds__(NT) void k_bscatter(const int* __restrict__ row,
                                                 const int* __restrict__ col,
                                                 int* __restrict__ bcur,
                                                 int2* __restrict__ ebuck,
                                                 int E, int NBK, int epb) {
    __shared__ int lh[512];
    __shared__ int lbase[512];
    int tid = threadIdx.x;
    for (int i = tid; i < NBK; i += NT) lh[i] = 0;
    __syncthreads();
    int start = blockIdx.x * epb;
    int end = min(start + epb, E);
    for (int e = start + tid; e < end; e += NT) atomicAdd(&lh[col[e] >> BSHIFT], 1);
    __syncthreads();
    for (int i = tid; i < NBK; i += NT) {
        int v = lh[i];
        lbase[i] = v ? atomicAdd(&bcur[i], v) : 0;
        lh[i] = 0;
    }
    __syncthreads();
    for (int e = start + tid; e < end; e += NT) {
        int c = col[e];
        int b = c >> BSHIFT;
        int li = atomicAdd(&lh[b], 1);  // LDS
        ebuck[lbase[b] + li] = make_int2(row[e], c);
    }
}

// ---- pass 4: per-bucket local counting sort -> offs + entries (coalesced region) ----
__global__ __launch_bounds__(NT) void k_bcsr(const int* __restrict__ bbase,
                                             const int2* __restrict__ ebuck,
                                             int* __restrict__ offs,
                                             int* __restrict__ entries,
                                             int N, int E, int NBK) {
    __shared__ int cnt[BSIZE];
    __shared__ int excl[BSIZE];
    int b = blockIdx.x, tid = threadIdx.x;
    int base = bbase[b], endr = bbase[b + 1];
    cnt[tid] = 0;
    __syncthreads();
    for (int e = base + tid; e < endr; e += NT)
        atomicAdd(&cnt[ebuck[e].y & (BSIZE - 1)], 1);  // LDS
    __syncthreads();
    int v = cnt[tid];
    excl[tid] = v;
    __syncthreads();
    for (int off = 1; off < BSIZE; off <<= 1) {
        int t = (tid >= off) ? excl[tid - off] : 0;
        __syncthreads();
        excl[tid] += t;
        __syncthreads();
    }
    int ex = excl[tid] - v;  // exclusive prefix
    int node = (b << BSHIFT) + tid;
    if (node < N) offs[node] = base + ex;
    cnt[tid] = ex;  // reuse as cursor
    __syncthreads();
    for (int e = base + tid; e < endr; e += NT) {
        int2 rc = ebuck[e];
        int li = atomicAdd(&cnt[rc.y & (BSIZE - 1)], 1);  // LDS
        entries[base + li] = rc.x;
    }
    if (b == 0 && tid == 0) offs[N] = E;
}

// ---- gather prop: dst[c] = -dis[c] * sum_{e in in(c)} dis[r_e] * src[r_e] ----
__global__ __launch_bounds__(NT) void k_prop_g(const int* __restrict__ offs,
                                               const int* __restrict__ entries,
                                               const float* __restrict__ dis,
                                               const float* __restrict__ src,
                                               float* __restrict__ dst, int N) {
    int idx = blockIdx.x * blockDim.x + threadIdx.x;
    int node = idx >> 2, q = idx & 3;
    if (node >= N) return;
    int s = offs[node], t = offs[node + 1];
    float a0x = 0, a0y = 0, a0z = 0, a0w = 0;
    float a1x = 0, a1y = 0, a1z = 0, a1w = 0;
    for (int e = s; e < t; e++) {
        int r = entries[e];
        float w = dis[r];
        const float4* p = (const float4*)(src + (size_t)r * 32 + q * 8);
        float4 v0 = p[0];
        float4 v1 = p[1];
        a0x += w * v0.x; a0y += w * v0.y; a0z += w * v0.z; a0w += w * v0.w;
        a1x += w * v1.x; a1y += w * v1.y; a1z += w * v1.z; a1w += w * v1.w;
    }
    float sc = -dis[node];
    float4 o0 = {sc * a0x, sc * a0y, sc * a0z, sc * a0w};
    float4 o1 = {sc * a1x, sc * a1y, sc * a1z, sc * a1w};
    float4* d = (float4*)(dst + (size_t)node * 32 + q * 8);
    d[0] = o0;
    d[1] = o1;
}

// ---- init pooled max to -inf ----
__global__ void k_ginit(float* __restrict__ g) {
    int i = blockIdx.x * blockDim.x + threadIdx.x;
    if (i < 64 * 32) g[i] = -__builtin_inff();
}

// ---- fused: h = x@W0 + Tx1@W1 + (2*P2 - x)@W2 + b ; block-segmented max -> atomicMax ----
__global__ __launch_bounds__(NT) void k_combine(
    const float* __restrict__ x, const float* __restrict__ tx1, const float* __restrict__ p2,
    const float* __restrict__ Wc, const float* __restrict__ bc,
    const int* __restrict__ batch, float* __restrict__ g, int N) {
    __shared__ float sW[3 * 32 * 32];
    __shared__ float sb[32];
    __shared__ float sx[8][32], s1[8][32], s2[8][32], sval[8][32];
    __shared__ int sbatch[8];

    int tid = threadIdx.x;
    for (int i = tid; i < 3072; i += NT) sW[i] = Wc[i];
    if (tid < 32) sb[tid] = bc[tid];

    int ty = tid >> 5, f = tid & 31;
    int r = blockIdx.x * 8 + ty;
    if (r < N) {
        sx[ty][f] = x[(size_t)r * 32 + f];
        s1[ty][f] = tx1[(size_t)r * 32 + f];
        s2[ty][f] = p2[(size_t)r * 32 + f];
        if (f == 0) sbatch[ty] = batch[r];
    } else if (f == 0) {
        sbatch[ty] = -1;
    }
    __syncthreads();

    float acc = sb[f];
    if (r < N) {
        for (int k = 0; k < 32; k++) {
            float t0 = sx[ty][k];
            float t1 = s1[ty][k];
            float t2 = 2.0f * s2[ty][k] - t0;
            acc += t0 * sW[k * 32 + f] + t1 * sW[1024 + k * 32 + f] + t2 * sW[2048 + k * 32 + f];
        }
    }
    sval[ty][f] = acc;
    __syncthreads();

    if (ty == 0) {
        int curb = -1;
        float curm = 0.0f;
        for (int j = 0; j < 8; j++) {
            int b = sbatch[j];
            if (b < 0) continue;
            if (b != curb) {
                if (curb >= 0) atomicMaxFloat(&g[curb * 32 + f], curm);
                curb = b;
                curm = sval[j][f];
            } else {
                curm = fmaxf(curm, sval[j][f]);
            }
        }
        if (curb >= 0) atomicMaxFloat(&g[curb * 32 + f], curm);
    }
}

// ---- MLP layers ----
__global__ void k_mlp1(const float* __restrict__ g, const float* __restrict__ W1,
                       const float* __restrict__ b1, float* __restrict__ h1) {
    __shared__ float sg[64 * 32];
    int tid = threadIdx.x;
    for (int i = tid; i < 64 * 32; i += NT) sg[i] = g[i];
    __syncthreads();
    int idx = blockIdx.x * NT + tid;
    int gi = idx >> 10, j = idx & 1023;
    float acc = b1[j];
    for (int k = 0; k < 32; k++) acc += sg[gi * 32 + k] * W1[k * 1024 + j];
    h1[idx] = fmaxf(acc, 0.0f);
}

__global__ void k_mlp2(const float* __restrict__ h1, const float* __restrict__ W2,
                       const float* __restrict__ b2, float* __restrict__ h2) {
    __shared__ float sh[1024];
    int gi = blockIdx.x, tid = threadIdx.x;
    for (int i = tid; i < 1024; i += NT) sh[i] = h1[gi * 1024 + i];
    __syncthreads();
    for (int j = tid; j < 512; j += NT) {
        float acc = b2[j];
        for (int k = 0; k < 1024; k++) acc += sh[k] * W2[k * 512 + j];
        h2[gi * 512 + j] = fmaxf(acc, 0.0f);
    }
}

__global__ void k_mlp3(const float* __restrict__ h2, const float* __restrict__ W3,
                       const float* __restrict__ b3, float* __restrict__ out) {
    int tid = threadIdx.x;  // 256 = 64*4
    int gi = tid >> 2, j = tid & 3;
    float acc = b3[j];
    for (int k = 0; k < 512; k++) acc += h2[gi * 512 + k] * W3[k * 4 + j];
    out[tid] = acc;
}

extern "C" void kernel_launch(void* const* d_in, const int* in_sizes, int n_in,
                              void* d_out, int out_size, void* d_ws, size_t ws_size,
                              hipStream_t stream) {
    const float* x   = (const float*)d_in[0];
    const int* ei    = (const int*)d_in[1];
    const int* batch = (const int*)d_in[2];
    const float* Wc  = (const float*)d_in[3];
    const float* bc  = (const float*)d_in[4];
    const float* W1  = (const float*)d_in[5];
    const float* b1  = (const float*)d_in[6];
    const float* W2  = (const float*)d_in[7];
    const float* b2  = (const float*)d_in[8];
    const float* W3  = (const float*)d_in[9];
    const float* b3  = (const float*)d_in[10];
    float* out       = (float*)d_out;

    const int N = in_sizes[2];      // 100000
    const int E = in_sizes[1] / 2;  // 1.6M
    const int* row = ei;
    const int* col = ei + E;
    const int NBK = (N + BSIZE - 1) / BSIZE;   // 391 (<= 512)
    const int HB = 256;                        // blocks for hist/scatter passes
    const int epb = (E + HB - 1) / HB;

    // workspace layout
    int* iws = (int*)d_ws;
    int* rowcnt  = iws;                         // N      (memset with bhist)
    int* bhist   = rowcnt + N;                  // 512
    int* bbase   = bhist + 512;                 // NBK+1 (pad 512)
    int* bcur    = bbase + 512;                 // 512
    int* offs    = bcur + 512;                  // N+4
    float* dis   = (float*)(offs + N + 4);      // N
    int* entries = (int*)(dis + N);             // E
    float* tx1   = (float*)(entries + E);       // 32N
    float* p2    = tx1 + (size_t)N * 32;        // 32N  -- aliased with ebuck
    int2* ebuck  = (int2*)p2;                   // E int2 (dead before p2 written)
    size_t p2_f  = (size_t)N * 32;
    size_t eb_f  = (size_t)E * 2;
    float* g     = p2 + (p2_f > eb_f ? p2_f : eb_f);  // 64*32
    float* h1    = g + 64 * 32;                 // 64*1024
    float* h2    = h1 + 64 * 1024;              // 64*512

    hipMemsetAsync(rowcnt, 0, sizeof(int) * ((size_t)N + 512), stream);

    k_hist2<<<HB, NT, 0, stream>>>(row, col, rowcnt, bhist, E, NBK, epb);
    k_bscan<<<1, 512, 0, stream>>>(bhist, bbase, bcur, NBK, E);
    k_dis<<<(N + NT - 1) / NT, NT, 0, stream>>>(rowcnt, dis, N);
    k_bscatter<<<HB, NT, 0, stream>>>(row, col, bcur, ebuck, E, NBK, epb);
    k_bcsr<<<NBK, NT, 0, stream>>>(bbase, ebuck, offs, entries, N, E, NBK);
    k_prop_g<<<((size_t)N * 4 + NT - 1) / NT, NT, 0, stream>>>(offs, entries, dis, x, tx1, N);
    k_prop_g<<<((size_t)N * 4 + NT - 1) / NT, NT, 0, stream>>>(offs, entries, dis, tx1, p2, N);
    k_ginit<<<8, NT, 0, stream>>>(g);
    k_combine<<<(N + 7) / 8, NT, 0, stream>>>(x, tx1, p2, Wc, bc, batch, g, N);
    k_mlp1<<<256, NT, 0, stream>>>(g, W1, b1, h1);
    k_mlp2<<<64, NT, 0, stream>>>(h1, W2, b2, h2);
    k_mlp3<<<1, NT, 0, stream>>>(h2, W3, b3, out);
}

// Round 7
// 390.762 us; speedup vs baseline: 4.0912x; 1.0970x over previous
//
#include <hip/hip_runtime.h>

// GCN1: ChebConv(K=3) -> global max pool -> MLP(32->1024->512->4)
// fp32 floats, int32 indices (established rounds 0-3).
// Round 7: (a) k_mlp2 was 72us at 2.7% occupancy (64 blocks, serial K=1024)
// -> K-split 512-block version with atomic accumulate, bias+relu folded into
// mlp3. (b) CSR entries annotated with dis[src] at build time so both props
// skip the random 4B dis gather (1.6M wasted sectors per prop).

#define NT 256
#define BSHIFT 8
#define BSIZE 256   // nodes per bucket; NBK = ceil(N/256) = 391 <= 512

__device__ __forceinline__ void atomicMaxFloat(float* addr, float val) {
    if (val >= 0.0f) atomicMax((int*)addr, __float_as_int(val));
    else             atomicMin((unsigned int*)addr, __float_as_uint(val));
}

// ---- pass 1: rowcnt histogram (global atomics) + LDS bucket histogram of col ----
__global__ __launch_bounds__(NT) void k_hist2(const int* __restrict__ row,
                                              const int* __restrict__ col,
                                              int* __restrict__ rowcnt,
                                              int* __restrict__ bhist,
                                              int E, int NBK, int epb) {
    __shared__ int lh[512];
    int tid = threadIdx.x;
    for (int i = tid; i < NBK; i += NT) lh[i] = 0;
    __syncthreads();
    int start = blockIdx.x * epb;
    int end = min(start + epb, E);
    for (int e = start + tid; e < end; e += NT) {
        atomicAdd(&rowcnt[row[e]], 1);
        atomicAdd(&lh[col[e] >> BSHIFT], 1);
    }
    __syncthreads();
    for (int i = tid; i < NBK; i += NT) {
        int v = lh[i];
        if (v) atomicAdd(&bhist[i], v);
    }
}

// ---- pass 2: exclusive scan of bucket counts (one block) ----
__global__ __launch_bounds__(512) void k_bscan(const int* __restrict__ bhist,
                                               int* __restrict__ bbase,
                                               int* __restrict__ bcur, int NBK, int E) {
    __shared__ int s[512];
    int tid = threadIdx.x;
    int v = (tid < NBK) ? bhist[tid] : 0;
    s[tid] = v;
    __syncthreads();
    for (int off = 1; off < 512; off <<= 1) {
        int t = (tid >= off) ? s[tid - off] : 0;
        __syncthreads();
        s[tid] += t;
        __syncthreads();
    }
    if (tid < NBK) {
        int b = s[tid] - v;
        bbase[tid] = b;
        bcur[tid] = b;
    }
    if (tid == 0) bbase[NBK] = E;
}

// ---- dis = rowcnt>0 ? rsqrt(rowcnt) : 0 ----
__global__ void k_dis(const int* __restrict__ rowcnt, float* __restrict__ dis, int N) {
    int i = blockIdx.x * blockDim.x + threadIdx.x;
    if (i < N) {
        int d = rowcnt[i];
        dis[i] = (d > 0) ? rsqrtf((float)d) : 0.0f;
    }
}

// ---- pass 3: bucket-scatter edges as int2, chunk-reserved (1 atomic per block-bucket) ----
__global__ __launch_bounds__(NT) void k_bscatter(const int* __restrict__ row,
                                                 const int* __restrict__ col,
                                                 int* __restrict__ bcur,
                                                 int2* __restrict__ ebuck,
                                                 int E, int NBK, int epb) {
    __shared__ int lh[512];
    __shared__ int lbase[512];
    int tid = threadIdx.x;
    for (int i = tid; i < NBK; i += NT) lh[i] = 0;
    __syncthreads();
    int start = blockIdx.x * epb;
    int end = min(start + epb, E);
    for (int e = start + tid; e < end; e += NT) atomicAdd(&lh[col[e] >> BSHIFT], 1);
    __syncthreads();
    for (int i = tid; i < NBK; i += NT) {
        int v = lh[i];
        lbase[i] = v ? atomicAdd(&bcur[i], v) : 0;
        lh[i] = 0;
    }
    __syncthreads();
    for (int e = start + tid; e < end; e += NT) {
        int c = col[e];
        int b = c >> BSHIFT;
        int li = atomicAdd(&lh[b], 1);  // LDS
        ebuck[lbase[b] + li] = make_int2(row[e], c);
    }
}

// ---- pass 4: per-bucket counting sort -> offs + weight-annotated entries ----
__global__ __launch_bounds__(NT) void k_bcsr(const int* __restrict__ bbase,
                                             const int2* __restrict__ ebuck,
                                             const float* __restrict__ dis,
                                             int* __restrict__ offs,
                                             int2* __restrict__ entries2,
                                             int N, int E, int NBK) {
    __shared__ int cnt[BSIZE];
    __shared__ int excl[BSIZE];
    int b = blockIdx.x, tid = threadIdx.x;
    int base = bbase[b], endr = bbase[b + 1];
    cnt[tid] = 0;
    __syncthreads();
    for (int e = base + tid; e < endr; e += NT)
        atomicAdd(&cnt[ebuck[e].y & (BSIZE - 1)], 1);  // LDS
    __syncthreads();
    int v = cnt[tid];
    excl[tid] = v;
    __syncthreads();
    for (int off = 1; off < BSIZE; off <<= 1) {
        int t = (tid >= off) ? excl[tid - off] : 0;
        __syncthreads();
        excl[tid] += t;
        __syncthreads();
    }
    int ex = excl[tid] - v;  // exclusive prefix
    int node = (b << BSHIFT) + tid;
    if (node < N) offs[node] = base + ex;
    cnt[tid] = ex;  // reuse as cursor
    __syncthreads();
    for (int e = base + tid; e < endr; e += NT) {
        int2 rc = ebuck[e];
        int li = atomicAdd(&cnt[rc.y & (BSIZE - 1)], 1);  // LDS
        entries2[base + li] = make_int2(rc.x, __float_as_int(dis[rc.x]));
    }
    if (b == 0 && tid == 0) offs[N] = E;
}

// ---- gather prop: dst[c] = -dis[c] * sum_{e in in(c)} w_e * src[r_e] ----
__global__ __launch_bounds__(NT) void k_prop_g(const int* __restrict__ offs,
                                               const int2* __restrict__ entries2,
                                               const float* __restrict__ dis,
                                               const float* __restrict__ src,
                                               float* __restrict__ dst, int N) {
    int idx = blockIdx.x * blockDim.x + threadIdx.x;
    int node = idx >> 2, q = idx & 3;
    if (node >= N) return;
    int s = offs[node], t = offs[node + 1];
    float a0x = 0, a0y = 0, a0z = 0, a0w = 0;
    float a1x = 0, a1y = 0, a1z = 0, a1w = 0;
    for (int e = s; e < t; e++) {
        int2 ew = entries2[e];
        float w = __int_as_float(ew.y);
        const float4* p = (const float4*)(src + (size_t)ew.x * 32 + q * 8);
        float4 v0 = p[0];
        float4 v1 = p[1];
        a0x += w * v0.x; a0y += w * v0.y; a0z += w * v0.z; a0w += w * v0.w;
        a1x += w * v1.x; a1y += w * v1.y; a1z += w * v1.z; a1w += w * v1.w;
    }
    float sc = -dis[node];
    float4 o0 = {sc * a0x, sc * a0y, sc * a0z, sc * a0w};
    float4 o1 = {sc * a1x, sc * a1y, sc * a1z, sc * a1w};
    float4* d = (float4*)(dst + (size_t)node * 32 + q * 8);
    d[0] = o0;
    d[1] = o1;
}

// ---- init pooled max to -inf ----
__global__ void k_ginit(float* __restrict__ g) {
    int i = blockIdx.x * blockDim.x + threadIdx.x;
    if (i < 64 * 32) g[i] = -__builtin_inff();
}

// ---- fused: h = x@W0 + Tx1@W1 + (2*P2 - x)@W2 + b ; block-segmented max -> atomicMax ----
__global__ __launch_bounds__(NT) void k_combine(
    const float* __restrict__ x, const float* __restrict__ tx1, const float* __restrict__ p2,
    const float* __restrict__ Wc, const float* __restrict__ bc,
    const int* __restrict__ batch, float* __restrict__ g, int N) {
    __shared__ float sW[3 * 32 * 32];
    __shared__ float sb[32];
    __shared__ float sx[8][32], s1[8][32], s2[8][32], sval[8][32];
    __shared__ int sbatch[8];

    int tid = threadIdx.x;
    for (int i = tid; i < 3072; i += NT) sW[i] = Wc[i];
    if (tid < 32) sb[tid] = bc[tid];

    int ty = tid >> 5, f = tid & 31;
    int r = blockIdx.x * 8 + ty;
    if (r < N) {
        sx[ty][f] = x[(size_t)r * 32 + f];
        s1[ty][f] = tx1[(size_t)r * 32 + f];
        s2[ty][f] = p2[(size_t)r * 32 + f];
        if (f == 0) sbatch[ty] = batch[r];
    } else if (f == 0) {
        sbatch[ty] = -1;
    }
    __syncthreads();

    float acc = sb[f];
    if (r < N) {
        for (int k = 0; k < 32; k++) {
            float t0 = sx[ty][k];
            float t1 = s1[ty][k];
            float t2 = 2.0f * s2[ty][k] - t0;
            acc += t0 * sW[k * 32 + f] + t1 * sW[1024 + k * 32 + f] + t2 * sW[2048 + k * 32 + f];
        }
    }
    sval[ty][f] = acc;
    __syncthreads();

    if (ty == 0) {
        int curb = -1;
        float curm = 0.0f;
        for (int j = 0; j < 8; j++) {
            int b = sbatch[j];
            if (b < 0) continue;
            if (b != curb) {
                if (curb >= 0) atomicMaxFloat(&g[curb * 32 + f], curm);
                curb = b;
                curm = sval[j][f];
            } else {
                curm = fmaxf(curm, sval[j][f]);
            }
        }
        if (curb >= 0) atomicMaxFloat(&g[curb * 32 + f], curm);
    }
}

// ---- MLP layer 1: h1[64,1024] = relu(g[64,32] @ W1 + b1) ----
__global__ void k_mlp1(const float* __restrict__ g, const float* __restrict__ W1,
                       const float* __restrict__ b1, float* __restrict__ h1) {
    __shared__ float sg[64 * 32];
    int tid = threadIdx.x;
    for (int i = tid; i < 64 * 32; i += NT) sg[i] = g[i];
    __syncthreads();
    int idx = blockIdx.x * NT + tid;
    int gi = idx >> 10, j = idx & 1023;
    float acc = b1[j];
    for (int k = 0; k < 32; k++) acc += sg[gi * 32 + k] * W1[k * 1024 + j];
    h1[idx] = fmaxf(acc, 0.0f);
}

// ---- MLP layer 2, K-split: h2acc[64,512] += h1[:,ks*128:+128] @ W2[ks*128:+128,:] ----
// grid = 64 graphs * 8 K-chunks; h2acc pre-zeroed; bias+relu applied in mlp3.
__global__ __launch_bounds__(NT) void k_mlp2s(const float* __restrict__ h1,
                                              const float* __restrict__ W2,
                                              float* __restrict__ h2acc) {
    __shared__ float sh[128];
    int gi = blockIdx.x >> 3, ks = blockIdx.x & 7;
    int tid = threadIdx.x;
    if (tid < 128) sh[tid] = h1[gi * 1024 + ks * 128 + tid];
    __syncthreads();
    const float* w = W2 + (size_t)(ks * 128) * 512;
    float acc0 = 0.0f, acc1 = 0.0f;
    for (int k = 0; k < 128; k++) {
        float h = sh[k];
        acc0 += h * w[k * 512 + tid];
        acc1 += h * w[k * 512 + tid + 256];
    }
    atomicAdd(&h2acc[gi * 512 + tid], acc0);
    atomicAdd(&h2acc[gi * 512 + tid + 256], acc1);
}

// ---- MLP layer 3: out[64,4] = relu(h2acc + b2) @ W3 + b3 ----
__global__ void k_mlp3(const float* __restrict__ h2acc, const float* __restrict__ b2,
                       const float* __restrict__ W3, const float* __restrict__ b3,
                       float* __restrict__ out) {
    int tid = threadIdx.x;  // 256 = 64*4
    int gi = tid >> 2, j = tid & 3;
    float acc = b3[j];
    for (int k = 0; k < 512; k++) {
        float h = fmaxf(h2acc[gi * 512 + k] + b2[k], 0.0f);
        acc += h * W3[k * 4 + j];
    }
    out[tid] = acc;
}

extern "C" void kernel_launch(void* const* d_in, const int* in_sizes, int n_in,
                              void* d_out, int out_size, void* d_ws, size_t ws_size,
                              hipStream_t stream) {
    const float* x   = (const float*)d_in[0];
    const int* ei    = (const int*)d_in[1];
    const int* batch = (const int*)d_in[2];
    const float* Wc  = (const float*)d_in[3];
    const float* bc  = (const float*)d_in[4];
    const float* W1  = (const float*)d_in[5];
    const float* b1  = (const float*)d_in[6];
    const float* W2  = (const float*)d_in[7];
    const float* b2  = (const float*)d_in[8];
    const float* W3  = (const float*)d_in[9];
    const float* b3  = (const float*)d_in[10];
    float* out       = (float*)d_out;

    const int N = in_sizes[2];      // 100000
    const int E = in_sizes[1] / 2;  // 1.6M
    const int* row = ei;
    const int* col = ei + E;
    const int NBK = (N + BSIZE - 1) / BSIZE;   // 391 (<= 512)
    const int HB = 256;
    const int epb = (E + HB - 1) / HB;

    // workspace layout (zeroed region first: rowcnt | bhist | h2acc)
    int* iws = (int*)d_ws;
    int* rowcnt   = iws;                          // N
    int* bhist    = rowcnt + N;                   // 512
    float* h2acc  = (float*)(bhist + 512);        // 64*512 = 32768
    int* bbase    = (int*)(h2acc + 64 * 512);     // NBK+1 (pad 512)
    int* bcur     = bbase + 512;                  // 512
    int* offs     = bcur + 512;                   // N+4
    float* dis    = (float*)(offs + N + 4);       // N
    int2* entries2 = (int2*)(dis + N);            // E int2 (offset is 8B-aligned)
    float* tx1    = (float*)(entries2 + E);       // 32N
    float* p2     = tx1 + (size_t)N * 32;         // 32N  -- aliased with ebuck
    int2* ebuck   = (int2*)p2;                    // E int2 (dead before p2 written)
    size_t p2_f   = (size_t)N * 32;
    size_t eb_f   = (size_t)E * 2;
    float* g      = p2 + (p2_f > eb_f ? p2_f : eb_f);  // 64*32
    float* h1     = g + 64 * 32;                  // 64*1024

    // one contiguous zero: rowcnt + bhist + h2acc
    hipMemsetAsync(rowcnt, 0, sizeof(int) * ((size_t)N + 512 + 64 * 512), stream);

    k_hist2<<<HB, NT, 0, stream>>>(row, col, rowcnt, bhist, E, NBK, epb);
    k_bscan<<<1, 512, 0, stream>>>(bhist, bbase, bcur, NBK, E);
    k_dis<<<(N + NT - 1) / NT, NT, 0, stream>>>(rowcnt, dis, N);
    k_bscatter<<<HB, NT, 0, stream>>>(row, col, bcur, ebuck, E, NBK, epb);
    k_bcsr<<<NBK, NT, 0, stream>>>(bbase, ebuck, dis, offs, entries2, N, E, NBK);
    k_prop_g<<<((size_t)N * 4 + NT - 1) / NT, NT, 0, stream>>>(offs, entries2, dis, x, tx1, N);
    k_prop_g<<<((size_t)N * 4 + NT - 1) / NT, NT, 0, stream>>>(offs, entries2, dis, tx1, p2, N);
    k_ginit<<<8, NT, 0, stream>>>(g);
    k_combine<<<(N + 7) / 8, NT, 0, stream>>>(x, tx1, p2, Wc, bc, batch, g, N);
    k_mlp1<<<256, NT, 0, stream>>>(g, W1, b1, h1);
    k_mlp2s<<<512, NT, 0, stream>>>(h1, W2, h2acc);
    k_mlp3<<<1, NT, 0, stream>>>(h2acc, b2, W3, b3, out);
}

// Round 8
// 354.785 us; speedup vs baseline: 4.5061x; 1.1014x over previous
//
#include <hip/hip_runtime.h>

// GCN1: ChebConv(K=3) -> global max pool -> MLP(32->1024->512->4)
// fp32 floats, int32 indices (established rounds 0-3).
// Round 8: kill the last per-edge global atomics. Round-7 k_hist2 spent 70us
// writing 50MB (1.6M rowcnt atomics x 32B write-through). Now: LDS bucket
// histograms for BOTH row and col, per-block counts staged to global so the
// scatter is single-pass, and out-degree counted bucket-locally (k_rcsr,
// which also produces dis directly — k_dis removed).

#define NT 256
#define BSHIFT 8
#define BSIZE 256   // nodes per bucket; NBK = ceil(N/256) = 391 <= 512
#define HB 256      // blocks for hist/scatter passes

__device__ __forceinline__ void atomicMaxFloat(float* addr, float val) {
    if (val >= 0.0f) atomicMax((int*)addr, __float_as_int(val));
    else             atomicMin((unsigned int*)addr, __float_as_uint(val));
}

// ---- pass 1: LDS bucket histograms of row and col; per-block counts to global ----
__global__ __launch_bounds__(NT) void k_hist2(const int* __restrict__ row,
                                              const int* __restrict__ col,
                                              int* __restrict__ bhc, int* __restrict__ bhr,
                                              int* __restrict__ blkc, int* __restrict__ blkr,
                                              int E, int NBK, int epb) {
    __shared__ int lhc[512], lhr[512];
    int tid = threadIdx.x;
    for (int i = tid; i < 512; i += NT) { lhc[i] = 0; lhr[i] = 0; }
    __syncthreads();
    int start = blockIdx.x * epb;
    int end = min(start + epb, E);
    for (int e = start + tid; e < end; e += NT) {
        atomicAdd(&lhr[row[e] >> BSHIFT], 1);  // LDS
        atomicAdd(&lhc[col[e] >> BSHIFT], 1);  // LDS
    }
    __syncthreads();
    int base = blockIdx.x * 512;
    for (int i = tid; i < NBK; i += NT) {
        int vc = lhc[i], vr = lhr[i];
        blkc[base + i] = vc;
        blkr[base + i] = vr;
        if (vc) atomicAdd(&bhc[i], vc);
        if (vr) atomicAdd(&bhr[i], vr);
    }
}

// ---- pass 2: exclusive scans of both bucket histograms (one block) ----
__global__ __launch_bounds__(512) void k_bscan2(const int* __restrict__ bhc,
                                                const int* __restrict__ bhr,
                                                int* __restrict__ bbase, int* __restrict__ bcur,
                                                int* __restrict__ rbase, int* __restrict__ rcur,
                                                int NBK, int E) {
    __shared__ int s[512];
    int tid = threadIdx.x;
    // col side
    int v = (tid < NBK) ? bhc[tid] : 0;
    s[tid] = v;
    __syncthreads();
    for (int off = 1; off < 512; off <<= 1) {
        int t = (tid >= off) ? s[tid - off] : 0;
        __syncthreads();
        s[tid] += t;
        __syncthreads();
    }
    if (tid < NBK) { int b = s[tid] - v; bbase[tid] = b; bcur[tid] = b; }
    if (tid == 0) bbase[NBK] = E;
    __syncthreads();
    // row side
    v = (tid < NBK) ? bhr[tid] : 0;
    s[tid] = v;
    __syncthreads();
    for (int off = 1; off < 512; off <<= 1) {
        int t = (tid >= off) ? s[tid - off] : 0;
        __syncthreads();
        s[tid] += t;
        __syncthreads();
    }
    if (tid < NBK) { int b = s[tid] - v; rbase[tid] = b; rcur[tid] = b; }
    if (tid == 0) rbase[NBK] = E;
}

// ---- pass 3: single-pass dual scatter (col->ebuck int2, row->rbuck int) ----
__global__ __launch_bounds__(NT) void k_bscatter2(const int* __restrict__ row,
                                                  const int* __restrict__ col,
                                                  const int* __restrict__ blkc,
                                                  const int* __restrict__ blkr,
                                                  int* __restrict__ bcur, int* __restrict__ rcur,
                                                  int2* __restrict__ ebuck, int* __restrict__ rbuck,
                                                  int E, int NBK, int epb) {
    __shared__ int lbasec[512], lbaser[512], lhc[512], lhr[512];
    int tid = threadIdx.x;
    int base = blockIdx.x * 512;
    for (int i = tid; i < NBK; i += NT) {
        int vc = blkc[base + i];
        int vr = blkr[base + i];
        lbasec[i] = vc ? atomicAdd(&bcur[i], vc) : 0;
        lbaser[i] = vr ? atomicAdd(&rcur[i], vr) : 0;
        lhc[i] = 0;
        lhr[i] = 0;
    }
    __syncthreads();
    int start = blockIdx.x * epb;
    int end = min(start + epb, E);
    for (int e = start + tid; e < end; e += NT) {
        int r = row[e], c = col[e];
        int bc_ = c >> BSHIFT;
        int li = atomicAdd(&lhc[bc_], 1);  // LDS
        ebuck[lbasec[bc_] + li] = make_int2(r, c);
        int br_ = r >> BSHIFT;
        int lj = atomicAdd(&lhr[br_], 1);  // LDS
        rbuck[lbaser[br_] + lj] = r;
    }
}

// ---- pass 4a: per-row-bucket count -> dis = rsqrt(outdeg) ----
__global__ __launch_bounds__(NT) void k_rcsr(const int* __restrict__ rbase,
                                             const int* __restrict__ rbuck,
                                             float* __restrict__ dis, int N) {
    __shared__ int cnt[BSIZE];
    int b = blockIdx.x, tid = threadIdx.x;
    int base = rbase[b], endr = rbase[b + 1];
    cnt[tid] = 0;
    __syncthreads();
    for (int e = base + tid; e < endr; e += NT)
        atomicAdd(&cnt[rbuck[e] & (BSIZE - 1)], 1);  // LDS
    __syncthreads();
    int node = (b << BSHIFT) + tid;
    if (node < N) {
        int d = cnt[tid];
        dis[node] = (d > 0) ? rsqrtf((float)d) : 0.0f;
    }
}

// ---- pass 4b: per-col-bucket counting sort -> offs + weight-annotated entries ----
__global__ __launch_bounds__(NT) void k_bcsr(const int* __restrict__ bbase,
                                             const int2* __restrict__ ebuck,
                                             const float* __restrict__ dis,
                                             int* __restrict__ offs,
                                             int2* __restrict__ entries2,
                                             int N, int E, int NBK) {
    __shared__ int cnt[BSIZE];
    __shared__ int excl[BSIZE];
    int b = blockIdx.x, tid = threadIdx.x;
    int base = bbase[b], endr = bbase[b + 1];
    cnt[tid] = 0;
    __syncthreads();
    for (int e = base + tid; e < endr; e += NT)
        atomicAdd(&cnt[ebuck[e].y & (BSIZE - 1)], 1);  // LDS
    __syncthreads();
    int v = cnt[tid];
    excl[tid] = v;
    __syncthreads();
    for (int off = 1; off < BSIZE; off <<= 1) {
        int t = (tid >= off) ? excl[tid - off] : 0;
        __syncthreads();
        excl[tid] += t;
        __syncthreads();
    }
    int ex = excl[tid] - v;  // exclusive prefix
    int node = (b << BSHIFT) + tid;
    if (node < N) offs[node] = base + ex;
    cnt[tid] = ex;  // reuse as cursor
    __syncthreads();
    for (int e = base + tid; e < endr; e += NT) {
        int2 rc = ebuck[e];
        int li = atomicAdd(&cnt[rc.y & (BSIZE - 1)], 1);  // LDS
        entries2[base + li] = make_int2(rc.x, __float_as_int(dis[rc.x]));
    }
    if (b == 0 && tid == 0) offs[N] = E;
}

// ---- gather prop: dst[c] = -dis[c] * sum_{e in in(c)} w_e * src[r_e] ----
__global__ __launch_bounds__(NT) void k_prop_g(const int* __restrict__ offs,
                                               const int2* __restrict__ entries2,
                                               const float* __restrict__ dis,
                                               const float* __restrict__ src,
                                               float* __restrict__ dst, int N) {
    int idx = blockIdx.x * blockDim.x + threadIdx.x;
    int node = idx >> 2, q = idx & 3;
    if (node >= N) return;
    int s = offs[node], t = offs[node + 1];
    float a0x = 0, a0y = 0, a0z = 0, a0w = 0;
    float a1x = 0, a1y = 0, a1z = 0, a1w = 0;
    for (int e = s; e < t; e++) {
        int2 ew = entries2[e];
        float w = __int_as_float(ew.y);
        const float4* p = (const float4*)(src + (size_t)ew.x * 32 + q * 8);
        float4 v0 = p[0];
        float4 v1 = p[1];
        a0x += w * v0.x; a0y += w * v0.y; a0z += w * v0.z; a0w += w * v0.w;
        a1x += w * v1.x; a1y += w * v1.y; a1z += w * v1.z; a1w += w * v1.w;
    }
    float sc = -dis[node];
    float4 o0 = {sc * a0x, sc * a0y, sc * a0z, sc * a0w};
    float4 o1 = {sc * a1x, sc * a1y, sc * a1z, sc * a1w};
    float4* d = (float4*)(dst + (size_t)node * 32 + q * 8);
    d[0] = o0;
    d[1] = o1;
}

// ---- init pooled max to -inf ----
__global__ void k_ginit(float* __restrict__ g) {
    int i = blockIdx.x * blockDim.x + threadIdx.x;
    if (i < 64 * 32) g[i] = -__builtin_inff();
}

// ---- fused: h = x@W0 + Tx1@W1 + (2*P2 - x)@W2 + b ; block-segmented max -> atomicMax ----
__global__ __launch_bounds__(NT) void k_combine(
    const float* __restrict__ x, const float* __restrict__ tx1, const float* __restrict__ p2,
    const float* __restrict__ Wc, const float* __restrict__ bc,
    const int* __restrict__ batch, float* __restrict__ g, int N) {
    __shared__ float sW[3 * 32 * 32];
    __shared__ float sb[32];
    __shared__ float sx[8][32], s1[8][32], s2[8][32], sval[8][32];
    __shared__ int sbatch[8];

    int tid = threadIdx.x;
    for (int i = tid; i < 3072; i += NT) sW[i] = Wc[i];
    if (tid < 32) sb[tid] = bc[tid];

    int ty = tid >> 5, f = tid & 31;
    int r = blockIdx.x * 8 + ty;
    if (r < N) {
        sx[ty][f] = x[(size_t)r * 32 + f];
        s1[ty][f] = tx1[(size_t)r * 32 + f];
        s2[ty][f] = p2[(size_t)r * 32 + f];
        if (f == 0) sbatch[ty] = batch[r];
    } else if (f == 0) {
        sbatch[ty] = -1;
    }
    __syncthreads();

    float acc = sb[f];
    if (r < N) {
        for (int k = 0; k < 32; k++) {
            float t0 = sx[ty][k];
            float t1 = s1[ty][k];
            float t2 = 2.0f * s2[ty][k] - t0;
            acc += t0 * sW[k * 32 + f] + t1 * sW[1024 + k * 32 + f] + t2 * sW[2048 + k * 32 + f];
        }
    }
    sval[ty][f] = acc;
    __syncthreads();

    if (ty == 0) {
        int curb = -1;
        float curm = 0.0f;
        for (int j = 0; j < 8; j++) {
            int b = sbatch[j];
            if (b < 0) continue;
            if (b != curb) {
                if (curb >= 0) atomicMaxFloat(&g[curb * 32 + f], curm);
                curb = b;
                curm = sval[j][f];
            } else {
                curm = fmaxf(curm, sval[j][f]);
            }
        }
        if (curb >= 0) atomicMaxFloat(&g[curb * 32 + f], curm);
    }
}

// ---- MLP layer 1: h1[64,1024] = relu(g[64,32] @ W1 + b1) ----
__global__ void k_mlp1(const float* __restrict__ g, const float* __restrict__ W1,
                       const float* __restrict__ b1, float* __restrict__ h1) {
    __shared__ float sg[64 * 32];
    int tid = threadIdx.x;
    for (int i = tid; i < 64 * 32; i += NT) sg[i] = g[i];
    __syncthreads();
    int idx = blockIdx.x * NT + tid;
    int gi = idx >> 10, j = idx & 1023;
    float acc = b1[j];
    for (int k = 0; k < 32; k++) acc += sg[gi * 32 + k] * W1[k * 1024 + j];
    h1[idx] = fmaxf(acc, 0.0f);
}

// ---- MLP layer 2, K-split: h2acc += h1-chunk @ W2-chunk; bias+relu in mlp3 ----
__global__ __launch_bounds__(NT) void k_mlp2s(const float* __restrict__ h1,
                                              const float* __restrict__ W2,
                                              float* __restrict__ h2acc) {
    __shared__ float sh[128];
    int gi = blockIdx.x >> 3, ks = blockIdx.x & 7;
    int tid = threadIdx.x;
    if (tid < 128) sh[tid] = h1[gi * 1024 + ks * 128 + tid];
    __syncthreads();
    const float* w = W2 + (size_t)(ks * 128) * 512;
    float acc0 = 0.0f, acc1 = 0.0f;
    for (int k = 0; k < 128; k++) {
        float h = sh[k];
        acc0 += h * w[k * 512 + tid];
        acc1 += h * w[k * 512 + tid + 256];
    }
    atomicAdd(&h2acc[gi * 512 + tid], acc0);
    atomicAdd(&h2acc[gi * 512 + tid + 256], acc1);
}

// ---- MLP layer 3: out[64,4] = relu(h2acc + b2) @ W3 + b3 ----
__global__ void k_mlp3(const float* __restrict__ h2acc, const float* __restrict__ b2,
                       const float* __restrict__ W3, const float* __restrict__ b3,
                       float* __restrict__ out) {
    int tid = threadIdx.x;  // 256 = 64*4
    int gi = tid >> 2, j = tid & 3;
    float acc = b3[j];
    for (int k = 0; k < 512; k++) {
        float h = fmaxf(h2acc[gi * 512 + k] + b2[k], 0.0f);
        acc += h * W3[k * 4 + j];
    }
    out[tid] = acc;
}

extern "C" void kernel_launch(void* const* d_in, const int* in_sizes, int n_in,
                              void* d_out, int out_size, void* d_ws, size_t ws_size,
                              hipStream_t stream) {
    const float* x   = (const float*)d_in[0];
    const int* ei    = (const int*)d_in[1];
    const int* batch = (const int*)d_in[2];
    const float* Wc  = (const float*)d_in[3];
    const float* bc  = (const float*)d_in[4];
    const float* W1  = (const float*)d_in[5];
    const float* b1  = (const float*)d_in[6];
    const float* W2  = (const float*)d_in[7];
    const float* b2  = (const float*)d_in[8];
    const float* W3  = (const float*)d_in[9];
    const float* b3  = (const float*)d_in[10];
    float* out       = (float*)d_out;

    const int N = in_sizes[2];      // 100000
    const int E = in_sizes[1] / 2;  // 1.6M
    const int* row = ei;
    const int* col = ei + E;
    const int NBK = (N + BSIZE - 1) / BSIZE;   // 391 (<= 512)
    const int epb = (E + HB - 1) / HB;

    // workspace layout (zeroed region first: bhc | bhr | h2acc)
    int* iws = (int*)d_ws;
    int* bhc       = iws;                          // 512
    int* bhr       = bhc + 512;                    // 512
    float* h2acc   = (float*)(bhr + 512);          // 64*512 = 32768
    int* bbase     = (int*)(h2acc + 64 * 512);     // 512 (NBK+1)
    int* bcur      = bbase + 512;                  // 512
    int* rbase     = bcur + 512;                   // 512 (NBK+1)
    int* rcur      = rbase + 512;                  // 512
    int* offs      = rcur + 512;                   // N+4
    float* dis     = (float*)(offs + N + 4);       // N
    int2* entries2 = (int2*)(dis + N);             // E int2
    int* blkc      = (int*)entries2;               // HB*512 (dead before k_bcsr writes entries2)
    int* blkr      = blkc + HB * 512;              // HB*512
    float* tx1     = (float*)(entries2 + E);       // 32N ; rbuck aliases (dead before prop1)
    int* rbuck     = (int*)tx1;                    // E ints
    float* p2      = tx1 + (size_t)N * 32;         // 32N ; ebuck aliases (dead before prop2)
    int2* ebuck    = (int2*)p2;                    // E int2
    float* g       = p2 + (size_t)N * 32;          // 64*32
    float* h1      = g + 64 * 32;                  // 64*1024

    // one contiguous zero: bhc + bhr + h2acc
    hipMemsetAsync(bhc, 0, sizeof(int) * (512 + 512 + 64 * 512), stream);

    k_hist2<<<HB, NT, 0, stream>>>(row, col, bhc, bhr, blkc, blkr, E, NBK, epb);
    k_bscan2<<<1, 512, 0, stream>>>(bhc, bhr, bbase, bcur, rbase, rcur, NBK, E);
    k_bscatter2<<<HB, NT, 0, stream>>>(row, col, blkc, blkr, bcur, rcur, ebuck, rbuck, E, NBK, epb);
    k_rcsr<<<NBK, NT, 0, stream>>>(rbase, rbuck, dis, N);
    k_bcsr<<<NBK, NT, 0, stream>>>(bbase, ebuck, dis, offs, entries2, N, E, NBK);
    k_prop_g<<<((size_t)N * 4 + NT - 1) / NT, NT, 0, stream>>>(offs, entries2, dis, x, tx1, N);
    k_prop_g<<<((size_t)N * 4 + NT - 1) / NT, NT, 0, stream>>>(offs, entries2, dis, tx1, p2, N);
    k_ginit<<<8, NT, 0, stream>>>(g);
    k_combine<<<(N + 7) / 8, NT, 0, stream>>>(x, tx1, p2, Wc, bc, batch, g, N);
    k_mlp1<<<256, NT, 0, stream>>>(g, W1, b1, h1);
    k_mlp2s<<<512, NT, 0, stream>>>(h1, W2, h2acc);
    k_mlp3<<<1, NT, 0, stream>>>(h2acc, b2, W3, b3, out);
}

// Round 10
// 339.350 us; speedup vs baseline: 4.7110x; 1.0455x over previous
//
#include <hip/hip_runtime.h>
#include <hip/hip_fp16.h>

// GCN1: ChebConv(K=3) -> global max pool -> MLP(32->1024->512->4)
// fp32 floats, int32 indices (established rounds 0-3).
// Round 9 (resubmitted round 10 after GPU-acquisition timeout): props are
// gather-BW bound (FETCH = 1.6M x 128B, ~0% L2 reuse). Store propagated
// features as fp16 -> 64B/row gathers, halving L2-miss traffic. fp16 rel
// err 0.05% vs 2% threshold.

#define NT 256
#define BSHIFT 8
#define BSIZE 256   // nodes per bucket; NBK = ceil(N/256) = 391 <= 512
#define HB 256      // blocks for hist/scatter passes

__device__ __forceinline__ void atomicMaxFloat(float* addr, float val) {
    if (val >= 0.0f) atomicMax((int*)addr, __float_as_int(val));
    else             atomicMin((unsigned int*)addr, __float_as_uint(val));
}

// ---- pass 1: LDS bucket histograms of row and col; per-block counts to global ----
__global__ __launch_bounds__(NT) void k_hist2(const int* __restrict__ row,
                                              const int* __restrict__ col,
                                              int* __restrict__ bhc, int* __restrict__ bhr,
                                              int* __restrict__ blkc, int* __restrict__ blkr,
                                              int E, int NBK, int epb) {
    __shared__ int lhc[512], lhr[512];
    int tid = threadIdx.x;
    for (int i = tid; i < 512; i += NT) { lhc[i] = 0; lhr[i] = 0; }
    __syncthreads();
    int start = blockIdx.x * epb;
    int end = min(start + epb, E);
    for (int e = start + tid; e < end; e += NT) {
        atomicAdd(&lhr[row[e] >> BSHIFT], 1);  // LDS
        atomicAdd(&lhc[col[e] >> BSHIFT], 1);  // LDS
    }
    __syncthreads();
    int base = blockIdx.x * 512;
    for (int i = tid; i < NBK; i += NT) {
        int vc = lhc[i], vr = lhr[i];
        blkc[base + i] = vc;
        blkr[base + i] = vr;
        if (vc) atomicAdd(&bhc[i], vc);
        if (vr) atomicAdd(&bhr[i], vr);
    }
}

// ---- pass 2: exclusive scans of both bucket histograms (one block) ----
__global__ __launch_bounds__(512) void k_bscan2(const int* __restrict__ bhc,
                                                const int* __restrict__ bhr,
                                                int* __restrict__ bbase, int* __restrict__ bcur,
                                                int* __restrict__ rbase, int* __restrict__ rcur,
                                                int NBK, int E) {
    __shared__ int s[512];
    int tid = threadIdx.x;
    int v = (tid < NBK) ? bhc[tid] : 0;
    s[tid] = v;
    __syncthreads();
    for (int off = 1; off < 512; off <<= 1) {
        int t = (tid >= off) ? s[tid - off] : 0;
        __syncthreads();
        s[tid] += t;
        __syncthreads();
    }
    if (tid < NBK) { int b = s[tid] - v; bbase[tid] = b; bcur[tid] = b; }
    if (tid == 0) bbase[NBK] = E;
    __syncthreads();
    v = (tid < NBK) ? bhr[tid] : 0;
    s[tid] = v;
    __syncthreads();
    for (int off = 1; off < 512; off <<= 1) {
        int t = (tid >= off) ? s[tid - off] : 0;
        __syncthreads();
        s[tid] += t;
        __syncthreads();
    }
    if (tid < NBK) { int b = s[tid] - v; rbase[tid] = b; rcur[tid] = b; }
    if (tid == 0) rbase[NBK] = E;
}

// ---- pass 3: single-pass dual scatter (col->ebuck int2, row->rbuck int) ----
__global__ __launch_bounds__(NT) void k_bscatter2(const int* __restrict__ row,
                                                  const int* __restrict__ col,
                                                  const int* __restrict__ blkc,
                                                  const int* __restrict__ blkr,
                                                  int* __restrict__ bcur, int* __restrict__ rcur,
                                                  int2* __restrict__ ebuck, int* __restrict__ rbuck,
                                                  int E, int NBK, int epb) {
    __shared__ int lbasec[512], lbaser[512], lhc[512], lhr[512];
    int tid = threadIdx.x;
    int base = blockIdx.x * 512;
    for (int i = tid; i < NBK; i += NT) {
        int vc = blkc[base + i];
        int vr = blkr[base + i];
        lbasec[i] = vc ? atomicAdd(&bcur[i], vc) : 0;
        lbaser[i] = vr ? atomicAdd(&rcur[i], vr) : 0;
        lhc[i] = 0;
        lhr[i] = 0;
    }
    __syncthreads();
    int start = blockIdx.x * epb;
    int end = min(start + epb, E);
    for (int e = start + tid; e < end; e += NT) {
        int r = row[e], c = col[e];
        int bc_ = c >> BSHIFT;
        int li = atomicAdd(&lhc[bc_], 1);  // LDS
        ebuck[lbasec[bc_] + li] = make_int2(r, c);
        int br_ = r >> BSHIFT;
        int lj = atomicAdd(&lhr[br_], 1);  // LDS
        rbuck[lbaser[br_] + lj] = r;
    }
}

// ---- pass 4a: per-row-bucket count -> dis = rsqrt(outdeg) ----
__global__ __launch_bounds__(NT) void k_rcsr(const int* __restrict__ rbase,
                                             const int* __restrict__ rbuck,
                                             float* __restrict__ dis, int N) {
    __shared__ int cnt[BSIZE];
    int b = blockIdx.x, tid = threadIdx.x;
    int base = rbase[b], endr = rbase[b + 1];
    cnt[tid] = 0;
    __syncthreads();
    for (int e = base + tid; e < endr; e += NT)
        atomicAdd(&cnt[rbuck[e] & (BSIZE - 1)], 1);  // LDS
    __syncthreads();
    int node = (b << BSHIFT) + tid;
    if (node < N) {
        int d = cnt[tid];
        dis[node] = (d > 0) ? rsqrtf((float)d) : 0.0f;
    }
}

// ---- pass 4b: per-col-bucket counting sort -> offs + weight-annotated entries ----
__global__ __launch_bounds__(NT) void k_bcsr(const int* __restrict__ bbase,
                                             const int2* __restrict__ ebuck,
                                             const float* __restrict__ dis,
                                             int* __restrict__ offs,
                                             int2* __restrict__ entries2,
                                             int N, int E, int NBK) {
    __shared__ int cnt[BSIZE];
    __shared__ int excl[BSIZE];
    int b = blockIdx.x, tid = threadIdx.x;
    int base = bbase[b], endr = bbase[b + 1];
    cnt[tid] = 0;
    __syncthreads();
    for (int e = base + tid; e < endr; e += NT)
        atomicAdd(&cnt[ebuck[e].y & (BSIZE - 1)], 1);  // LDS
    __syncthreads();
    int v = cnt[tid];
    excl[tid] = v;
    __syncthreads();
    for (int off = 1; off < BSIZE; off <<= 1) {
        int t = (tid >= off) ? excl[tid - off] : 0;
        __syncthreads();
        excl[tid] += t;
        __syncthreads();
    }
    int ex = excl[tid] - v;  // exclusive prefix
    int node = (b << BSHIFT) + tid;
    if (node < N) offs[node] = base + ex;
    cnt[tid] = ex;  // reuse as cursor
    __syncthreads();
    for (int e = base + tid; e < endr; e += NT) {
        int2 rc = ebuck[e];
        int li = atomicAdd(&cnt[rc.y & (BSIZE - 1)], 1);  // LDS
        entries2[base + li] = make_int2(rc.x, __float_as_int(dis[rc.x]));
    }
    if (b == 0 && tid == 0) offs[N] = E;
}

// ---- x (fp32) -> xh (fp16), 4 elems/thread ----
__global__ void k_xh(const float* __restrict__ x, __half* __restrict__ xh, int n4) {
    int i = blockIdx.x * blockDim.x + threadIdx.x;
    if (i < n4) {
        float4 v = ((const float4*)x)[i];
        float2 o;
        ((__half2*)&o)[0] = __floats2half2_rn(v.x, v.y);
        ((__half2*)&o)[1] = __floats2half2_rn(v.z, v.w);
        ((float2*)xh)[i] = o;
    }
}

// ---- gather prop (fp16 src): dst[c] = -dis[c] * sum w_e * src[r_e]
// mode 0: write dsth (fp16). mode 1: write dstf (fp32).
__global__ __launch_bounds__(NT) void k_prop_gh(const int* __restrict__ offs,
                                                const int2* __restrict__ entries2,
                                                const float* __restrict__ dis,
                                                const __half* __restrict__ src,
                                                __half* __restrict__ dsth,
                                                float* __restrict__ dstf,
                                                int N, int mode) {
    int idx = blockIdx.x * blockDim.x + threadIdx.x;
    int node = idx >> 2, q = idx & 3;
    if (node >= N) return;
    int s = offs[node], t = offs[node + 1];
    float a0 = 0, a1 = 0, a2 = 0, a3 = 0, a4 = 0, a5 = 0, a6 = 0, a7 = 0;
    for (int e = s; e < t; e++) {
        int2 ew = entries2[e];
        float w = __int_as_float(ew.y);
        float4 raw = *(const float4*)(src + (size_t)ew.x * 32 + q * 8);  // 8 halfs
        const __half2* hp = (const __half2*)&raw;
        float2 f0 = __half22float2(hp[0]);
        float2 f1 = __half22float2(hp[1]);
        float2 f2 = __half22float2(hp[2]);
        float2 f3 = __half22float2(hp[3]);
        a0 += w * f0.x; a1 += w * f0.y;
        a2 += w * f1.x; a3 += w * f1.y;
        a4 += w * f2.x; a5 += w * f2.y;
        a6 += w * f3.x; a7 += w * f3.y;
    }
    float sc = -dis[node];
    if (mode == 0) {
        float4 ov;
        ((__half2*)&ov)[0] = __floats2half2_rn(sc * a0, sc * a1);
        ((__half2*)&ov)[1] = __floats2half2_rn(sc * a2, sc * a3);
        ((__half2*)&ov)[2] = __floats2half2_rn(sc * a4, sc * a5);
        ((__half2*)&ov)[3] = __floats2half2_rn(sc * a6, sc * a7);
        *(float4*)(dsth + (size_t)node * 32 + q * 8) = ov;
    } else {
        float4 o0 = {sc * a0, sc * a1, sc * a2, sc * a3};
        float4 o1 = {sc * a4, sc * a5, sc * a6, sc * a7};
        float4* d = (float4*)(dstf + (size_t)node * 32 + q * 8);
        d[0] = o0;
        d[1] = o1;
    }
}

// ---- init pooled max to -inf ----
__global__ void k_ginit(float* __restrict__ g) {
    int i = blockIdx.x * blockDim.x + threadIdx.x;
    if (i < 64 * 32) g[i] = -__builtin_inff();
}

// ---- fused: h = x@W0 + Tx1@W1 + (2*P2 - x)@W2 + b ; block-segmented max -> atomicMax ----
__global__ __launch_bounds__(NT) void k_combine(
    const float* __restrict__ x, const __half* __restrict__ tx1h, const float* __restrict__ p2,
    const float* __restrict__ Wc, const float* __restrict__ bc,
    const int* __restrict__ batch, float* __restrict__ g, int N) {
    __shared__ float sW[3 * 32 * 32];
    __shared__ float sb[32];
    __shared__ float sx[8][32], s1[8][32], s2[8][32], sval[8][32];
    __shared__ int sbatch[8];

    int tid = threadIdx.x;
    for (int i = tid; i < 3072; i += NT) sW[i] = Wc[i];
    if (tid < 32) sb[tid] = bc[tid];

    int ty = tid >> 5, f = tid & 31;
    int r = blockIdx.x * 8 + ty;
    if (r < N) {
        sx[ty][f] = x[(size_t)r * 32 + f];
        s1[ty][f] = __half2float(tx1h[(size_t)r * 32 + f]);
        s2[ty][f] = p2[(size_t)r * 32 + f];
        if (f == 0) sbatch[ty] = batch[r];
    } else if (f == 0) {
        sbatch[ty] = -1;
    }
    __syncthreads();

    float acc = sb[f];
    if (r < N) {
        for (int k = 0; k < 32; k++) {
            float t0 = sx[ty][k];
            float t1 = s1[ty][k];
            float t2 = 2.0f * s2[ty][k] - t0;
            acc += t0 * sW[k * 32 + f] + t1 * sW[1024 + k * 32 + f] + t2 * sW[2048 + k * 32 + f];
        }
    }
    sval[ty][f] = acc;
    __syncthreads();

    if (ty == 0) {
        int curb = -1;
        float curm = 0.0f;
        for (int j = 0; j < 8; j++) {
            int b = sbatch[j];
            if (b < 0) continue;
            if (b != curb) {
                if (curb >= 0) atomicMaxFloat(&g[curb * 32 + f], curm);
                curb = b;
                curm = sval[j][f];
            } else {
                curm = fmaxf(curm, sval[j][f]);
            }
        }
        if (curb >= 0) atomicMaxFloat(&g[curb * 32 + f], curm);
    }
}

// ---- MLP layer 1: h1[64,1024] = relu(g[64,32] @ W1 + b1) ----
__global__ void k_mlp1(const float* __restrict__ g, const float* __restrict__ W1,
                       const float* __restrict__ b1, float* __restrict__ h1) {
    __shared__ float sg[64 * 32];
    int tid = threadIdx.x;
    for (int i = tid; i < 64 * 32; i += NT) sg[i] = g[i];
    __syncthreads();
    int idx = blockIdx.x * NT + tid;
    int gi = idx >> 10, j = idx & 1023;
    float acc = b1[j];
    for (int k = 0; k < 32; k++) acc += sg[gi * 32 + k] * W1[k * 1024 + j];
    h1[idx] = fmaxf(acc, 0.0f);
}

// ---- MLP layer 2, K-split: h2acc += h1-chunk @ W2-chunk; bias+relu in mlp3 ----
__global__ __launch_bounds__(NT) void k_mlp2s(const float* __restrict__ h1,
                                              const float* __restrict__ W2,
                                              float* __restrict__ h2acc) {
    __shared__ float sh[128];
    int gi = blockIdx.x >> 3, ks = blockIdx.x & 7;
    int tid = threadIdx.x;
    if (tid < 128) sh[tid] = h1[gi * 1024 + ks * 128 + tid];
    __syncthreads();
    const float* w = W2 + (size_t)(ks * 128) * 512;
    float acc0 = 0.0f, acc1 = 0.0f;
    for (int k = 0; k < 128; k++) {
        float h = sh[k];
        acc0 += h * w[k * 512 + tid];
        acc1 += h * w[k * 512 + tid + 256];
    }
    atomicAdd(&h2acc[gi * 512 + tid], acc0);
    atomicAdd(&h2acc[gi * 512 + tid + 256], acc1);
}

// ---- MLP layer 3: out[64,4] = relu(h2acc + b2) @ W3 + b3 ----
__global__ void k_mlp3(const float* __restrict__ h2acc, const float* __restrict__ b2,
                       const float* __restrict__ W3, const float* __restrict__ b3,
                       float* __restrict__ out) {
    int tid = threadIdx.x;  // 256 = 64*4
    int gi = tid >> 2, j = tid & 3;
    float acc = b3[j];
    for (int k = 0; k < 512; k++) {
        float h = fmaxf(h2acc[gi * 512 + k] + b2[k], 0.0f);
        acc += h * W3[k * 4 + j];
    }
    out[tid] = acc;
}

extern "C" void kernel_launch(void* const* d_in, const int* in_sizes, int n_in,
                              void* d_out, int out_size, void* d_ws, size_t ws_size,
                              hipStream_t stream) {
    const float* x   = (const float*)d_in[0];
    const int* ei    = (const int*)d_in[1];
    const int* batch = (const int*)d_in[2];
    const float* Wc  = (const float*)d_in[3];
    const float* bc  = (const float*)d_in[4];
    const float* W1  = (const float*)d_in[5];
    const float* b1  = (const float*)d_in[6];
    const float* W2  = (const float*)d_in[7];
    const float* b2  = (const float*)d_in[8];
    const float* W3  = (const float*)d_in[9];
    const float* b3  = (const float*)d_in[10];
    float* out       = (float*)d_out;

    const int N = in_sizes[2];      // 100000
    const int E = in_sizes[1] / 2;  // 1.6M
    const int* row = ei;
    const int* col = ei + E;
    const int NBK = (N + BSIZE - 1) / BSIZE;   // 391 (<= 512)
    const int epb = (E + HB - 1) / HB;

    // workspace layout (zeroed region first: bhc | bhr | h2acc)
    int* iws = (int*)d_ws;
    int* bhc       = iws;                          // 512
    int* bhr       = bhc + 512;                    // 512
    float* h2acc   = (float*)(bhr + 512);          // 64*512
    int* bbase     = (int*)(h2acc + 64 * 512);     // 512 (NBK+1)
    int* bcur      = bbase + 512;                  // 512
    int* rbase     = bcur + 512;                   // 512 (NBK+1)
    int* rcur      = rbase + 512;                  // 512
    int* offs      = rcur + 512;                   // N+4
    float* dis     = (float*)(offs + N + 4);       // N
    int2* entries2 = (int2*)(dis + N);             // E int2
    int* blkc      = (int*)entries2;               // HB*512 (dead before k_bcsr)
    int* blkr      = blkc + HB * 512;              // HB*512
    __half* xh     = (__half*)(entries2 + E);      // 32N halfs (6.4MB)
    __half* tx1h   = xh + (size_t)N * 32;          // 32N halfs ; rbuck aliases
    int* rbuck     = (int*)tx1h;                   // E ints (dead before prop1 writes tx1h)
    float* p2      = (float*)(tx1h + (size_t)N * 32);  // 32N floats ; ebuck aliases
    int2* ebuck    = (int2*)p2;                    // E int2 (dead before prop2 writes p2)
    float* g       = p2 + (size_t)N * 32;          // 64*32
    float* h1      = g + 64 * 32;                  // 64*1024

    // one contiguous zero: bhc + bhr + h2acc
    hipMemsetAsync(bhc, 0, sizeof(int) * (512 + 512 + 64 * 512), stream);

    k_hist2<<<HB, NT, 0, stream>>>(row, col, bhc, bhr, blkc, blkr, E, NBK, epb);
    k_bscan2<<<1, 512, 0, stream>>>(bhc, bhr, bbase, bcur, rbase, rcur, NBK, E);
    k_bscatter2<<<HB, NT, 0, stream>>>(row, col, blkc, blkr, bcur, rcur, ebuck, rbuck, E, NBK, epb);
    k_rcsr<<<NBK, NT, 0, stream>>>(rbase, rbuck, dis, N);
    k_bcsr<<<NBK, NT, 0, stream>>>(bbase, ebuck, dis, offs, entries2, N, E, NBK);
    k_xh<<<(N * 32 / 4 + NT - 1) / NT, NT, 0, stream>>>(x, xh, N * 32 / 4);
    k_prop_gh<<<((size_t)N * 4 + NT - 1) / NT, NT, 0, stream>>>(offs, entries2, dis, xh, tx1h, (float*)nullptr, N, 0);
    k_prop_gh<<<((size_t)N * 4 + NT - 1) / NT, NT, 0, stream>>>(offs, entries2, dis, tx1h, (__half*)nullptr, p2, N, 1);
    k_ginit<<<8, NT, 0, stream>>>(g);
    k_combine<<<(N + 7) / 8, NT, 0, stream>>>(x, tx1h, p2, Wc, bc, batch, g, N);
    k_mlp1<<<256, NT, 0, stream>>>(g, W1, b1, h1);
    k_mlp2s<<<512, NT, 0, stream>>>(h1, W2, h2acc);
    k_mlp3<<<1, NT, 0, stream>>>(h2acc, b2, W3, b3, out);
}

// Round 11
// 306.816 us; speedup vs baseline: 5.2106x; 1.1060x over previous
//
#include <hip/hip_runtime.h>
#include <hip/hip_fp16.h>

// GCN1: ChebConv(K=3) -> global max pool -> MLP(32->1024->512->4)
// fp32 floats, int32 indices (established rounds 0-3).
// Round 11: k_combine was LDS-issue-bound (192 ds_read_b32/thread, 58us).
// Replace with MFMA: h = [T0|T1|T2]@[W0;W1;W2] as 16x16x32 f16 MFMA,
// K-chunks = Chebyshev orders. T2 built elementwise on A-fragments.
// prop2 now emits fp16 (p2h).

#define NT 256
#define BSHIFT 8
#define BSIZE 256   // nodes per bucket; NBK = ceil(N/256) = 391 <= 512
#define HB 256      // blocks for hist/scatter passes

typedef _Float16 half8 __attribute__((ext_vector_type(8)));
typedef float f32x4 __attribute__((ext_vector_type(4)));

__device__ __forceinline__ void atomicMaxFloat(float* addr, float val) {
    if (val >= 0.0f) atomicMax((int*)addr, __float_as_int(val));
    else             atomicMin((unsigned int*)addr, __float_as_uint(val));
}

// ---- pass 1: LDS bucket histograms of row and col; per-block counts to global ----
__global__ __launch_bounds__(NT) void k_hist2(const int* __restrict__ row,
                                              const int* __restrict__ col,
                                              int* __restrict__ bhc, int* __restrict__ bhr,
                                              int* __restrict__ blkc, int* __restrict__ blkr,
                                              int E, int NBK, int epb) {
    __shared__ int lhc[512], lhr[512];
    int tid = threadIdx.x;
    for (int i = tid; i < 512; i += NT) { lhc[i] = 0; lhr[i] = 0; }
    __syncthreads();
    int start = blockIdx.x * epb;
    int end = min(start + epb, E);
    for (int e = start + tid; e < end; e += NT) {
        atomicAdd(&lhr[row[e] >> BSHIFT], 1);  // LDS
        atomicAdd(&lhc[col[e] >> BSHIFT], 1);  // LDS
    }
    __syncthreads();
    int base = blockIdx.x * 512;
    for (int i = tid; i < NBK; i += NT) {
        int vc = lhc[i], vr = lhr[i];
        blkc[base + i] = vc;
        blkr[base + i] = vr;
        if (vc) atomicAdd(&bhc[i], vc);
        if (vr) atomicAdd(&bhr[i], vr);
    }
}

// ---- pass 2: exclusive scans of both bucket histograms (one block) ----
__global__ __launch_bounds__(512) void k_bscan2(const int* __restrict__ bhc,
                                                const int* __restrict__ bhr,
                                                int* __restrict__ bbase, int* __restrict__ bcur,
                                                int* __restrict__ rbase, int* __restrict__ rcur,
                                                int NBK, int E) {
    __shared__ int s[512];
    int tid = threadIdx.x;
    int v = (tid < NBK) ? bhc[tid] : 0;
    s[tid] = v;
    __syncthreads();
    for (int off = 1; off < 512; off <<= 1) {
        int t = (tid >= off) ? s[tid - off] : 0;
        __syncthreads();
        s[tid] += t;
        __syncthreads();
    }
    if (tid < NBK) { int b = s[tid] - v; bbase[tid] = b; bcur[tid] = b; }
    if (tid == 0) bbase[NBK] = E;
    __syncthreads();
    v = (tid < NBK) ? bhr[tid] : 0;
    s[tid] = v;
    __syncthreads();
    for (int off = 1; off < 512; off <<= 1) {
        int t = (tid >= off) ? s[tid - off] : 0;
        __syncthreads();
        s[tid] += t;
        __syncthreads();
    }
    if (tid < NBK) { int b = s[tid] - v; rbase[tid] = b; rcur[tid] = b; }
    if (tid == 0) rbase[NBK] = E;
}

// ---- pass 3: single-pass dual scatter (col->ebuck int2, row->rbuck int) ----
__global__ __launch_bounds__(NT) void k_bscatter2(const int* __restrict__ row,
                                                  const int* __restrict__ col,
                                                  const int* __restrict__ blkc,
                                                  const int* __restrict__ blkr,
                                                  int* __restrict__ bcur, int* __restrict__ rcur,
                                                  int2* __restrict__ ebuck, int* __restrict__ rbuck,
                                                  int E, int NBK, int epb) {
    __shared__ int lbasec[512], lbaser[512], lhc[512], lhr[512];
    int tid = threadIdx.x;
    int base = blockIdx.x * 512;
    for (int i = tid; i < NBK; i += NT) {
        int vc = blkc[base + i];
        int vr = blkr[base + i];
        lbasec[i] = vc ? atomicAdd(&bcur[i], vc) : 0;
        lbaser[i] = vr ? atomicAdd(&rcur[i], vr) : 0;
        lhc[i] = 0;
        lhr[i] = 0;
    }
    __syncthreads();
    int start = blockIdx.x * epb;
    int end = min(start + epb, E);
    for (int e = start + tid; e < end; e += NT) {
        int r = row[e], c = col[e];
        int bc_ = c >> BSHIFT;
        int li = atomicAdd(&lhc[bc_], 1);  // LDS
        ebuck[lbasec[bc_] + li] = make_int2(r, c);
        int br_ = r >> BSHIFT;
        int lj = atomicAdd(&lhr[br_], 1);  // LDS
        rbuck[lbaser[br_] + lj] = r;
    }
}

// ---- pass 4a: per-row-bucket count -> dis = rsqrt(outdeg) ----
__global__ __launch_bounds__(NT) void k_rcsr(const int* __restrict__ rbase,
                                             const int* __restrict__ rbuck,
                                             float* __restrict__ dis, int N) {
    __shared__ int cnt[BSIZE];
    int b = blockIdx.x, tid = threadIdx.x;
    int base = rbase[b], endr = rbase[b + 1];
    cnt[tid] = 0;
    __syncthreads();
    for (int e = base + tid; e < endr; e += NT)
        atomicAdd(&cnt[rbuck[e] & (BSIZE - 1)], 1);  // LDS
    __syncthreads();
    int node = (b << BSHIFT) + tid;
    if (node < N) {
        int d = cnt[tid];
        dis[node] = (d > 0) ? rsqrtf((float)d) : 0.0f;
    }
}

// ---- pass 4b: per-col-bucket counting sort -> offs + weight-annotated entries ----
__global__ __launch_bounds__(NT) void k_bcsr(const int* __restrict__ bbase,
                                             const int2* __restrict__ ebuck,
                                             const float* __restrict__ dis,
                                             int* __restrict__ offs,
                                             int2* __restrict__ entries2,
                                             int N, int E, int NBK) {
    __shared__ int cnt[BSIZE];
    __shared__ int excl[BSIZE];
    int b = blockIdx.x, tid = threadIdx.x;
    int base = bbase[b], endr = bbase[b + 1];
    cnt[tid] = 0;
    __syncthreads();
    for (int e = base + tid; e < endr; e += NT)
        atomicAdd(&cnt[ebuck[e].y & (BSIZE - 1)], 1);  // LDS
    __syncthreads();
    int v = cnt[tid];
    excl[tid] = v;
    __syncthreads();
    for (int off = 1; off < BSIZE; off <<= 1) {
        int t = (tid >= off) ? excl[tid - off] : 0;
        __syncthreads();
        excl[tid] += t;
        __syncthreads();
    }
    int ex = excl[tid] - v;  // exclusive prefix
    int node = (b << BSHIFT) + tid;
    if (node < N) offs[node] = base + ex;
    cnt[tid] = ex;  // reuse as cursor
    __syncthreads();
    for (int e = base + tid; e < endr; e += NT) {
        int2 rc = ebuck[e];
        int li = atomicAdd(&cnt[rc.y & (BSIZE - 1)], 1);  // LDS
        entries2[base + li] = make_int2(rc.x, __float_as_int(dis[rc.x]));
    }
    if (b == 0 && tid == 0) offs[N] = E;
}

// ---- x (fp32) -> xh (fp16), 4 elems/thread ----
__global__ void k_xh(const float* __restrict__ x, __half* __restrict__ xh, int n4) {
    int i = blockIdx.x * blockDim.x + threadIdx.x;
    if (i < n4) {
        float4 v = ((const float4*)x)[i];
        float2 o;
        ((__half2*)&o)[0] = __floats2half2_rn(v.x, v.y);
        ((__half2*)&o)[1] = __floats2half2_rn(v.z, v.w);
        ((float2*)xh)[i] = o;
    }
}

// ---- gather prop (fp16 src): dst[c] = -dis[c] * sum w_e * src[r_e], fp16 out ----
__global__ __launch_bounds__(NT) void k_prop_gh(const int* __restrict__ offs,
                                                const int2* __restrict__ entries2,
                                                const float* __restrict__ dis,
                                                const __half* __restrict__ src,
                                                __half* __restrict__ dsth, int N) {
    int idx = blockIdx.x * blockDim.x + threadIdx.x;
    int node = idx >> 2, q = idx & 3;
    if (node >= N) return;
    int s = offs[node], t = offs[node + 1];
    float a0 = 0, a1 = 0, a2 = 0, a3 = 0, a4 = 0, a5 = 0, a6 = 0, a7 = 0;
    for (int e = s; e < t; e++) {
        int2 ew = entries2[e];
        float w = __int_as_float(ew.y);
        float4 raw = *(const float4*)(src + (size_t)ew.x * 32 + q * 8);  // 8 halfs
        const __half2* hp = (const __half2*)&raw;
        float2 f0 = __half22float2(hp[0]);
        float2 f1 = __half22float2(hp[1]);
        float2 f2 = __half22float2(hp[2]);
        float2 f3 = __half22float2(hp[3]);
        a0 += w * f0.x; a1 += w * f0.y;
        a2 += w * f1.x; a3 += w * f1.y;
        a4 += w * f2.x; a5 += w * f2.y;
        a6 += w * f3.x; a7 += w * f3.y;
    }
    float sc = -dis[node];
    float4 ov;
    ((__half2*)&ov)[0] = __floats2half2_rn(sc * a0, sc * a1);
    ((__half2*)&ov)[1] = __floats2half2_rn(sc * a2, sc * a3);
    ((__half2*)&ov)[2] = __floats2half2_rn(sc * a4, sc * a5);
    ((__half2*)&ov)[3] = __floats2half2_rn(sc * a6, sc * a7);
    *(float4*)(dsth + (size_t)node * 32 + q * 8) = ov;
}

// ---- init pooled max to -inf ----
__global__ void k_ginit(float* __restrict__ g) {
    int i = blockIdx.x * blockDim.x + threadIdx.x;
    if (i < 64 * 32) g[i] = -__builtin_inff();
}

// ---- MFMA combine: h = T0@W0 + T1@W1 + (2*P2-T0)@W2 + b ; segmented max -> g ----
// 256 thr = 4 waves; wave handles 16 rows. K-chunk c of the 96-wide GEMM = order c.
// A layout (m120-verified): A[m=lane&15][k=quad*8+j]. B: B[k=quad*8+j][n=lane&15].
// C/D (m89-verified): col=lane&15, row=quad*4+reg.
__global__ __launch_bounds__(NT) void k_combine_m(
    const _Float16* __restrict__ xh, const _Float16* __restrict__ tx1h,
    const _Float16* __restrict__ p2h,
    const float* __restrict__ Wc, const float* __restrict__ bc,
    const int* __restrict__ batch, float* __restrict__ g, int N) {
    __shared__ _Float16 sW[3072];
    __shared__ float sb[32];
    __shared__ float hs[64][33];
    __shared__ int sbatch[64];

    int tid = threadIdx.x;
    for (int i = tid; i < 3072; i += NT) sW[i] = (_Float16)Wc[i];
    if (tid < 32) sb[tid] = bc[tid];
    int rowbase = blockIdx.x * 64;
    if (tid < 64) {
        int gr = rowbase + tid;
        sbatch[tid] = (gr < N) ? batch[gr] : -1;
    }
    __syncthreads();

    int wave = tid >> 6;
    int lane = tid & 63;
    int m = lane & 15;
    int quad = lane >> 4;
    int grow = rowbase + wave * 16 + m;

    half8 a0 = {}, a1 = {}, a2 = {};
    if (grow < N) {
        size_t off = (size_t)grow * 32 + quad * 8;
        a0 = *(const half8*)(xh + off);
        a1 = *(const half8*)(tx1h + off);
        half8 p = *(const half8*)(p2h + off);
        a2 = p + p - a0;  // T2 = 2*P2 - T0, elementwise (same fragment layout)
    }

    f32x4 acc[2];
    #pragma unroll
    for (int n = 0; n < 2; n++) {
        half8 b0, b1, b2;
        int colb = n * 16 + m;
        #pragma unroll
        for (int j = 0; j < 8; j++) {
            int k = quad * 8 + j;
            b0[j] = sW[k * 32 + colb];
            b1[j] = sW[1024 + k * 32 + colb];
            b2[j] = sW[2048 + k * 32 + colb];
        }
        f32x4 c = {0.f, 0.f, 0.f, 0.f};
        c = __builtin_amdgcn_mfma_f32_16x16x32_f16(a0, b0, c, 0, 0, 0);
        c = __builtin_amdgcn_mfma_f32_16x16x32_f16(a1, b1, c, 0, 0, 0);
        c = __builtin_amdgcn_mfma_f32_16x16x32_f16(a2, b2, c, 0, 0, 0);
        acc[n] = c;
    }

    #pragma unroll
    for (int n = 0; n < 2; n++)
        #pragma unroll
        for (int r = 0; r < 4; r++)
            hs[wave * 16 + quad * 4 + r][n * 16 + m] = acc[n][r] + sb[n * 16 + m];
    __syncthreads();

    // segmented max: 32 features x 8 row-groups of 8 rows
    int f = tid & 31, s = tid >> 5;
    int curb = -1;
    float curm = 0.0f;
    for (int j = s * 8; j < s * 8 + 8; j++) {
        int b = sbatch[j];
        if (b < 0) continue;
        float v = hs[j][f];
        if (b != curb) {
            if (curb >= 0) atomicMaxFloat(&g[curb * 32 + f], curm);
            curb = b;
            curm = v;
        } else {
            curm = fmaxf(curm, v);
        }
    }
    if (curb >= 0) atomicMaxFloat(&g[curb * 32 + f], curm);
}

// ---- MLP layer 1: h1[64,1024] = relu(g[64,32] @ W1 + b1) ----
__global__ void k_mlp1(const float* __restrict__ g, const float* __restrict__ W1,
                       const float* __restrict__ b1, float* __restrict__ h1) {
    __shared__ float sg[64 * 32];
    int tid = threadIdx.x;
    for (int i = tid; i < 64 * 32; i += NT) sg[i] = g[i];
    __syncthreads();
    int idx = blockIdx.x * NT + tid;
    int gi = idx >> 10, j = idx & 1023;
    float acc = b1[j];
    for (int k = 0; k < 32; k++) acc += sg[gi * 32 + k] * W1[k * 1024 + j];
    h1[idx] = fmaxf(acc, 0.0f);
}

// ---- MLP layer 2, K-split: h2acc += h1-chunk @ W2-chunk; bias+relu in mlp3 ----
__global__ __launch_bounds__(NT) void k_mlp2s(const float* __restrict__ h1,
                                              const float* __restrict__ W2,
                                              float* __restrict__ h2acc) {
    __shared__ float sh[128];
    int gi = blockIdx.x >> 3, ks = blockIdx.x & 7;
    int tid = threadIdx.x;
    if (tid < 128) sh[tid] = h1[gi * 1024 + ks * 128 + tid];
    __syncthreads();
    const float* w = W2 + (size_t)(ks * 128) * 512;
    float acc0 = 0.0f, acc1 = 0.0f;
    for (int k = 0; k < 128; k++) {
        float h = sh[k];
        acc0 += h * w[k * 512 + tid];
        acc1 += h * w[k * 512 + tid + 256];
    }
    atomicAdd(&h2acc[gi * 512 + tid], acc0);
    atomicAdd(&h2acc[gi * 512 + tid + 256], acc1);
}

// ---- MLP layer 3: out[64,4] = relu(h2acc + b2) @ W3 + b3 ----
__global__ void k_mlp3(const float* __restrict__ h2acc, const float* __restrict__ b2,
                       const float* __restrict__ W3, const float* __restrict__ b3,
                       float* __restrict__ out) {
    int tid = threadIdx.x;  // 256 = 64*4
    int gi = tid >> 2, j = tid & 3;
    float acc = b3[j];
    for (int k = 0; k < 512; k++) {
        float h = fmaxf(h2acc[gi * 512 + k] + b2[k], 0.0f);
        acc += h * W3[k * 4 + j];
    }
    out[tid] = acc;
}

extern "C" void kernel_launch(void* const* d_in, const int* in_sizes, int n_in,
                              void* d_out, int out_size, void* d_ws, size_t ws_size,
                              hipStream_t stream) {
    const float* x   = (const float*)d_in[0];
    const int* ei    = (const int*)d_in[1];
    const int* batch = (const int*)d_in[2];
    const float* Wc  = (const float*)d_in[3];
    const float* bc  = (const float*)d_in[4];
    const float* W1  = (const float*)d_in[5];
    const float* b1  = (const float*)d_in[6];
    const float* W2  = (const float*)d_in[7];
    const float* b2  = (const float*)d_in[8];
    const float* W3  = (const float*)d_in[9];
    const float* b3  = (const float*)d_in[10];
    float* out       = (float*)d_out;

    const int N = in_sizes[2];      // 100000
    const int E = in_sizes[1] / 2;  // 1.6M
    const int* row = ei;
    const int* col = ei + E;
    const int NBK = (N + BSIZE - 1) / BSIZE;   // 391 (<= 512)
    const int epb = (E + HB - 1) / HB;

    // workspace layout (zeroed region first: bhc | bhr | h2acc)
    int* iws = (int*)d_ws;
    int* bhc        = iws;                          // 512
    int* bhr        = bhc + 512;                    // 512
    float* h2acc    = (float*)(bhr + 512);          // 64*512
    int* bbase      = (int*)(h2acc + 64 * 512);     // 512 (NBK+1)
    int* bcur       = bbase + 512;                  // 512
    int* rbase      = bcur + 512;                   // 512 (NBK+1)
    int* rcur       = rbase + 512;                  // 512
    int* offs       = rcur + 512;                   // N+4
    float* dis      = (float*)(offs + N + 4);       // N
    int2* entries2  = (int2*)(dis + N);             // E int2
    int* blkc       = (int*)entries2;               // HB*512 (dead before k_bcsr)
    int* blkr       = blkc + HB * 512;              // HB*512
    _Float16* xh    = (_Float16*)(entries2 + E);    // 32N halfs (6.4MB)
    _Float16* tx1h  = xh + (size_t)N * 32;          // 32N halfs ; rbuck aliases
    int* rbuck      = (int*)tx1h;                   // E ints (dead before prop1)
    _Float16* p2h   = tx1h + (size_t)N * 32;        // 32N halfs ; ebuck starts here
    int2* ebuck     = (int2*)p2h;                   // E int2 (12.8MB, spans past p2h; dead before prop2/g/h1 writes)
    float* g        = (float*)((char*)p2h + (size_t)E * sizeof(int2));  // after ebuck end
    float* h1       = g + 64 * 32;                  // 64*1024

    // one contiguous zero: bhc + bhr + h2acc
    hipMemsetAsync(bhc, 0, sizeof(int) * (512 + 512 + 64 * 512), stream);

    k_hist2<<<HB, NT, 0, stream>>>(row, col, bhc, bhr, blkc, blkr, E, NBK, epb);
    k_bscan2<<<1, 512, 0, stream>>>(bhc, bhr, bbase, bcur, rbase, rcur, NBK, E);
    k_bscatter2<<<HB, NT, 0, stream>>>(row, col, blkc, blkr, bcur, rcur, ebuck, rbuck, E, NBK, epb);
    k_rcsr<<<NBK, NT, 0, stream>>>(rbase, rbuck, dis, N);
    k_bcsr<<<NBK, NT, 0, stream>>>(bbase, ebuck, dis, offs, entries2, N, E, NBK);
    k_xh<<<(N * 32 / 4 + NT - 1) / NT, NT, 0, stream>>>(x, (__half*)xh, N * 32 / 4);
    k_prop_gh<<<((size_t)N * 4 + NT - 1) / NT, NT, 0, stream>>>(offs, entries2, dis, (const __half*)xh, (__half*)tx1h, N);
    k_prop_gh<<<((size_t)N * 4 + NT - 1) / NT, NT, 0, stream>>>(offs, entries2, dis, (const __half*)tx1h, (__half*)p2h, N);
    k_ginit<<<8, NT, 0, stream>>>(g);
    k_combine_m<<<(N + 63) / 64, NT, 0, stream>>>(xh, tx1h, p2h, Wc, bc, batch, g, N);
    k_mlp1<<<256, NT, 0, stream>>>(g, W1, b1, h1);
    k_mlp2s<<<512, NT, 0, stream>>>(h1, W2, h2acc);
    k_mlp3<<<1, NT, 0, stream>>>(h2acc, b2, W3, b3, out);
}

// Round 12
// 286.880 us; speedup vs baseline: 5.5727x; 1.0695x over previous
//
#include <hip/hip_runtime.h>
#include <hip/hip_fp16.h>

// GCN1: ChebConv(K=3) -> global max pool -> MLP(32->1024->512->4)
// fp32 floats, int32 indices (established rounds 0-3).
// Round 12: algebraic refactor — pre-scale features by dis (y=dis*h) so
// props need NO per-edge weight: entries int2->int (6.4MB less fetch/prop),
// ebuck packed (src<<8)|(col&255) (bscatter2 writes halved), k_bcsr loses
// the 1.6M random dis gathers. Harness d_ws poison fill (45us @ 6TB/s) is
// fixed overhead.

#define NT 256
#define BSHIFT 8
#define BSIZE 256   // nodes per bucket; NBK = ceil(N/256) = 391 <= 512
#define HB 256      // blocks for hist/scatter passes

typedef _Float16 half8 __attribute__((ext_vector_type(8)));
typedef float f32x4 __attribute__((ext_vector_type(4)));

__device__ __forceinline__ void atomicMaxFloat(float* addr, float val) {
    if (val >= 0.0f) atomicMax((int*)addr, __float_as_int(val));
    else             atomicMin((unsigned int*)addr, __float_as_uint(val));
}

// ---- pass 1: LDS bucket histograms of row and col; per-block counts to global ----
__global__ __launch_bounds__(NT) void k_hist2(const int* __restrict__ row,
                                              const int* __restrict__ col,
                                              int* __restrict__ bhc, int* __restrict__ bhr,
                                              int* __restrict__ blkc, int* __restrict__ blkr,
                                              int E, int NBK, int epb) {
    __shared__ int lhc[512], lhr[512];
    int tid = threadIdx.x;
    for (int i = tid; i < 512; i += NT) { lhc[i] = 0; lhr[i] = 0; }
    __syncthreads();
    int start = blockIdx.x * epb;
    int end = min(start + epb, E);
    for (int e = start + tid; e < end; e += NT) {
        atomicAdd(&lhr[row[e] >> BSHIFT], 1);  // LDS
        atomicAdd(&lhc[col[e] >> BSHIFT], 1);  // LDS
    }
    __syncthreads();
    int base = blockIdx.x * 512;
    for (int i = tid; i < NBK; i += NT) {
        int vc = lhc[i], vr = lhr[i];
        blkc[base + i] = vc;
        blkr[base + i] = vr;
        if (vc) atomicAdd(&bhc[i], vc);
        if (vr) atomicAdd(&bhr[i], vr);
    }
}

// ---- pass 2: exclusive scans of both bucket histograms (one block) ----
__global__ __launch_bounds__(512) void k_bscan2(const int* __restrict__ bhc,
                                                const int* __restrict__ bhr,
                                                int* __restrict__ bbase, int* __restrict__ bcur,
                                                int* __restrict__ rbase, int* __restrict__ rcur,
                                                int NBK, int E) {
    __shared__ int s[512];
    int tid = threadIdx.x;
    int v = (tid < NBK) ? bhc[tid] : 0;
    s[tid] = v;
    __syncthreads();
    for (int off = 1; off < 512; off <<= 1) {
        int t = (tid >= off) ? s[tid - off] : 0;
        __syncthreads();
        s[tid] += t;
        __syncthreads();
    }
    if (tid < NBK) { int b = s[tid] - v; bbase[tid] = b; bcur[tid] = b; }
    if (tid == 0) bbase[NBK] = E;
    __syncthreads();
    v = (tid < NBK) ? bhr[tid] : 0;
    s[tid] = v;
    __syncthreads();
    for (int off = 1; off < 512; off <<= 1) {
        int t = (tid >= off) ? s[tid - off] : 0;
        __syncthreads();
        s[tid] += t;
        __syncthreads();
    }
    if (tid < NBK) { int b = s[tid] - v; rbase[tid] = b; rcur[tid] = b; }
    if (tid == 0) rbase[NBK] = E;
}

// ---- pass 3: single-pass dual scatter (col->ebuck packed int, row->rbuck int) ----
__global__ __launch_bounds__(NT) void k_bscatter2(const int* __restrict__ row,
                                                  const int* __restrict__ col,
                                                  const int* __restrict__ blkc,
                                                  const int* __restrict__ blkr,
                                                  int* __restrict__ bcur, int* __restrict__ rcur,
                                                  int* __restrict__ ebuck, int* __restrict__ rbuck,
                                                  int E, int NBK, int epb) {
    __shared__ int lbasec[512], lbaser[512], lhc[512], lhr[512];
    int tid = threadIdx.x;
    int base = blockIdx.x * 512;
    for (int i = tid; i < NBK; i += NT) {
        int vc = blkc[base + i];
        int vr = blkr[base + i];
        lbasec[i] = vc ? atomicAdd(&bcur[i], vc) : 0;
        lbaser[i] = vr ? atomicAdd(&rcur[i], vr) : 0;
        lhc[i] = 0;
        lhr[i] = 0;
    }
    __syncthreads();
    int start = blockIdx.x * epb;
    int end = min(start + epb, E);
    for (int e = start + tid; e < end; e += NT) {
        int r = row[e], c = col[e];
        int bc_ = c >> BSHIFT;
        int li = atomicAdd(&lhc[bc_], 1);  // LDS
        ebuck[lbasec[bc_] + li] = (r << 8) | (c & (BSIZE - 1));  // r<2^17, fits
        int br_ = r >> BSHIFT;
        int lj = atomicAdd(&lhr[br_], 1);  // LDS
        rbuck[lbaser[br_] + lj] = r;
    }
}

// ---- pass 4a: per-row-bucket count -> dis = rsqrt(outdeg) ----
__global__ __launch_bounds__(NT) void k_rcsr(const int* __restrict__ rbase,
                                             const int* __restrict__ rbuck,
                                             float* __restrict__ dis, int N) {
    __shared__ int cnt[BSIZE];
    int b = blockIdx.x, tid = threadIdx.x;
    int base = rbase[b], endr = rbase[b + 1];
    cnt[tid] = 0;
    __syncthreads();
    for (int e = base + tid; e < endr; e += NT)
        atomicAdd(&cnt[rbuck[e] & (BSIZE - 1)], 1);  // LDS
    __syncthreads();
    int node = (b << BSHIFT) + tid;
    if (node < N) {
        int d = cnt[tid];
        dis[node] = (d > 0) ? rsqrtf((float)d) : 0.0f;
    }
}

// ---- pass 4b: per-col-bucket counting sort -> offs + src-index entries ----
__global__ __launch_bounds__(NT) void k_bcsr(const int* __restrict__ bbase,
                                             const int* __restrict__ ebuck,
                                             int* __restrict__ offs,
                                             int* __restrict__ entries,
                                             int N, int E, int NBK) {
    __shared__ int cnt[BSIZE];
    __shared__ int excl[BSIZE];
    int b = blockIdx.x, tid = threadIdx.x;
    int base = bbase[b], endr = bbase[b + 1];
    cnt[tid] = 0;
    __syncthreads();
    for (int e = base + tid; e < endr; e += NT)
        atomicAdd(&cnt[ebuck[e] & (BSIZE - 1)], 1);  // LDS
    __syncthreads();
    int v = cnt[tid];
    excl[tid] = v;
    __syncthreads();
    for (int off = 1; off < BSIZE; off <<= 1) {
        int t = (tid >= off) ? excl[tid - off] : 0;
        __syncthreads();
        excl[tid] += t;
        __syncthreads();
    }
    int ex = excl[tid] - v;  // exclusive prefix
    int node = (b << BSHIFT) + tid;
    if (node < N) offs[node] = base + ex;
    cnt[tid] = ex;  // reuse as cursor
    __syncthreads();
    for (int e = base + tid; e < endr; e += NT) {
        int pv = ebuck[e];
        int li = atomicAdd(&cnt[pv & (BSIZE - 1)], 1);  // LDS
        entries[base + li] = pv >> 8;  // src index
    }
    if (b == 0 && tid == 0) offs[N] = E;
}

// ---- x (fp32) -> xh (fp16, for combine) + xsh (dis-scaled fp16, for prop1) ----
__global__ void k_xs(const float* __restrict__ x, const float* __restrict__ dis,
                     __half* __restrict__ xh, __half* __restrict__ xsh, int n4) {
    int i = blockIdx.x * blockDim.x + threadIdx.x;
    if (i < n4) {
        float4 v = ((const float4*)x)[i];
        float d = dis[i >> 3];
        float2 o, os;
        ((__half2*)&o)[0] = __floats2half2_rn(v.x, v.y);
        ((__half2*)&o)[1] = __floats2half2_rn(v.z, v.w);
        ((__half2*)&os)[0] = __floats2half2_rn(d * v.x, d * v.y);
        ((__half2*)&os)[1] = __floats2half2_rn(d * v.z, d * v.w);
        ((float2*)xh)[i] = o;
        ((float2*)xsh)[i] = os;
    }
}

// ---- prop1: S = sum xs[r]; tx1 = -dis[c]*S (fp16) ; xs2 = dis[c]*tx1 (fp16) ----
__global__ __launch_bounds__(NT) void k_prop1(const int* __restrict__ offs,
                                              const int* __restrict__ entries,
                                              const float* __restrict__ dis,
                                              const __half* __restrict__ xsh,
                                              __half* __restrict__ tx1h,
                                              __half* __restrict__ xs2h, int N) {
    int idx = blockIdx.x * blockDim.x + threadIdx.x;
    int node = idx >> 2, q = idx & 3;
    if (node >= N) return;
    int s = offs[node], t = offs[node + 1];
    float a0 = 0, a1 = 0, a2 = 0, a3 = 0, a4 = 0, a5 = 0, a6 = 0, a7 = 0;
    for (int e = s; e < t; e++) {
        int r = entries[e];
        float4 raw = *(const float4*)(xsh + (size_t)r * 32 + q * 8);  // 8 halfs
        const __half2* hp = (const __half2*)&raw;
        float2 f0 = __half22float2(hp[0]);
        float2 f1 = __half22float2(hp[1]);
        float2 f2 = __half22float2(hp[2]);
        float2 f3 = __half22float2(hp[3]);
        a0 += f0.x; a1 += f0.y; a2 += f1.x; a3 += f1.y;
        a4 += f2.x; a5 += f2.y; a6 += f3.x; a7 += f3.y;
    }
    float d = dis[node];
    float sc = -d;
    float4 o1, o2;
    ((__half2*)&o1)[0] = __floats2half2_rn(sc * a0, sc * a1);
    ((__half2*)&o1)[1] = __floats2half2_rn(sc * a2, sc * a3);
    ((__half2*)&o1)[2] = __floats2half2_rn(sc * a4, sc * a5);
    ((__half2*)&o1)[3] = __floats2half2_rn(sc * a6, sc * a7);
    float sd = sc * d;  // -dis^2
    ((__half2*)&o2)[0] = __floats2half2_rn(sd * a0, sd * a1);
    ((__half2*)&o2)[1] = __floats2half2_rn(sd * a2, sd * a3);
    ((__half2*)&o2)[2] = __floats2half2_rn(sd * a4, sd * a5);
    ((__half2*)&o2)[3] = __floats2half2_rn(sd * a6, sd * a7);
    *(float4*)(tx1h + (size_t)node * 32 + q * 8) = o1;
    *(float4*)(xs2h + (size_t)node * 32 + q * 8) = o2;
}

// ---- prop2: S2 = sum xs2[r]; p2 = -dis[c]*S2 (fp16) ----
__global__ __launch_bounds__(NT) void k_prop2(const int* __restrict__ offs,
                                              const int* __restrict__ entries,
                                              const float* __restrict__ dis,
                                              const __half* __restrict__ xs2h,
                                              __half* __restrict__ p2h, int N) {
    int idx = blockIdx.x * blockDim.x + threadIdx.x;
    int node = idx >> 2, q = idx & 3;
    if (node >= N) return;
    int s = offs[node], t = offs[node + 1];
    float a0 = 0, a1 = 0, a2 = 0, a3 = 0, a4 = 0, a5 = 0, a6 = 0, a7 = 0;
    for (int e = s; e < t; e++) {
        int r = entries[e];
        float4 raw = *(const float4*)(xs2h + (size_t)r * 32 + q * 8);
        const __half2* hp = (const __half2*)&raw;
        float2 f0 = __half22float2(hp[0]);
        float2 f1 = __half22float2(hp[1]);
        float2 f2 = __half22float2(hp[2]);
        float2 f3 = __half22float2(hp[3]);
        a0 += f0.x; a1 += f0.y; a2 += f1.x; a3 += f1.y;
        a4 += f2.x; a5 += f2.y; a6 += f3.x; a7 += f3.y;
    }
    float sc = -dis[node];
    float4 ov;
    ((__half2*)&ov)[0] = __floats2half2_rn(sc * a0, sc * a1);
    ((__half2*)&ov)[1] = __floats2half2_rn(sc * a2, sc * a3);
    ((__half2*)&ov)[2] = __floats2half2_rn(sc * a4, sc * a5);
    ((__half2*)&ov)[3] = __floats2half2_rn(sc * a6, sc * a7);
    *(float4*)(p2h + (size_t)node * 32 + q * 8) = ov;
}

// ---- init pooled max to -inf ----
__global__ void k_ginit(float* __restrict__ g) {
    int i = blockIdx.x * blockDim.x + threadIdx.x;
    if (i < 64 * 32) g[i] = -__builtin_inff();
}

// ---- MFMA combine: h = T0@W0 + T1@W1 + (2*P2-T0)@W2 + b ; segmented max -> g ----
__global__ __launch_bounds__(NT) void k_combine_m(
    const _Float16* __restrict__ xh, const _Float16* __restrict__ tx1h,
    const _Float16* __restrict__ p2h,
    const float* __restrict__ Wc, const float* __restrict__ bc,
    const int* __restrict__ batch, float* __restrict__ g, int N) {
    __shared__ _Float16 sW[3072];
    __shared__ float sb[32];
    __shared__ float hs[64][33];
    __shared__ int sbatch[64];

    int tid = threadIdx.x;
    for (int i = tid; i < 3072; i += NT) sW[i] = (_Float16)Wc[i];
    if (tid < 32) sb[tid] = bc[tid];
    int rowbase = blockIdx.x * 64;
    if (tid < 64) {
        int gr = rowbase + tid;
        sbatch[tid] = (gr < N) ? batch[gr] : -1;
    }
    __syncthreads();

    int wave = tid >> 6;
    int lane = tid & 63;
    int m = lane & 15;
    int quad = lane >> 4;
    int grow = rowbase + wave * 16 + m;

    half8 a0 = {}, a1 = {}, a2 = {};
    if (grow < N) {
        size_t off = (size_t)grow * 32 + quad * 8;
        a0 = *(const half8*)(xh + off);
        a1 = *(const half8*)(tx1h + off);
        half8 p = *(const half8*)(p2h + off);
        a2 = p + p - a0;  // T2 = 2*P2 - T0
    }

    f32x4 acc[2];
    #pragma unroll
    for (int n = 0; n < 2; n++) {
        half8 b0, b1, b2;
        int colb = n * 16 + m;
        #pragma unroll
        for (int j = 0; j < 8; j++) {
            int k = quad * 8 + j;
            b0[j] = sW[k * 32 + colb];
            b1[j] = sW[1024 + k * 32 + colb];
            b2[j] = sW[2048 + k * 32 + colb];
        }
        f32x4 c = {0.f, 0.f, 0.f, 0.f};
        c = __builtin_amdgcn_mfma_f32_16x16x32_f16(a0, b0, c, 0, 0, 0);
        c = __builtin_amdgcn_mfma_f32_16x16x32_f16(a1, b1, c, 0, 0, 0);
        c = __builtin_amdgcn_mfma_f32_16x16x32_f16(a2, b2, c, 0, 0, 0);
        acc[n] = c;
    }

    #pragma unroll
    for (int n = 0; n < 2; n++)
        #pragma unroll
        for (int r = 0; r < 4; r++)
            hs[wave * 16 + quad * 4 + r][n * 16 + m] = acc[n][r] + sb[n * 16 + m];
    __syncthreads();

    int f = tid & 31, s = tid >> 5;
    int curb = -1;
    float curm = 0.0f;
    for (int j = s * 8; j < s * 8 + 8; j++) {
        int b = sbatch[j];
        if (b < 0) continue;
        float v = hs[j][f];
        if (b != curb) {
            if (curb >= 0) atomicMaxFloat(&g[curb * 32 + f], curm);
            curb = b;
            curm = v;
        } else {
            curm = fmaxf(curm, v);
        }
    }
    if (curb >= 0) atomicMaxFloat(&g[curb * 32 + f], curm);
}

// ---- MLP layer 1: h1[64,1024] = relu(g[64,32] @ W1 + b1) ----
__global__ void k_mlp1(const float* __restrict__ g, const float* __restrict__ W1,
                       const float* __restrict__ b1, float* __restrict__ h1) {
    __shared__ float sg[64 * 32];
    int tid = threadIdx.x;
    for (int i = tid; i < 64 * 32; i += NT) sg[i] = g[i];
    __syncthreads();
    int idx = blockIdx.x * NT + tid;
    int gi = idx >> 10, j = idx & 1023;
    float acc = b1[j];
    for (int k = 0; k < 32; k++) acc += sg[gi * 32 + k] * W1[k * 1024 + j];
    h1[idx] = fmaxf(acc, 0.0f);
}

// ---- MLP layer 2, K-split: h2acc += h1-chunk @ W2-chunk; bias+relu in mlp3 ----
__global__ __launch_bounds__(NT) void k_mlp2s(const float* __restrict__ h1,
                                              const float* __restrict__ W2,
                                              float* __restrict__ h2acc) {
    __shared__ float sh[128];
    int gi = blockIdx.x >> 3, ks = blockIdx.x & 7;
    int tid = threadIdx.x;
    if (tid < 128) sh[tid] = h1[gi * 1024 + ks * 128 + tid];
    __syncthreads();
    const float* w = W2 + (size_t)(ks * 128) * 512;
    float acc0 = 0.0f, acc1 = 0.0f;
    for (int k = 0; k < 128; k++) {
        float h = sh[k];
        acc0 += h * w[k * 512 + tid];
        acc1 += h * w[k * 512 + tid + 256];
    }
    atomicAdd(&h2acc[gi * 512 + tid], acc0);
    atomicAdd(&h2acc[gi * 512 + tid + 256], acc1);
}

// ---- MLP layer 3: out[64,4] = relu(h2acc + b2) @ W3 + b3 ----
__global__ void k_mlp3(const float* __restrict__ h2acc, const float* __restrict__ b2,
                       const float* __restrict__ W3, const float* __restrict__ b3,
                       float* __restrict__ out) {
    int tid = threadIdx.x;  // 256 = 64*4
    int gi = tid >> 2, j = tid & 3;
    float acc = b3[j];
    for (int k = 0; k < 512; k++) {
        float h = fmaxf(h2acc[gi * 512 + k] + b2[k], 0.0f);
        acc += h * W3[k * 4 + j];
    }
    out[tid] = acc;
}

extern "C" void kernel_launch(void* const* d_in, const int* in_sizes, int n_in,
                              void* d_out, int out_size, void* d_ws, size_t ws_size,
                              hipStream_t stream) {
    const float* x   = (const float*)d_in[0];
    const int* ei    = (const int*)d_in[1];
    const int* batch = (const int*)d_in[2];
    const float* Wc  = (const float*)d_in[3];
    const float* bc  = (const float*)d_in[4];
    const float* W1  = (const float*)d_in[5];
    const float* b1  = (const float*)d_in[6];
    const float* W2  = (const float*)d_in[7];
    const float* b2  = (const float*)d_in[8];
    const float* W3  = (const float*)d_in[9];
    const float* b3  = (const float*)d_in[10];
    float* out       = (float*)d_out;

    const int N = in_sizes[2];      // 100000
    const int E = in_sizes[1] / 2;  // 1.6M
    const int* row = ei;
    const int* col = ei + E;
    const int NBK = (N + BSIZE - 1) / BSIZE;   // 391 (<= 512)
    const int epb = (E + HB - 1) / HB;

    // workspace layout (zeroed region first: bhc | bhr | h2acc)
    int* iws = (int*)d_ws;
    int* bhc        = iws;                          // 512
    int* bhr        = bhc + 512;                    // 512
    float* h2acc    = (float*)(bhr + 512);          // 64*512
    int* bbase      = (int*)(h2acc + 64 * 512);     // 512 (NBK+1)
    int* bcur       = bbase + 512;                  // 512
    int* rbase      = bcur + 512;                   // 512 (NBK+1)
    int* rcur       = rbase + 512;                  // 512
    int* offs       = rcur + 512;                   // N+4
    float* dis      = (float*)(offs + N + 4);       // N
    int* entries    = (int*)(dis + N);              // E ints (6.4MB)
    int* blkc       = entries;                      // HB*512 (dead before k_bcsr)
    int* blkr       = blkc + HB * 512;              // HB*512 (total 1MB < 6.4MB)
    _Float16* xh    = (_Float16*)(entries + E);     // 32N halfs (6.4MB)
    _Float16* xsh   = xh + (size_t)N * 32;          // 32N halfs
    _Float16* tx1h  = xsh + (size_t)N * 32;         // 32N halfs ; rbuck aliases
    int* rbuck      = (int*)tx1h;                   // E ints (dead before prop1)
    _Float16* xs2h  = tx1h + (size_t)N * 32;        // 32N halfs
    _Float16* p2h   = xs2h + (size_t)N * 32;        // 32N halfs ; ebuck aliases
    int* ebuck      = (int*)p2h;                    // E ints (dead before prop2)
    float* g        = (float*)(p2h + (size_t)N * 32);  // 64*32
    float* h1       = g + 64 * 32;                  // 64*1024

    // one contiguous zero: bhc + bhr + h2acc
    hipMemsetAsync(bhc, 0, sizeof(int) * (512 + 512 + 64 * 512), stream);

    k_hist2<<<HB, NT, 0, stream>>>(row, col, bhc, bhr, blkc, blkr, E, NBK, epb);
    k_bscan2<<<1, 512, 0, stream>>>(bhc, bhr, bbase, bcur, rbase, rcur, NBK, E);
    k_bscatter2<<<HB, NT, 0, stream>>>(row, col, blkc, blkr, bcur, rcur, ebuck, rbuck, E, NBK, epb);
    k_rcsr<<<NBK, NT, 0, stream>>>(rbase, rbuck, dis, N);
    k_bcsr<<<NBK, NT, 0, stream>>>(bbase, ebuck, offs, entries, N, E, NBK);
    k_xs<<<(N * 32 / 4 + NT - 1) / NT, NT, 0, stream>>>(x, dis, (__half*)xh, (__half*)xsh, N * 32 / 4);
    k_prop1<<<((size_t)N * 4 + NT - 1) / NT, NT, 0, stream>>>(offs, entries, dis, (const __half*)xsh, (__half*)tx1h, (__half*)xs2h, N);
    k_prop2<<<((size_t)N * 4 + NT - 1) / NT, NT, 0, stream>>>(offs, entries, dis, (const __half*)xs2h, (__half*)p2h, N);
    k_ginit<<<8, NT, 0, stream>>>(g);
    k_combine_m<<<(N + 63) / 64, NT, 0, stream>>>(xh, tx1h, p2h, Wc, bc, batch, g, N);
    k_mlp1<<<256, NT, 0, stream>>>(g, W1, b1, h1);
    k_mlp2s<<<512, NT, 0, stream>>>(h1, W2, h2acc);
    k_mlp3<<<1, NT, 0, stream>>>(h2acc, b2, W3, b3, out);
}

// Round 13
// 271.170 us; speedup vs baseline: 5.8955x; 1.0579x over previous
//
#include <hip/hip_runtime.h>
#include <hip/hip_fp16.h>

// GCN1: ChebConv(K=3) -> global max pool -> MLP(32->1024->512->4)
// fp32 floats, int32 indices (established rounds 0-3).
// Round 13: consolidation. Fuse prop2 into MFMA combine (p2 via LDS, fp32),
// mlp1 into mlp2 (h1 chunk in LDS), xs into rcsr, ginit into bscan2;
// parallelize mlp3 (1 block serial-512 -> 64 blocks + LDS reduce).
// 14 -> 10 dispatches; kills p2h and h1 global round-trips.

#define NT 256
#define BSHIFT 8
#define BSIZE 256   // nodes per bucket; NBK = ceil(N/256) = 391 <= 512
#define HB 256      // blocks for hist/scatter passes

typedef _Float16 half8 __attribute__((ext_vector_type(8)));
typedef float f32x4 __attribute__((ext_vector_type(4)));

__device__ __forceinline__ void atomicMaxFloat(float* addr, float val) {
    if (val >= 0.0f) atomicMax((int*)addr, __float_as_int(val));
    else             atomicMin((unsigned int*)addr, __float_as_uint(val));
}

// ---- pass 1: LDS bucket histograms of row and col; per-block counts to global ----
__global__ __launch_bounds__(NT) void k_hist2(const int* __restrict__ row,
                                              const int* __restrict__ col,
                                              int* __restrict__ bhc, int* __restrict__ bhr,
                                              int* __restrict__ blkc, int* __restrict__ blkr,
                                              int E, int NBK, int epb) {
    __shared__ int lhc[512], lhr[512];
    int tid = threadIdx.x;
    for (int i = tid; i < 512; i += NT) { lhc[i] = 0; lhr[i] = 0; }
    __syncthreads();
    int start = blockIdx.x * epb;
    int end = min(start + epb, E);
    for (int e = start + tid; e < end; e += NT) {
        atomicAdd(&lhr[row[e] >> BSHIFT], 1);  // LDS
        atomicAdd(&lhc[col[e] >> BSHIFT], 1);  // LDS
    }
    __syncthreads();
    int base = blockIdx.x * 512;
    for (int i = tid; i < NBK; i += NT) {
        int vc = lhc[i], vr = lhr[i];
        blkc[base + i] = vc;
        blkr[base + i] = vr;
        if (vc) atomicAdd(&bhc[i], vc);
        if (vr) atomicAdd(&bhr[i], vr);
    }
}

// ---- pass 2: exclusive scans of both bucket histograms; also inits g to -inf ----
__global__ __launch_bounds__(512) void k_bscan2(const int* __restrict__ bhc,
                                                const int* __restrict__ bhr,
                                                int* __restrict__ bbase, int* __restrict__ bcur,
                                                int* __restrict__ rbase, int* __restrict__ rcur,
                                                float* __restrict__ g,
                                                int NBK, int E) {
    __shared__ int s[512];
    int tid = threadIdx.x;
    for (int i = tid; i < 64 * 32; i += 512) g[i] = -__builtin_inff();
    int v = (tid < NBK) ? bhc[tid] : 0;
    s[tid] = v;
    __syncthreads();
    for (int off = 1; off < 512; off <<= 1) {
        int t = (tid >= off) ? s[tid - off] : 0;
        __syncthreads();
        s[tid] += t;
        __syncthreads();
    }
    if (tid < NBK) { int b = s[tid] - v; bbase[tid] = b; bcur[tid] = b; }
    if (tid == 0) bbase[NBK] = E;
    __syncthreads();
    v = (tid < NBK) ? bhr[tid] : 0;
    s[tid] = v;
    __syncthreads();
    for (int off = 1; off < 512; off <<= 1) {
        int t = (tid >= off) ? s[tid - off] : 0;
        __syncthreads();
        s[tid] += t;
        __syncthreads();
    }
    if (tid < NBK) { int b = s[tid] - v; rbase[tid] = b; rcur[tid] = b; }
    if (tid == 0) rbase[NBK] = E;
}

// ---- pass 3: single-pass dual scatter (col->ebuck packed int, row->rbuck int) ----
__global__ __launch_bounds__(NT) void k_bscatter2(const int* __restrict__ row,
                                                  const int* __restrict__ col,
                                                  const int* __restrict__ blkc,
                                                  const int* __restrict__ blkr,
                                                  int* __restrict__ bcur, int* __restrict__ rcur,
                                                  int* __restrict__ ebuck, int* __restrict__ rbuck,
                                                  int E, int NBK, int epb) {
    __shared__ int lbasec[512], lbaser[512], lhc[512], lhr[512];
    int tid = threadIdx.x;
    int base = blockIdx.x * 512;
    for (int i = tid; i < NBK; i += NT) {
        int vc = blkc[base + i];
        int vr = blkr[base + i];
        lbasec[i] = vc ? atomicAdd(&bcur[i], vc) : 0;
        lbaser[i] = vr ? atomicAdd(&rcur[i], vr) : 0;
        lhc[i] = 0;
        lhr[i] = 0;
    }
    __syncthreads();
    int start = blockIdx.x * epb;
    int end = min(start + epb, E);
    for (int e = start + tid; e < end; e += NT) {
        int r = row[e], c = col[e];
        int bc_ = c >> BSHIFT;
        int li = atomicAdd(&lhc[bc_], 1);  // LDS
        ebuck[lbasec[bc_] + li] = (r << 8) | (c & (BSIZE - 1));  // r<2^17, fits
        int br_ = r >> BSHIFT;
        int lj = atomicAdd(&lhr[br_], 1);  // LDS
        rbuck[lbaser[br_] + lj] = r;
    }
}

// ---- pass 4a: per-row-bucket count -> dis = rsqrt(outdeg); fused xh/xsh convert ----
__global__ __launch_bounds__(NT) void k_rcsr_xs(const int* __restrict__ rbase,
                                                const int* __restrict__ rbuck,
                                                const float* __restrict__ x,
                                                float* __restrict__ dis,
                                                __half* __restrict__ xh,
                                                __half* __restrict__ xsh, int N) {
    __shared__ int cnt[BSIZE];
    __shared__ float sdis[BSIZE];
    int b = blockIdx.x, tid = threadIdx.x;
    int base = rbase[b], endr = rbase[b + 1];
    cnt[tid] = 0;
    __syncthreads();
    for (int e = base + tid; e < endr; e += NT)
        atomicAdd(&cnt[rbuck[e] & (BSIZE - 1)], 1);  // LDS
    __syncthreads();
    int node = (b << BSHIFT) + tid;
    float d = 0.0f;
    if (node < N) {
        int c = cnt[tid];
        d = (c > 0) ? rsqrtf((float)c) : 0.0f;
        dis[node] = d;
    }
    sdis[tid] = d;
    __syncthreads();
    // convert this bucket's 256 rows: 2048 float4's
    int nodebase = b << BSHIFT;
    for (int i4 = tid; i4 < 2048; i4 += NT) {
        int gnode = nodebase + (i4 >> 3);
        if (gnode >= N) break;
        float4 v = ((const float4*)x)[(size_t)nodebase * 8 + i4];
        float dd = sdis[i4 >> 3];
        float2 o, os;
        ((__half2*)&o)[0] = __floats2half2_rn(v.x, v.y);
        ((__half2*)&o)[1] = __floats2half2_rn(v.z, v.w);
        ((__half2*)&os)[0] = __floats2half2_rn(dd * v.x, dd * v.y);
        ((__half2*)&os)[1] = __floats2half2_rn(dd * v.z, dd * v.w);
        ((float2*)xh)[(size_t)nodebase * 8 + i4] = o;
        ((float2*)xsh)[(size_t)nodebase * 8 + i4] = os;
    }
}

// ---- pass 4b: per-col-bucket counting sort -> offs + src-index entries ----
__global__ __launch_bounds__(NT) void k_bcsr(const int* __restrict__ bbase,
                                             const int* __restrict__ ebuck,
                                             int* __restrict__ offs,
                                             int* __restrict__ entries,
                                             int N, int E, int NBK) {
    __shared__ int cnt[BSIZE];
    __shared__ int excl[BSIZE];
    int b = blockIdx.x, tid = threadIdx.x;
    int base = bbase[b], endr = bbase[b + 1];
    cnt[tid] = 0;
    __syncthreads();
    for (int e = base + tid; e < endr; e += NT)
        atomicAdd(&cnt[ebuck[e] & (BSIZE - 1)], 1);  // LDS
    __syncthreads();
    int v = cnt[tid];
    excl[tid] = v;
    __syncthreads();
    for (int off = 1; off < BSIZE; off <<= 1) {
        int t = (tid >= off) ? excl[tid - off] : 0;
        __syncthreads();
        excl[tid] += t;
        __syncthreads();
    }
    int ex = excl[tid] - v;  // exclusive prefix
    int node = (b << BSHIFT) + tid;
    if (node < N) offs[node] = base + ex;
    cnt[tid] = ex;  // reuse as cursor
    __syncthreads();
    for (int e = base + tid; e < endr; e += NT) {
        int pv = ebuck[e];
        int li = atomicAdd(&cnt[pv & (BSIZE - 1)], 1);  // LDS
        entries[base + li] = pv >> 8;  // src index
    }
    if (b == 0 && tid == 0) offs[N] = E;
}

// ---- prop1: S = sum xs[r]; tx1 = -dis[c]*S (fp16) ; xs2 = dis[c]*tx1 (fp16) ----
__global__ __launch_bounds__(NT) void k_prop1(const int* __restrict__ offs,
                                              const int* __restrict__ entries,
                                              const float* __restrict__ dis,
                                              const __half* __restrict__ xsh,
                                              __half* __restrict__ tx1h,
                                              __half* __restrict__ xs2h, int N) {
    int idx = blockIdx.x * blockDim.x + threadIdx.x;
    int node = idx >> 2, q = idx & 3;
    if (node >= N) return;
    int s = offs[node], t = offs[node + 1];
    float a0 = 0, a1 = 0, a2 = 0, a3 = 0, a4 = 0, a5 = 0, a6 = 0, a7 = 0;
    for (int e = s; e < t; e++) {
        int r = entries[e];
        float4 raw = *(const float4*)(xsh + (size_t)r * 32 + q * 8);  // 8 halfs
        const __half2* hp = (const __half2*)&raw;
        float2 f0 = __half22float2(hp[0]);
        float2 f1 = __half22float2(hp[1]);
        float2 f2 = __half22float2(hp[2]);
        float2 f3 = __half22float2(hp[3]);
        a0 += f0.x; a1 += f0.y; a2 += f1.x; a3 += f1.y;
        a4 += f2.x; a5 += f2.y; a6 += f3.x; a7 += f3.y;
    }
    float d = dis[node];
    float sc = -d;
    float4 o1, o2;
    ((__half2*)&o1)[0] = __floats2half2_rn(sc * a0, sc * a1);
    ((__half2*)&o1)[1] = __floats2half2_rn(sc * a2, sc * a3);
    ((__half2*)&o1)[2] = __floats2half2_rn(sc * a4, sc * a5);
    ((__half2*)&o1)[3] = __floats2half2_rn(sc * a6, sc * a7);
    float sd = sc * d;  // -dis^2
    ((__half2*)&o2)[0] = __floats2half2_rn(sd * a0, sd * a1);
    ((__half2*)&o2)[1] = __floats2half2_rn(sd * a2, sd * a3);
    ((__half2*)&o2)[2] = __floats2half2_rn(sd * a4, sd * a5);
    ((__half2*)&o2)[3] = __floats2half2_rn(sd * a6, sd * a7);
    *(float4*)(tx1h + (size_t)node * 32 + q * 8) = o1;
    *(float4*)(xs2h + (size_t)node * 32 + q * 8) = o2;
}

// ---- fused prop2 + MFMA combine + segmented max ----
// Phase 1 (4 thr/node): p2 = -dis*sum xs2h[r] -> LDS (fp32).
// Phase 2: h = T0@W0 + T1@W1 + (2*p2-T0)@W2 + b via 16x16x32 f16 MFMA.
// Phase 3: block-segmented max -> atomicMax g.
__global__ __launch_bounds__(NT) void k_combine_f(
    const int* __restrict__ offs, const int* __restrict__ entries,
    const float* __restrict__ dis, const __half* __restrict__ xs2h,
    const _Float16* __restrict__ xh, const _Float16* __restrict__ tx1h,
    const float* __restrict__ Wc, const float* __restrict__ bc,
    const int* __restrict__ batch, float* __restrict__ g, int N) {
    __shared__ _Float16 sW[3072];
    __shared__ float sb[32];
    __shared__ float sp2[64][33];
    __shared__ float hs[64][33];
    __shared__ int sbatch[64];

    int tid = threadIdx.x;
    for (int i = tid; i < 3072; i += NT) sW[i] = (_Float16)Wc[i];
    if (tid < 32) sb[tid] = bc[tid];
    int rowbase = blockIdx.x * 64;
    if (tid < 64) {
        int gr = rowbase + tid;
        sbatch[tid] = (gr < N) ? batch[gr] : -1;
    }

    // phase 1: gather prop2 into sp2
    int node_l = tid >> 2, q = tid & 3;
    int gnode = rowbase + node_l;
    if (gnode < N) {
        int s = offs[gnode], t = offs[gnode + 1];
        float a0 = 0, a1 = 0, a2 = 0, a3 = 0, a4 = 0, a5 = 0, a6 = 0, a7 = 0;
        for (int e = s; e < t; e++) {
            int r = entries[e];
            float4 raw = *(const float4*)(xs2h + (size_t)r * 32 + q * 8);
            const __half2* hp = (const __half2*)&raw;
            float2 f0 = __half22float2(hp[0]);
            float2 f1 = __half22float2(hp[1]);
            float2 f2 = __half22float2(hp[2]);
            float2 f3 = __half22float2(hp[3]);
            a0 += f0.x; a1 += f0.y; a2 += f1.x; a3 += f1.y;
            a4 += f2.x; a5 += f2.y; a6 += f3.x; a7 += f3.y;
        }
        float sc = -dis[gnode];
        float* p = &sp2[node_l][q * 8];
        p[0] = sc * a0; p[1] = sc * a1; p[2] = sc * a2; p[3] = sc * a3;
        p[4] = sc * a4; p[5] = sc * a5; p[6] = sc * a6; p[7] = sc * a7;
    }
    __syncthreads();

    // phase 2: MFMA
    int wave = tid >> 6;
    int lane = tid & 63;
    int m = lane & 15;
    int quad = lane >> 4;
    int grow = rowbase + wave * 16 + m;

    half8 a0 = {}, a1 = {}, a2 = {};
    if (grow < N) {
        size_t off = (size_t)grow * 32 + quad * 8;
        a0 = *(const half8*)(xh + off);
        a1 = *(const half8*)(tx1h + off);
        const float* p = &sp2[wave * 16 + m][quad * 8];
        #pragma unroll
        for (int j = 0; j < 8; j++)
            a2[j] = (_Float16)(2.0f * p[j] - (float)a0[j]);
    }

    f32x4 acc[2];
    #pragma unroll
    for (int n = 0; n < 2; n++) {
        half8 b0, b1, b2;
        int colb = n * 16 + m;
        #pragma unroll
        for (int j = 0; j < 8; j++) {
            int k = quad * 8 + j;
            b0[j] = sW[k * 32 + colb];
            b1[j] = sW[1024 + k * 32 + colb];
            b2[j] = sW[2048 + k * 32 + colb];
        }
        f32x4 c = {0.f, 0.f, 0.f, 0.f};
        c = __builtin_amdgcn_mfma_f32_16x16x32_f16(a0, b0, c, 0, 0, 0);
        c = __builtin_amdgcn_mfma_f32_16x16x32_f16(a1, b1, c, 0, 0, 0);
        c = __builtin_amdgcn_mfma_f32_16x16x32_f16(a2, b2, c, 0, 0, 0);
        acc[n] = c;
    }

    #pragma unroll
    for (int n = 0; n < 2; n++)
        #pragma unroll
        for (int r = 0; r < 4; r++)
            hs[wave * 16 + quad * 4 + r][n * 16 + m] = acc[n][r] + sb[n * 16 + m];
    __syncthreads();

    // phase 3: segmented max: 32 features x 8 row-groups of 8 rows
    int f = tid & 31, s = tid >> 5;
    int curb = -1;
    float curm = 0.0f;
    for (int j = s * 8; j < s * 8 + 8; j++) {
        int b = sbatch[j];
        if (b < 0) continue;
        float v = hs[j][f];
        if (b != curb) {
            if (curb >= 0) atomicMaxFloat(&g[curb * 32 + f], curm);
            curb = b;
            curm = v;
        } else {
            curm = fmaxf(curm, v);
        }
    }
    if (curb >= 0) atomicMaxFloat(&g[curb * 32 + f], curm);
}

// ---- fused MLP1+MLP2: block (gi,ks) computes h1 chunk in LDS then W2 chunk ----
__global__ __launch_bounds__(NT) void k_mlp12(const float* __restrict__ g,
                                              const float* __restrict__ W1,
                                              const float* __restrict__ b1,
                                              const float* __restrict__ W2,
                                              float* __restrict__ h2acc) {
    __shared__ float sg[32];
    __shared__ float sh[128];
    int gi = blockIdx.x >> 3, ks = blockIdx.x & 7;
    int tid = threadIdx.x;
    if (tid < 32) sg[tid] = g[gi * 32 + tid];
    __syncthreads();
    if (tid < 128) {
        int c = ks * 128 + tid;
        float a = b1[c];
        #pragma unroll
        for (int k = 0; k < 32; k++) a += sg[k] * W1[k * 1024 + c];
        sh[tid] = fmaxf(a, 0.0f);
    }
    __syncthreads();
    const float* w = W2 + (size_t)(ks * 128) * 512;
    float acc0 = 0.0f, acc1 = 0.0f;
    for (int k = 0; k < 128; k++) {
        float h = sh[k];
        acc0 += h * w[k * 512 + tid];
        acc1 += h * w[k * 512 + tid + 256];
    }
    atomicAdd(&h2acc[gi * 512 + tid], acc0);
    atomicAdd(&h2acc[gi * 512 + tid + 256], acc1);
}

// ---- MLP layer 3 (parallel): out[64,4] = relu(h2acc + b2) @ W3 + b3 ----
__global__ __launch_bounds__(NT) void k_mlp3p(const float* __restrict__ h2acc,
                                              const float* __restrict__ b2,
                                              const float* __restrict__ W3,
                                              const float* __restrict__ b3,
                                              float* __restrict__ out) {
    __shared__ float sp[256];
    int gi = blockIdx.x;
    int tid = threadIdx.x;
    int j = tid & 3, slot = tid >> 2;  // 64 K-slots x 4 outputs
    float part = 0.0f;
    #pragma unroll
    for (int kk = 0; kk < 8; kk++) {
        int k = slot * 8 + kk;
        float h = fmaxf(h2acc[gi * 512 + k] + b2[k], 0.0f);
        part += h * W3[k * 4 + j];
    }
    sp[tid] = part;
    __syncthreads();
    for (int s = 32; s >= 1; s >>= 1) {
        if (slot < s) sp[tid] += sp[(slot + s) * 4 + j];
        __syncthreads();
    }
    if (slot == 0) out[gi * 4 + j] = sp[j] + b3[j];
}

extern "C" void kernel_launch(void* const* d_in, const int* in_sizes, int n_in,
                              void* d_out, int out_size, void* d_ws, size_t ws_size,
                              hipStream_t stream) {
    const float* x   = (const float*)d_in[0];
    const int* ei    = (const int*)d_in[1];
    const int* batch = (const int*)d_in[2];
    const float* Wc  = (const float*)d_in[3];
    const float* bc  = (const float*)d_in[4];
    const float* W1  = (const float*)d_in[5];
    const float* b1  = (const float*)d_in[6];
    const float* W2  = (const float*)d_in[7];
    const float* b2  = (const float*)d_in[8];
    const float* W3  = (const float*)d_in[9];
    const float* b3  = (const float*)d_in[10];
    float* out       = (float*)d_out;

    const int N = in_sizes[2];      // 100000
    const int E = in_sizes[1] / 2;  // 1.6M
    const int* row = ei;
    const int* col = ei + E;
    const int NBK = (N + BSIZE - 1) / BSIZE;   // 391 (<= 512)
    const int epb = (E + HB - 1) / HB;

    // workspace layout (zeroed region first: bhc | bhr | h2acc)
    int* iws = (int*)d_ws;
    int* bhc        = iws;                          // 512
    int* bhr        = bhc + 512;                    // 512
    float* h2acc    = (float*)(bhr + 512);          // 64*512
    int* bbase      = (int*)(h2acc + 64 * 512);     // 512 (NBK+1)
    int* bcur       = bbase + 512;                  // 512
    int* rbase      = bcur + 512;                   // 512 (NBK+1)
    int* rcur       = rbase + 512;                  // 512
    int* offs       = rcur + 512;                   // N+4
    float* dis      = (float*)(offs + N + 4);       // N
    int* entries    = (int*)(dis + N);              // E ints (6.4MB)
    int* blkc       = entries;                      // HB*512 (dead before k_bcsr)
    int* blkr       = blkc + HB * 512;              // HB*512 (total 1MB < 6.4MB)
    _Float16* xh    = (_Float16*)(entries + E);     // 32N halfs (6.4MB)
    _Float16* xsh   = xh + (size_t)N * 32;          // 32N halfs
    _Float16* tx1h  = xsh + (size_t)N * 32;         // 32N halfs ; rbuck aliases
    int* rbuck      = (int*)tx1h;                   // E ints (dead before prop1)
    _Float16* xs2h  = tx1h + (size_t)N * 32;        // 32N halfs
    int* ebuck      = (int*)(xs2h + (size_t)N * 32); // E ints (dead after bcsr)
    float* g        = (float*)(ebuck + E);          // 64*32

    // one contiguous zero: bhc + bhr + h2acc
    hipMemsetAsync(bhc, 0, sizeof(int) * (512 + 512 + 64 * 512), stream);

    k_hist2<<<HB, NT, 0, stream>>>(row, col, bhc, bhr, blkc, blkr, E, NBK, epb);
    k_bscan2<<<1, 512, 0, stream>>>(bhc, bhr, bbase, bcur, rbase, rcur, g, NBK, E);
    k_bscatter2<<<HB, NT, 0, stream>>>(row, col, blkc, blkr, bcur, rcur, ebuck, rbuck, E, NBK, epb);
    k_rcsr_xs<<<NBK, NT, 0, stream>>>(rbase, rbuck, x, dis, (__half*)xh, (__half*)xsh, N);
    k_bcsr<<<NBK, NT, 0, stream>>>(bbase, ebuck, offs, entries, N, E, NBK);
    k_prop1<<<((size_t)N * 4 + NT - 1) / NT, NT, 0, stream>>>(offs, entries, dis, (const __half*)xsh, (__half*)tx1h, (__half*)xs2h, N);
    k_combine_f<<<(N + 63) / 64, NT, 0, stream>>>(offs, entries, dis, (const __half*)xs2h, xh, tx1h, Wc, bc, batch, g, N);
    k_mlp12<<<512, NT, 0, stream>>>(g, W1, b1, W2, h2acc);
    k_mlp3p<<<64, NT, 0, stream>>>(h2acc, b2, W3, b3, out);
}

// Round 14
// 252.277 us; speedup vs baseline: 6.3370x; 1.0749x over previous
//
#include <hip/hip_runtime.h>
#include <hip/hip_fp16.h>

// GCN1: ChebConv(K=3) -> global max pool -> MLP(32->1024->512->4)
// fp32 floats, int32 indices (established rounds 0-3).
// Round 14: k_combine_f had 800K LDS bank conflicts (B-fragment reads
// sW[k*32+colb]: 4 quads -> same bank, 4-way serialized; plus per-block
// re-staging of block-invariant W). Fix: precompute the 6 MFMA B-fragments
// (3 matrices x 2 n-tiles x 64 lanes x 8 halfs = 6KB) once in k_bscan2 into
// global wfrag; combine loads them as six coalesced 16B L2-hit loads.

#define NT 256
#define BSHIFT 8
#define BSIZE 256   // nodes per bucket; NBK = ceil(N/256) = 391 <= 512
#define HB 256      // blocks for hist/scatter passes

typedef _Float16 half8 __attribute__((ext_vector_type(8)));
typedef float f32x4 __attribute__((ext_vector_type(4)));

__device__ __forceinline__ void atomicMaxFloat(float* addr, float val) {
    if (val >= 0.0f) atomicMax((int*)addr, __float_as_int(val));
    else             atomicMin((unsigned int*)addr, __float_as_uint(val));
}

// ---- pass 1: LDS bucket histograms of row and col; per-block counts to global ----
__global__ __launch_bounds__(NT) void k_hist2(const int* __restrict__ row,
                                              const int* __restrict__ col,
                                              int* __restrict__ bhc, int* __restrict__ bhr,
                                              int* __restrict__ blkc, int* __restrict__ blkr,
                                              int E, int NBK, int epb) {
    __shared__ int lhc[512], lhr[512];
    int tid = threadIdx.x;
    for (int i = tid; i < 512; i += NT) { lhc[i] = 0; lhr[i] = 0; }
    __syncthreads();
    int start = blockIdx.x * epb;
    int end = min(start + epb, E);
    for (int e = start + tid; e < end; e += NT) {
        atomicAdd(&lhr[row[e] >> BSHIFT], 1);  // LDS
        atomicAdd(&lhc[col[e] >> BSHIFT], 1);  // LDS
    }
    __syncthreads();
    int base = blockIdx.x * 512;
    for (int i = tid; i < NBK; i += NT) {
        int vc = lhc[i], vr = lhr[i];
        blkc[base + i] = vc;
        blkr[base + i] = vr;
        if (vc) atomicAdd(&bhc[i], vc);
        if (vr) atomicAdd(&bhr[i], vr);
    }
}

// ---- pass 2: scans of both bucket histograms; inits g; precomputes W fragments ----
__global__ __launch_bounds__(512) void k_bscan2(const int* __restrict__ bhc,
                                                const int* __restrict__ bhr,
                                                int* __restrict__ bbase, int* __restrict__ bcur,
                                                int* __restrict__ rbase, int* __restrict__ rcur,
                                                float* __restrict__ g,
                                                const float* __restrict__ Wc,
                                                _Float16* __restrict__ wfrag,
                                                int NBK, int E) {
    __shared__ int s[512];
    int tid = threadIdx.x;
    for (int i = tid; i < 64 * 32; i += 512) g[i] = -__builtin_inff();
    // precompute MFMA B-fragments: combo = mat*2+n, frag[combo][lane][j]
    if (tid < 384) {
        int combo = tid >> 6, lane = tid & 63;
        int mat = combo >> 1, n = combo & 1;
        int m = lane & 15, quad = lane >> 4;
        #pragma unroll
        for (int j = 0; j < 8; j++)
            wfrag[(size_t)combo * 512 + lane * 8 + j] =
                (_Float16)Wc[mat * 1024 + (quad * 8 + j) * 32 + n * 16 + m];
    }
    int v = (tid < NBK) ? bhc[tid] : 0;
    s[tid] = v;
    __syncthreads();
    for (int off = 1; off < 512; off <<= 1) {
        int t = (tid >= off) ? s[tid - off] : 0;
        __syncthreads();
        s[tid] += t;
        __syncthreads();
    }
    if (tid < NBK) { int b = s[tid] - v; bbase[tid] = b; bcur[tid] = b; }
    if (tid == 0) bbase[NBK] = E;
    __syncthreads();
    v = (tid < NBK) ? bhr[tid] : 0;
    s[tid] = v;
    __syncthreads();
    for (int off = 1; off < 512; off <<= 1) {
        int t = (tid >= off) ? s[tid - off] : 0;
        __syncthreads();
        s[tid] += t;
        __syncthreads();
    }
    if (tid < NBK) { int b = s[tid] - v; rbase[tid] = b; rcur[tid] = b; }
    if (tid == 0) rbase[NBK] = E;
}

// ---- pass 3: single-pass dual scatter (col->ebuck packed int, row->rbuck int) ----
__global__ __launch_bounds__(NT) void k_bscatter2(const int* __restrict__ row,
                                                  const int* __restrict__ col,
                                                  const int* __restrict__ blkc,
                                                  const int* __restrict__ blkr,
                                                  int* __restrict__ bcur, int* __restrict__ rcur,
                                                  int* __restrict__ ebuck, int* __restrict__ rbuck,
                                                  int E, int NBK, int epb) {
    __shared__ int lbasec[512], lbaser[512], lhc[512], lhr[512];
    int tid = threadIdx.x;
    int base = blockIdx.x * 512;
    for (int i = tid; i < NBK; i += NT) {
        int vc = blkc[base + i];
        int vr = blkr[base + i];
        lbasec[i] = vc ? atomicAdd(&bcur[i], vc) : 0;
        lbaser[i] = vr ? atomicAdd(&rcur[i], vr) : 0;
        lhc[i] = 0;
        lhr[i] = 0;
    }
    __syncthreads();
    int start = blockIdx.x * epb;
    int end = min(start + epb, E);
    for (int e = start + tid; e < end; e += NT) {
        int r = row[e], c = col[e];
        int bc_ = c >> BSHIFT;
        int li = atomicAdd(&lhc[bc_], 1);  // LDS
        ebuck[lbasec[bc_] + li] = (r << 8) | (c & (BSIZE - 1));  // r<2^17, fits
        int br_ = r >> BSHIFT;
        int lj = atomicAdd(&lhr[br_], 1);  // LDS
        rbuck[lbaser[br_] + lj] = r;
    }
}

// ---- pass 4a: per-row-bucket count -> dis = rsqrt(outdeg); fused xh/xsh convert ----
__global__ __launch_bounds__(NT) void k_rcsr_xs(const int* __restrict__ rbase,
                                                const int* __restrict__ rbuck,
                                                const float* __restrict__ x,
                                                float* __restrict__ dis,
                                                __half* __restrict__ xh,
                                                __half* __restrict__ xsh, int N) {
    __shared__ int cnt[BSIZE];
    __shared__ float sdis[BSIZE];
    int b = blockIdx.x, tid = threadIdx.x;
    int base = rbase[b], endr = rbase[b + 1];
    cnt[tid] = 0;
    __syncthreads();
    for (int e = base + tid; e < endr; e += NT)
        atomicAdd(&cnt[rbuck[e] & (BSIZE - 1)], 1);  // LDS
    __syncthreads();
    int node = (b << BSHIFT) + tid;
    float d = 0.0f;
    if (node < N) {
        int c = cnt[tid];
        d = (c > 0) ? rsqrtf((float)c) : 0.0f;
        dis[node] = d;
    }
    sdis[tid] = d;
    __syncthreads();
    // convert this bucket's 256 rows: 2048 float4's
    int nodebase = b << BSHIFT;
    for (int i4 = tid; i4 < 2048; i4 += NT) {
        int gnode = nodebase + (i4 >> 3);
        if (gnode >= N) break;
        float4 v = ((const float4*)x)[(size_t)nodebase * 8 + i4];
        float dd = sdis[i4 >> 3];
        float2 o, os;
        ((__half2*)&o)[0] = __floats2half2_rn(v.x, v.y);
        ((__half2*)&o)[1] = __floats2half2_rn(v.z, v.w);
        ((__half2*)&os)[0] = __floats2half2_rn(dd * v.x, dd * v.y);
        ((__half2*)&os)[1] = __floats2half2_rn(dd * v.z, dd * v.w);
        ((float2*)xh)[(size_t)nodebase * 8 + i4] = o;
        ((float2*)xsh)[(size_t)nodebase * 8 + i4] = os;
    }
}

// ---- pass 4b: per-col-bucket counting sort -> offs + src-index entries ----
__global__ __launch_bounds__(NT) void k_bcsr(const int* __restrict__ bbase,
                                             const int* __restrict__ ebuck,
                                             int* __restrict__ offs,
                                             int* __restrict__ entries,
                                             int N, int E, int NBK) {
    __shared__ int cnt[BSIZE];
    __shared__ int excl[BSIZE];
    int b = blockIdx.x, tid = threadIdx.x;
    int base = bbase[b], endr = bbase[b + 1];
    cnt[tid] = 0;
    __syncthreads();
    for (int e = base + tid; e < endr; e += NT)
        atomicAdd(&cnt[ebuck[e] & (BSIZE - 1)], 1);  // LDS
    __syncthreads();
    int v = cnt[tid];
    excl[tid] = v;
    __syncthreads();
    for (int off = 1; off < BSIZE; off <<= 1) {
        int t = (tid >= off) ? excl[tid - off] : 0;
        __syncthreads();
        excl[tid] += t;
        __syncthreads();
    }
    int ex = excl[tid] - v;  // exclusive prefix
    int node = (b << BSHIFT) + tid;
    if (node < N) offs[node] = base + ex;
    cnt[tid] = ex;  // reuse as cursor
    __syncthreads();
    for (int e = base + tid; e < endr; e += NT) {
        int pv = ebuck[e];
        int li = atomicAdd(&cnt[pv & (BSIZE - 1)], 1);  // LDS
        entries[base + li] = pv >> 8;  // src index
    }
    if (b == 0 && tid == 0) offs[N] = E;
}

// ---- prop1: S = sum xs[r]; tx1 = -dis[c]*S (fp16) ; xs2 = dis[c]*tx1 (fp16) ----
__global__ __launch_bounds__(NT) void k_prop1(const int* __restrict__ offs,
                                              const int* __restrict__ entries,
                                              const float* __restrict__ dis,
                                              const __half* __restrict__ xsh,
                                              __half* __restrict__ tx1h,
                                              __half* __restrict__ xs2h, int N) {
    int idx = blockIdx.x * blockDim.x + threadIdx.x;
    int node = idx >> 2, q = idx & 3;
    if (node >= N) return;
    int s = offs[node], t = offs[node + 1];
    float a0 = 0, a1 = 0, a2 = 0, a3 = 0, a4 = 0, a5 = 0, a6 = 0, a7 = 0;
    for (int e = s; e < t; e++) {
        int r = entries[e];
        float4 raw = *(const float4*)(xsh + (size_t)r * 32 + q * 8);  // 8 halfs
        const __half2* hp = (const __half2*)&raw;
        float2 f0 = __half22float2(hp[0]);
        float2 f1 = __half22float2(hp[1]);
        float2 f2 = __half22float2(hp[2]);
        float2 f3 = __half22float2(hp[3]);
        a0 += f0.x; a1 += f0.y; a2 += f1.x; a3 += f1.y;
        a4 += f2.x; a5 += f2.y; a6 += f3.x; a7 += f3.y;
    }
    float d = dis[node];
    float sc = -d;
    float4 o1, o2;
    ((__half2*)&o1)[0] = __floats2half2_rn(sc * a0, sc * a1);
    ((__half2*)&o1)[1] = __floats2half2_rn(sc * a2, sc * a3);
    ((__half2*)&o1)[2] = __floats2half2_rn(sc * a4, sc * a5);
    ((__half2*)&o1)[3] = __floats2half2_rn(sc * a6, sc * a7);
    float sd = sc * d;  // -dis^2
    ((__half2*)&o2)[0] = __floats2half2_rn(sd * a0, sd * a1);
    ((__half2*)&o2)[1] = __floats2half2_rn(sd * a2, sd * a3);
    ((__half2*)&o2)[2] = __floats2half2_rn(sd * a4, sd * a5);
    ((__half2*)&o2)[3] = __floats2half2_rn(sd * a6, sd * a7);
    *(float4*)(tx1h + (size_t)node * 32 + q * 8) = o1;
    *(float4*)(xs2h + (size_t)node * 32 + q * 8) = o2;
}

// ---- fused prop2 + MFMA combine + segmented max ----
__global__ __launch_bounds__(NT) void k_combine_f(
    const int* __restrict__ offs, const int* __restrict__ entries,
    const float* __restrict__ dis, const __half* __restrict__ xs2h,
    const _Float16* __restrict__ xh, const _Float16* __restrict__ tx1h,
    const _Float16* __restrict__ wfrag, const float* __restrict__ bc,
    const int* __restrict__ batch, float* __restrict__ g, int N) {
    __shared__ float sb[32];
    __shared__ float sp2[64][33];
    __shared__ float hs[64][33];
    __shared__ int sbatch[64];

    int tid = threadIdx.x;
    if (tid < 32) sb[tid] = bc[tid];
    int rowbase = blockIdx.x * 64;
    if (tid >= 64 && tid < 128) {
        int gr = rowbase + tid - 64;
        sbatch[tid - 64] = (gr < N) ? batch[gr] : -1;
    }

    // phase 1: gather prop2 into sp2
    int node_l = tid >> 2, q = tid & 3;
    int gnode = rowbase + node_l;
    if (gnode < N) {
        int s = offs[gnode], t = offs[gnode + 1];
        float a0 = 0, a1 = 0, a2 = 0, a3 = 0, a4 = 0, a5 = 0, a6 = 0, a7 = 0;
        for (int e = s; e < t; e++) {
            int r = entries[e];
            float4 raw = *(const float4*)(xs2h + (size_t)r * 32 + q * 8);
            const __half2* hp = (const __half2*)&raw;
            float2 f0 = __half22float2(hp[0]);
            float2 f1 = __half22float2(hp[1]);
            float2 f2 = __half22float2(hp[2]);
            float2 f3 = __half22float2(hp[3]);
            a0 += f0.x; a1 += f0.y; a2 += f1.x; a3 += f1.y;
            a4 += f2.x; a5 += f2.y; a6 += f3.x; a7 += f3.y;
        }
        float sc = -dis[gnode];
        float* p = &sp2[node_l][q * 8];
        p[0] = sc * a0; p[1] = sc * a1; p[2] = sc * a2; p[3] = sc * a3;
        p[4] = sc * a4; p[5] = sc * a5; p[6] = sc * a6; p[7] = sc * a7;
    }
    __syncthreads();

    // phase 2: MFMA with precomputed B-fragments (L2-resident, coalesced 16B loads)
    int wave = tid >> 6;
    int lane = tid & 63;
    int m = lane & 15;
    int quad = lane >> 4;
    int grow = rowbase + wave * 16 + m;

    half8 a0 = {}, a1 = {}, a2 = {};
    if (grow < N) {
        size_t off = (size_t)grow * 32 + quad * 8;
        a0 = *(const half8*)(xh + off);
        a1 = *(const half8*)(tx1h + off);
        const float* p = &sp2[wave * 16 + m][quad * 8];
        #pragma unroll
        for (int j = 0; j < 8; j++)
            a2[j] = (_Float16)(2.0f * p[j] - (float)a0[j]);
    }

    const half8* wf = (const half8*)wfrag;
    f32x4 acc[2];
    #pragma unroll
    for (int n = 0; n < 2; n++) {
        f32x4 c = {0.f, 0.f, 0.f, 0.f};
        c = __builtin_amdgcn_mfma_f32_16x16x32_f16(a0, wf[(0 * 2 + n) * 64 + lane], c, 0, 0, 0);
        c = __builtin_amdgcn_mfma_f32_16x16x32_f16(a1, wf[(1 * 2 + n) * 64 + lane], c, 0, 0, 0);
        c = __builtin_amdgcn_mfma_f32_16x16x32_f16(a2, wf[(2 * 2 + n) * 64 + lane], c, 0, 0, 0);
        acc[n] = c;
    }

    #pragma unroll
    for (int n = 0; n < 2; n++)
        #pragma unroll
        for (int r = 0; r < 4; r++)
            hs[wave * 16 + quad * 4 + r][n * 16 + m] = acc[n][r] + sb[n * 16 + m];
    __syncthreads();

    // phase 3: segmented max: 32 features x 8 row-groups of 8 rows
    int f = tid & 31, s = tid >> 5;
    int curb = -1;
    float curm = 0.0f;
    for (int j = s * 8; j < s * 8 + 8; j++) {
        int b = sbatch[j];
        if (b < 0) continue;
        float v = hs[j][f];
        if (b != curb) {
            if (curb >= 0) atomicMaxFloat(&g[curb * 32 + f], curm);
            curb = b;
            curm = v;
        } else {
            curm = fmaxf(curm, v);
        }
    }
    if (curb >= 0) atomicMaxFloat(&g[curb * 32 + f], curm);
}

// ---- fused MLP1+MLP2: block (gi,ks) computes h1 chunk in LDS then W2 chunk ----
__global__ __launch_bounds__(NT) void k_mlp12(const float* __restrict__ g,
                                              const float* __restrict__ W1,
                                              const float* __restrict__ b1,
                                              const float* __restrict__ W2,
                                              float* __restrict__ h2acc) {
    __shared__ float sg[32];
    __shared__ float sh[128];
    int gi = blockIdx.x >> 3, ks = blockIdx.x & 7;
    int tid = threadIdx.x;
    if (tid < 32) sg[tid] = g[gi * 32 + tid];
    __syncthreads();
    if (tid < 128) {
        int c = ks * 128 + tid;
        float a = b1[c];
        #pragma unroll
        for (int k = 0; k < 32; k++) a += sg[k] * W1[k * 1024 + c];
        sh[tid] = fmaxf(a, 0.0f);
    }
    __syncthreads();
    const float* w = W2 + (size_t)(ks * 128) * 512;
    float acc0 = 0.0f, acc1 = 0.0f;
    for (int k = 0; k < 128; k++) {
        float h = sh[k];
        acc0 += h * w[k * 512 + tid];
        acc1 += h * w[k * 512 + tid + 256];
    }
    atomicAdd(&h2acc[gi * 512 + tid], acc0);
    atomicAdd(&h2acc[gi * 512 + tid + 256], acc1);
}

// ---- MLP layer 3 (parallel): out[64,4] = relu(h2acc + b2) @ W3 + b3 ----
__global__ __launch_bounds__(NT) void k_mlp3p(const float* __restrict__ h2acc,
                                              const float* __restrict__ b2,
                                              const float* __restrict__ W3,
                                              const float* __restrict__ b3,
                                              float* __restrict__ out) {
    __shared__ float sp[256];
    int gi = blockIdx.x;
    int tid = threadIdx.x;
    int j = tid & 3, slot = tid >> 2;  // 64 K-slots x 4 outputs
    float part = 0.0f;
    #pragma unroll
    for (int kk = 0; kk < 8; kk++) {
        int k = slot * 8 + kk;
        float h = fmaxf(h2acc[gi * 512 + k] + b2[k], 0.0f);
        part += h * W3[k * 4 + j];
    }
    sp[tid] = part;
    __syncthreads();
    for (int s = 32; s >= 1; s >>= 1) {
        if (slot < s) sp[tid] += sp[(slot + s) * 4 + j];
        __syncthreads();
    }
    if (slot == 0) out[gi * 4 + j] = sp[j] + b3[j];
}

extern "C" void kernel_launch(void* const* d_in, const int* in_sizes, int n_in,
                              void* d_out, int out_size, void* d_ws, size_t ws_size,
                              hipStream_t stream) {
    const float* x   = (const float*)d_in[0];
    const int* ei    = (const int*)d_in[1];
    const int* batch = (const int*)d_in[2];
    const float* Wc  = (const float*)d_in[3];
    const float* bc  = (const float*)d_in[4];
    const float* W1  = (const float*)d_in[5];
    const float* b1  = (const float*)d_in[6];
    const float* W2  = (const float*)d_in[7];
    const float* b2  = (const float*)d_in[8];
    const float* W3  = (const float*)d_in[9];
    const float* b3  = (const float*)d_in[10];
    float* out       = (float*)d_out;

    const int N = in_sizes[2];      // 100000
    const int E = in_sizes[1] / 2;  // 1.6M
    const int* row = ei;
    const int* col = ei + E;
    const int NBK = (N + BSIZE - 1) / BSIZE;   // 391 (<= 512)
    const int epb = (E + HB - 1) / HB;

    // workspace layout (zeroed region first: bhc | bhr | h2acc)
    int* iws = (int*)d_ws;
    int* bhc        = iws;                          // 512
    int* bhr        = bhc + 512;                    // 512
    float* h2acc    = (float*)(bhr + 512);          // 64*512
    int* bbase      = (int*)(h2acc + 64 * 512);     // 512 (NBK+1)
    int* bcur       = bbase + 512;                  // 512
    int* rbase      = bcur + 512;                   // 512 (NBK+1)
    int* rcur       = rbase + 512;                  // 512
    int* offs       = rcur + 512;                   // N+4
    float* dis      = (float*)(offs + N + 4);       // N
    int* entries    = (int*)(dis + N);              // E ints (6.4MB)
    int* blkc       = entries;                      // HB*512 (dead before k_bcsr)
    int* blkr       = blkc + HB * 512;              // HB*512 (total 1MB < 6.4MB)
    _Float16* xh    = (_Float16*)(entries + E);     // 32N halfs (6.4MB)
    _Float16* xsh   = xh + (size_t)N * 32;          // 32N halfs
    _Float16* tx1h  = xsh + (size_t)N * 32;         // 32N halfs ; rbuck aliases
    int* rbuck      = (int*)tx1h;                   // E ints (dead before prop1)
    _Float16* xs2h  = tx1h + (size_t)N * 32;        // 32N halfs
    int* ebuck      = (int*)(xs2h + (size_t)N * 32); // E ints (dead after bcsr)
    float* g        = (float*)(ebuck + E);          // 64*32
    _Float16* wfrag = (_Float16*)(g + 64 * 32);     // 6*512 halfs (6KB)

    // one contiguous zero: bhc + bhr + h2acc
    hipMemsetAsync(bhc, 0, sizeof(int) * (512 + 512 + 64 * 512), stream);

    k_hist2<<<HB, NT, 0, stream>>>(row, col, bhc, bhr, blkc, blkr, E, NBK, epb);
    k_bscan2<<<1, 512, 0, stream>>>(bhc, bhr, bbase, bcur, rbase, rcur, g, Wc, wfrag, NBK, E);
    k_bscatter2<<<HB, NT, 0, stream>>>(row, col, blkc, blkr, bcur, rcur, ebuck, rbuck, E, NBK, epb);
    k_rcsr_xs<<<NBK, NT, 0, stream>>>(rbase, rbuck, x, dis, (__half*)xh, (__half*)xsh, N);
    k_bcsr<<<NBK, NT, 0, stream>>>(bbase, ebuck, offs, entries, N, E, NBK);
    k_prop1<<<((size_t)N * 4 + NT - 1) / NT, NT, 0, stream>>>(offs, entries, dis, (const __half*)xsh, (__half*)tx1h, (__half*)xs2h, N);
    k_combine_f<<<(N + 63) / 64, NT, 0, stream>>>(offs, entries, dis, (const __half*)xs2h, xh, tx1h, wfrag, bc, batch, g, N);
    k_mlp12<<<512, NT, 0, stream>>>(g, W1, b1, W2, h2acc);
    k_mlp3p<<<64, NT, 0, stream>>>(h2acc, b2, W3, b3, out);
}

// Round 15
// 250.613 us; speedup vs baseline: 6.3791x; 1.0066x over previous
//
#include <hip/hip_runtime.h>
#include <hip/hip_fp16.h>

// GCN1: ChebConv(K=3) -> global max pool -> MLP(32->1024->512->4)
// fp32 floats, int32 indices (established rounds 0-3).
// Round 15: gather kernels are latency-bound (46% occ, 12% VALU, ~2TB/s).
// (a) prop1: 8 thr/node (edge-range halves) + shfl_xor combine -> 2x waves;
// (b) 4-deep unrolled gather loops -> 4 gathers in flight/thread;
// (c) tx1h eliminated: combine reconstructs T1 = xs2 * rdis (rdis = sqrt(deg)).

#define NT 256
#define BSHIFT 8
#define BSIZE 256   // nodes per bucket; NBK = ceil(N/256) = 391 <= 512
#define HB 256      // blocks for hist/scatter passes

typedef _Float16 half8 __attribute__((ext_vector_type(8)));
typedef float f32x4 __attribute__((ext_vector_type(4)));

__device__ __forceinline__ void atomicMaxFloat(float* addr, float val) {
    if (val >= 0.0f) atomicMax((int*)addr, __float_as_int(val));
    else             atomicMin((unsigned int*)addr, __float_as_uint(val));
}

#define ACC8(raw)                                        \
    do {                                                 \
        const __half2* hp_ = (const __half2*)&(raw);     \
        float2 f0_ = __half22float2(hp_[0]);             \
        float2 f1_ = __half22float2(hp_[1]);             \
        float2 f2_ = __half22float2(hp_[2]);             \
        float2 f3_ = __half22float2(hp_[3]);             \
        a0 += f0_.x; a1 += f0_.y; a2 += f1_.x; a3 += f1_.y; \
        a4 += f2_.x; a5 += f2_.y; a6 += f3_.x; a7 += f3_.y; \
    } while (0)

// ---- pass 1: LDS bucket histograms of row and col; per-block counts to global ----
__global__ __launch_bounds__(NT) void k_hist2(const int* __restrict__ row,
                                              const int* __restrict__ col,
                                              int* __restrict__ bhc, int* __restrict__ bhr,
                                              int* __restrict__ blkc, int* __restrict__ blkr,
                                              int E, int NBK, int epb) {
    __shared__ int lhc[512], lhr[512];
    int tid = threadIdx.x;
    for (int i = tid; i < 512; i += NT) { lhc[i] = 0; lhr[i] = 0; }
    __syncthreads();
    int start = blockIdx.x * epb;
    int end = min(start + epb, E);
    for (int e = start + tid; e < end; e += NT) {
        atomicAdd(&lhr[row[e] >> BSHIFT], 1);  // LDS
        atomicAdd(&lhc[col[e] >> BSHIFT], 1);  // LDS
    }
    __syncthreads();
    int base = blockIdx.x * 512;
    for (int i = tid; i < NBK; i += NT) {
        int vc = lhc[i], vr = lhr[i];
        blkc[base + i] = vc;
        blkr[base + i] = vr;
        if (vc) atomicAdd(&bhc[i], vc);
        if (vr) atomicAdd(&bhr[i], vr);
    }
}

// ---- pass 2: scans of both bucket histograms; inits g; precomputes W fragments ----
__global__ __launch_bounds__(512) void k_bscan2(const int* __restrict__ bhc,
                                                const int* __restrict__ bhr,
                                                int* __restrict__ bbase, int* __restrict__ bcur,
                                                int* __restrict__ rbase, int* __restrict__ rcur,
                                                float* __restrict__ g,
                                                const float* __restrict__ Wc,
                                                _Float16* __restrict__ wfrag,
                                                int NBK, int E) {
    __shared__ int s[512];
    int tid = threadIdx.x;
    for (int i = tid; i < 64 * 32; i += 512) g[i] = -__builtin_inff();
    // precompute MFMA B-fragments: combo = mat*2+n, frag[combo][lane][j]
    if (tid < 384) {
        int combo = tid >> 6, lane = tid & 63;
        int mat = combo >> 1, n = combo & 1;
        int m = lane & 15, quad = lane >> 4;
        #pragma unroll
        for (int j = 0; j < 8; j++)
            wfrag[(size_t)combo * 512 + lane * 8 + j] =
                (_Float16)Wc[mat * 1024 + (quad * 8 + j) * 32 + n * 16 + m];
    }
    int v = (tid < NBK) ? bhc[tid] : 0;
    s[tid] = v;
    __syncthreads();
    for (int off = 1; off < 512; off <<= 1) {
        int t = (tid >= off) ? s[tid - off] : 0;
        __syncthreads();
        s[tid] += t;
        __syncthreads();
    }
    if (tid < NBK) { int b = s[tid] - v; bbase[tid] = b; bcur[tid] = b; }
    if (tid == 0) bbase[NBK] = E;
    __syncthreads();
    v = (tid < NBK) ? bhr[tid] : 0;
    s[tid] = v;
    __syncthreads();
    for (int off = 1; off < 512; off <<= 1) {
        int t = (tid >= off) ? s[tid - off] : 0;
        __syncthreads();
        s[tid] += t;
        __syncthreads();
    }
    if (tid < NBK) { int b = s[tid] - v; rbase[tid] = b; rcur[tid] = b; }
    if (tid == 0) rbase[NBK] = E;
}

// ---- pass 3: single-pass dual scatter (col->ebuck packed int, row->rbuck int) ----
__global__ __launch_bounds__(NT) void k_bscatter2(const int* __restrict__ row,
                                                  const int* __restrict__ col,
                                                  const int* __restrict__ blkc,
                                                  const int* __restrict__ blkr,
                                                  int* __restrict__ bcur, int* __restrict__ rcur,
                                                  int* __restrict__ ebuck, int* __restrict__ rbuck,
                                                  int E, int NBK, int epb) {
    __shared__ int lbasec[512], lbaser[512], lhc[512], lhr[512];
    int tid = threadIdx.x;
    int base = blockIdx.x * 512;
    for (int i = tid; i < NBK; i += NT) {
        int vc = blkc[base + i];
        int vr = blkr[base + i];
        lbasec[i] = vc ? atomicAdd(&bcur[i], vc) : 0;
        lbaser[i] = vr ? atomicAdd(&rcur[i], vr) : 0;
        lhc[i] = 0;
        lhr[i] = 0;
    }
    __syncthreads();
    int start = blockIdx.x * epb;
    int end = min(start + epb, E);
    for (int e = start + tid; e < end; e += NT) {
        int r = row[e], c = col[e];
        int bc_ = c >> BSHIFT;
        int li = atomicAdd(&lhc[bc_], 1);  // LDS
        ebuck[lbasec[bc_] + li] = (r << 8) | (c & (BSIZE - 1));  // r<2^17, fits
        int br_ = r >> BSHIFT;
        int lj = atomicAdd(&lhr[br_], 1);  // LDS
        rbuck[lbaser[br_] + lj] = r;
    }
}

// ---- pass 4a: per-row-bucket count -> dis/rdis; fused xh/xsh convert ----
__global__ __launch_bounds__(NT) void k_rcsr_xs(const int* __restrict__ rbase,
                                                const int* __restrict__ rbuck,
                                                const float* __restrict__ x,
                                                float* __restrict__ dis,
                                                float* __restrict__ rdis,
                                                __half* __restrict__ xh,
                                                __half* __restrict__ xsh, int N) {
    __shared__ int cnt[BSIZE];
    __shared__ float sdis[BSIZE];
    int b = blockIdx.x, tid = threadIdx.x;
    int base = rbase[b], endr = rbase[b + 1];
    cnt[tid] = 0;
    __syncthreads();
    for (int e = base + tid; e < endr; e += NT)
        atomicAdd(&cnt[rbuck[e] & (BSIZE - 1)], 1);  // LDS
    __syncthreads();
    int node = (b << BSHIFT) + tid;
    float d = 0.0f;
    if (node < N) {
        int c = cnt[tid];
        d = (c > 0) ? rsqrtf((float)c) : 0.0f;
        dis[node] = d;
        rdis[node] = (c > 0) ? sqrtf((float)c) : 0.0f;  // 1/dis
    }
    sdis[tid] = d;
    __syncthreads();
    // convert this bucket's 256 rows: 2048 float4's
    int nodebase = b << BSHIFT;
    for (int i4 = tid; i4 < 2048; i4 += NT) {
        int gnode = nodebase + (i4 >> 3);
        if (gnode >= N) break;
        float4 v = ((const float4*)x)[(size_t)nodebase * 8 + i4];
        float dd = sdis[i4 >> 3];
        float2 o, os;
        ((__half2*)&o)[0] = __floats2half2_rn(v.x, v.y);
        ((__half2*)&o)[1] = __floats2half2_rn(v.z, v.w);
        ((__half2*)&os)[0] = __floats2half2_rn(dd * v.x, dd * v.y);
        ((__half2*)&os)[1] = __floats2half2_rn(dd * v.z, dd * v.w);
        ((float2*)xh)[(size_t)nodebase * 8 + i4] = o;
        ((float2*)xsh)[(size_t)nodebase * 8 + i4] = os;
    }
}

// ---- pass 4b: per-col-bucket counting sort -> offs + src-index entries ----
__global__ __launch_bounds__(NT) void k_bcsr(const int* __restrict__ bbase,
                                             const int* __restrict__ ebuck,
                                             int* __restrict__ offs,
                                             int* __restrict__ entries,
                                             int N, int E, int NBK) {
    __shared__ int cnt[BSIZE];
    __shared__ int excl[BSIZE];
    int b = blockIdx.x, tid = threadIdx.x;
    int base = bbase[b], endr = bbase[b + 1];
    cnt[tid] = 0;
    __syncthreads();
    for (int e = base + tid; e < endr; e += NT)
        atomicAdd(&cnt[ebuck[e] & (BSIZE - 1)], 1);  // LDS
    __syncthreads();
    int v = cnt[tid];
    excl[tid] = v;
    __syncthreads();
    for (int off = 1; off < BSIZE; off <<= 1) {
        int t = (tid >= off) ? excl[tid - off] : 0;
        __syncthreads();
        excl[tid] += t;
        __syncthreads();
    }
    int ex = excl[tid] - v;  // exclusive prefix
    int node = (b << BSHIFT) + tid;
    if (node < N) offs[node] = base + ex;
    cnt[tid] = ex;  // reuse as cursor
    __syncthreads();
    for (int e = base + tid; e < endr; e += NT) {
        int pv = ebuck[e];
        int li = atomicAdd(&cnt[pv & (BSIZE - 1)], 1);  // LDS
        entries[base + li] = pv >> 8;  // src index
    }
    if (b == 0 && tid == 0) offs[N] = E;
}

// ---- prop1: xs2 = -dis^2 * sum xs[r] (fp16). 8 thr/node: 2 edge-halves x 4 q. ----
__global__ __launch_bounds__(NT) void k_prop1(const int* __restrict__ offs,
                                              const int* __restrict__ entries,
                                              const float* __restrict__ dis,
                                              const __half* __restrict__ xsh,
                                              __half* __restrict__ xs2h, int N) {
    int idx = blockIdx.x * blockDim.x + threadIdx.x;
    int node = idx >> 3, sp = (idx >> 2) & 1, q = idx & 3;
    if (node >= N) return;
    int s = offs[node], t = offs[node + 1];
    int mid = s + ((t - s) >> 1);
    int lo = sp ? mid : s;
    int hi = sp ? t : mid;
    float a0 = 0, a1 = 0, a2 = 0, a3 = 0, a4 = 0, a5 = 0, a6 = 0, a7 = 0;
    int e = lo;
    for (; e + 4 <= hi; e += 4) {
        int r0 = entries[e], r1 = entries[e + 1], r2 = entries[e + 2], r3 = entries[e + 3];
        float4 w0 = *(const float4*)(xsh + (size_t)r0 * 32 + q * 8);
        float4 w1 = *(const float4*)(xsh + (size_t)r1 * 32 + q * 8);
        float4 w2 = *(const float4*)(xsh + (size_t)r2 * 32 + q * 8);
        float4 w3 = *(const float4*)(xsh + (size_t)r3 * 32 + q * 8);
        ACC8(w0); ACC8(w1); ACC8(w2); ACC8(w3);
    }
    for (; e < hi; e++) {
        int r = entries[e];
        float4 w = *(const float4*)(xsh + (size_t)r * 32 + q * 8);
        ACC8(w);
    }
    // combine the two edge-halves (lanes differ in bit 2)
    a0 += __shfl_xor(a0, 4); a1 += __shfl_xor(a1, 4);
    a2 += __shfl_xor(a2, 4); a3 += __shfl_xor(a3, 4);
    a4 += __shfl_xor(a4, 4); a5 += __shfl_xor(a5, 4);
    a6 += __shfl_xor(a6, 4); a7 += __shfl_xor(a7, 4);
    if (sp == 0) {
        float d = dis[node];
        float sd = -d * d;  // xs2 = dis * tx1 = -dis^2 * S
        float4 ov;
        ((__half2*)&ov)[0] = __floats2half2_rn(sd * a0, sd * a1);
        ((__half2*)&ov)[1] = __floats2half2_rn(sd * a2, sd * a3);
        ((__half2*)&ov)[2] = __floats2half2_rn(sd * a4, sd * a5);
        ((__half2*)&ov)[3] = __floats2half2_rn(sd * a6, sd * a7);
        *(float4*)(xs2h + (size_t)node * 32 + q * 8) = ov;
    }
}

// ---- fused prop2 + MFMA combine + segmented max ----
// T1 reconstructed as xs2 * rdis (rdis = sqrt(deg) = 1/dis; 0 if deg=0).
__global__ __launch_bounds__(NT) void k_combine_f(
    const int* __restrict__ offs, const int* __restrict__ entries,
    const float* __restrict__ dis, const float* __restrict__ rdis,
    const __half* __restrict__ xs2h, const _Float16* __restrict__ xh,
    const _Float16* __restrict__ wfrag, const float* __restrict__ bc,
    const int* __restrict__ batch, float* __restrict__ g, int N) {
    __shared__ float sb[32];
    __shared__ float sp2[64][33];
    __shared__ float hs[64][33];
    __shared__ int sbatch[64];

    int tid = threadIdx.x;
    if (tid < 32) sb[tid] = bc[tid];
    int rowbase = blockIdx.x * 64;
    if (tid >= 64 && tid < 128) {
        int gr = rowbase + tid - 64;
        sbatch[tid - 64] = (gr < N) ? batch[gr] : -1;
    }

    // phase 1: gather prop2 into sp2 (4 thr/node, 4-deep unroll)
    int node_l = tid >> 2, q = tid & 3;
    int gnode = rowbase + node_l;
    if (gnode < N) {
        int s = offs[gnode], t = offs[gnode + 1];
        float a0 = 0, a1 = 0, a2 = 0, a3 = 0, a4 = 0, a5 = 0, a6 = 0, a7 = 0;
        int e = s;
        for (; e + 4 <= t; e += 4) {
            int r0 = entries[e], r1 = entries[e + 1], r2 = entries[e + 2], r3 = entries[e + 3];
            float4 w0 = *(const float4*)(xs2h + (size_t)r0 * 32 + q * 8);
            float4 w1 = *(const float4*)(xs2h + (size_t)r1 * 32 + q * 8);
            float4 w2 = *(const float4*)(xs2h + (size_t)r2 * 32 + q * 8);
            float4 w3 = *(const float4*)(xs2h + (size_t)r3 * 32 + q * 8);
            ACC8(w0); ACC8(w1); ACC8(w2); ACC8(w3);
        }
        for (; e < t; e++) {
            int r = entries[e];
            float4 w = *(const float4*)(xs2h + (size_t)r * 32 + q * 8);
            ACC8(w);
        }
        float sc = -dis[gnode];
        float* p = &sp2[node_l][q * 8];
        p[0] = sc * a0; p[1] = sc * a1; p[2] = sc * a2; p[3] = sc * a3;
        p[4] = sc * a4; p[5] = sc * a5; p[6] = sc * a6; p[7] = sc * a7;
    }
    __syncthreads();

    // phase 2: MFMA with precomputed B-fragments (L2-resident, coalesced 16B loads)
    int wave = tid >> 6;
    int lane = tid & 63;
    int m = lane & 15;
    int quad = lane >> 4;
    int grow = rowbase + wave * 16 + m;

    half8 a0 = {}, a1 = {}, a2 = {};
    if (grow < N) {
        size_t off = (size_t)grow * 32 + quad * 8;
        a0 = *(const half8*)(xh + off);
        half8 x2 = *(const half8*)((const _Float16*)xs2h + off);
        float rd = rdis[grow];
        const float* p = &sp2[wave * 16 + m][quad * 8];
        #pragma unroll
        for (int j = 0; j < 8; j++) {
            a1[j] = (_Float16)((float)x2[j] * rd);          // T1 = xs2 / dis
            a2[j] = (_Float16)(2.0f * p[j] - (float)a0[j]); // T2 = 2*P2 - T0
        }
    }

    const half8* wf = (const half8*)wfrag;
    f32x4 acc[2];
    #pragma unroll
    for (int n = 0; n < 2; n++) {
        f32x4 c = {0.f, 0.f, 0.f, 0.f};
        c = __builtin_amdgcn_mfma_f32_16x16x32_f16(a0, wf[(0 * 2 + n) * 64 + lane], c, 0, 0, 0);
        c = __builtin_amdgcn_mfma_f32_16x16x32_f16(a1, wf[(1 * 2 + n) * 64 + lane], c, 0, 0, 0);
        c = __builtin_amdgcn_mfma_f32_16x16x32_f16(a2, wf[(2 * 2 + n) * 64 + lane], c, 0, 0, 0);
        acc[n] = c;
    }

    #pragma unroll
    for (int n = 0; n < 2; n++)
        #pragma unroll
        for (int r = 0; r < 4; r++)
            hs[wave * 16 + quad * 4 + r][n * 16 + m] = acc[n][r] + sb[n * 16 + m];
    __syncthreads();

    // phase 3: segmented max: 32 features x 8 row-groups of 8 rows
    int f = tid & 31, s = tid >> 5;
    int curb = -1;
    float curm = 0.0f;
    for (int j = s * 8; j < s * 8 + 8; j++) {
        int b = sbatch[j];
        if (b < 0) continue;
        float v = hs[j][f];
        if (b != curb) {
            if (curb >= 0) atomicMaxFloat(&g[curb * 32 + f], curm);
            curb = b;
            curm = v;
        } else {
            curm = fmaxf(curm, v);
        }
    }
    if (curb >= 0) atomicMaxFloat(&g[curb * 32 + f], curm);
}

// ---- fused MLP1+MLP2: block (gi,ks) computes h1 chunk in LDS then W2 chunk ----
__global__ __launch_bounds__(NT) void k_mlp12(const float* __restrict__ g,
                                              const float* __restrict__ W1,
                                              const float* __restrict__ b1,
                                              const float* __restrict__ W2,
                                              float* __restrict__ h2acc) {
    __shared__ float sg[32];
    __shared__ float sh[128];
    int gi = blockIdx.x >> 3, ks = blockIdx.x & 7;
    int tid = threadIdx.x;
    if (tid < 32) sg[tid] = g[gi * 32 + tid];
    __syncthreads();
    if (tid < 128) {
        int c = ks * 128 + tid;
        float a = b1[c];
        #pragma unroll
        for (int k = 0; k < 32; k++) a += sg[k] * W1[k * 1024 + c];
        sh[tid] = fmaxf(a, 0.0f);
    }
    __syncthreads();
    const float* w = W2 + (size_t)(ks * 128) * 512;
    float acc0 = 0.0f, acc1 = 0.0f;
    for (int k = 0; k < 128; k++) {
        float h = sh[k];
        acc0 += h * w[k * 512 + tid];
        acc1 += h * w[k * 512 + tid + 256];
    }
    atomicAdd(&h2acc[gi * 512 + tid], acc0);
    atomicAdd(&h2acc[gi * 512 + tid + 256], acc1);
}

// ---- MLP layer 3 (parallel): out[64,4] = relu(h2acc + b2) @ W3 + b3 ----
__global__ __launch_bounds__(NT) void k_mlp3p(const float* __restrict__ h2acc,
                                              const float* __restrict__ b2,
                                              const float* __restrict__ W3,
                                              const float* __restrict__ b3,
                                              float* __restrict__ out) {
    __shared__ float sp[256];
    int gi = blockIdx.x;
    int tid = threadIdx.x;
    int j = tid & 3, slot = tid >> 2;  // 64 K-slots x 4 outputs
    float part = 0.0f;
    #pragma unroll
    for (int kk = 0; kk < 8; kk++) {
        int k = slot * 8 + kk;
        float h = fmaxf(h2acc[gi * 512 + k] + b2[k], 0.0f);
        part += h * W3[k * 4 + j];
    }
    sp[tid] = part;
    __syncthreads();
    for (int s = 32; s >= 1; s >>= 1) {
        if (slot < s) sp[tid] += sp[(slot + s) * 4 + j];
        __syncthreads();
    }
    if (slot == 0) out[gi * 4 + j] = sp[j] + b3[j];
}

extern "C" void kernel_launch(void* const* d_in, const int* in_sizes, int n_in,
                              void* d_out, int out_size, void* d_ws, size_t ws_size,
                              hipStream_t stream) {
    const float* x   = (const float*)d_in[0];
    const int* ei    = (const int*)d_in[1];
    const int* batch = (const int*)d_in[2];
    const float* Wc  = (const float*)d_in[3];
    const float* bc  = (const float*)d_in[4];
    const float* W1  = (const float*)d_in[5];
    const float* b1  = (const float*)d_in[6];
    const float* W2  = (const float*)d_in[7];
    const float* b2  = (const float*)d_in[8];
    const float* W3  = (const float*)d_in[9];
    const float* b3  = (const float*)d_in[10];
    float* out       = (float*)d_out;

    const int N = in_sizes[2];      // 100000
    const int E = in_sizes[1] / 2;  // 1.6M
    const int* row = ei;
    const int* col = ei + E;
    const int NBK = (N + BSIZE - 1) / BSIZE;   // 391 (<= 512)
    const int epb = (E + HB - 1) / HB;

    // workspace layout (zeroed region first: bhc | bhr | h2acc)
    int* iws = (int*)d_ws;
    int* bhc        = iws;                          // 512
    int* bhr        = bhc + 512;                    // 512
    float* h2acc    = (float*)(bhr + 512);          // 64*512
    int* bbase      = (int*)(h2acc + 64 * 512);     // 512 (NBK+1)
    int* bcur       = bbase + 512;                  // 512
    int* rbase      = bcur + 512;                   // 512 (NBK+1)
    int* rcur       = rbase + 512;                  // 512
    int* offs       = rcur + 512;                   // N+4
    float* dis      = (float*)(offs + N + 4);       // N
    float* rdis     = dis + N;                      // N
    int* entries    = (int*)(rdis + N);             // E ints (6.4MB)
    int* blkc       = entries;                      // HB*512 (dead before k_bcsr)
    int* blkr       = blkc + HB * 512;              // HB*512 (total 1MB < 6.4MB)
    _Float16* xh    = (_Float16*)(entries + E);     // 32N halfs (6.4MB)
    _Float16* xsh   = xh + (size_t)N * 32;          // 32N halfs
    int* rbuck      = (int*)(xsh + (size_t)N * 32); // E ints (dead after rcsr_xs)
    _Float16* xs2h  = (_Float16*)(rbuck + E);       // 32N halfs
    int* ebuck      = (int*)(xs2h + (size_t)N * 32); // E ints (dead after bcsr)
    float* g        = (float*)(ebuck + E);          // 64*32
    _Float16* wfrag = (_Float16*)(g + 64 * 32);     // 6*512 halfs (6KB)

    // one contiguous zero: bhc + bhr + h2acc
    hipMemsetAsync(bhc, 0, sizeof(int) * (512 + 512 + 64 * 512), stream);

    k_hist2<<<HB, NT, 0, stream>>>(row, col, bhc, bhr, blkc, blkr, E, NBK, epb);
    k_bscan2<<<1, 512, 0, stream>>>(bhc, bhr, bbase, bcur, rbase, rcur, g, Wc, wfrag, NBK, E);
    k_bscatter2<<<HB, NT, 0, stream>>>(row, col, blkc, blkr, bcur, rcur, ebuck, rbuck, E, NBK, epb);
    k_rcsr_xs<<<NBK, NT, 0, stream>>>(rbase, rbuck, x, dis, rdis, (__half*)xh, (__half*)xsh, N);
    k_bcsr<<<NBK, NT, 0, stream>>>(bbase, ebuck, offs, entries, N, E, NBK);
    k_prop1<<<((size_t)N * 8 + NT - 1) / NT, NT, 0, stream>>>(offs, entries, dis, (const __half*)xsh, (__half*)xs2h, N);
    k_combine_f<<<(N + 63) / 64, NT, 0, stream>>>(offs, entries, dis, rdis, (const __half*)xs2h, xh, wfrag, bc, batch, g, N);
    k_mlp12<<<512, NT, 0, stream>>>(g, W1, b1, W2, h2acc);
    k_mlp3p<<<64, NT, 0, stream>>>(h2acc, b2, W3, b3, out);
}